// Round 1
// baseline (1859.960 us; speedup 1.0000x reference)
//
#include <hip/hip_runtime.h>
#include <cstdint>
#include <math.h>

// Problem sizes (fixed by the reference).
#define NN 50000
#define EE 800000
#define RR 850000      // NN + EE rows
#define NT_N 3125      // NN/16
#define NT_R 53125     // RR/16

typedef short  bf16x8 __attribute__((ext_vector_type(8)));
typedef float  f32x4  __attribute__((ext_vector_type(4)));

__device__ __forceinline__ float bf2f(unsigned short b) {
    unsigned int u = ((unsigned int)b) << 16;
    return __builtin_bit_cast(float, u);
}
__device__ __forceinline__ unsigned short f2bf(float f) {
    unsigned int u = __builtin_bit_cast(unsigned int, f);
    u = u + 0x7fffu + ((u >> 16) & 1u);
    return (unsigned short)(u >> 16);
}
__device__ __forceinline__ void atomAddF(float* p, float v) { unsafeAtomicAdd(p, v); }
__device__ __forceinline__ void atomAddD(double* p, double v) { unsafeAtomicAdd(p, v); }
__device__ __forceinline__ int atomAddI(int* p, int v) { return atomicAdd(p, v); }

// split 8 consecutive f32 into hi/lo bf16 fragments: hi+lo == v to ~2^-16 rel
__device__ __forceinline__ void split8(const float* p, bf16x8& hi, bf16x8& lo) {
    f32x4 v0 = *reinterpret_cast<const f32x4*>(p);
    f32x4 v1 = *reinterpret_cast<const f32x4*>(p + 4);
#pragma unroll
    for (int j = 0; j < 4; j++) {
        unsigned short h0 = f2bf(v0[j]);
        hi[j] = (short)h0; lo[j] = (short)f2bf(v0[j] - bf2f(h0));
        unsigned short h1 = f2bf(v1[j]);
        hi[4 + j] = (short)h1; lo[4 + j] = (short)f2bf(v1[j] - bf2f(h1));
    }
}
__device__ __forceinline__ void split8r(const float* v, bf16x8& hi, bf16x8& lo) {
#pragma unroll
    for (int j = 0; j < 8; j++) {
        unsigned short h = f2bf(v[j]);
        hi[j] = (short)h; lo[j] = (short)f2bf(v[j] - bf2f(h));
    }
}

// LDS-staged coalesced tile store: MFMA C-layout -> 4x 1KB contiguous dwordx4 stores.
template <bool RELU, bool STATS>
__device__ __forceinline__ void epi_tile(float* wl, int lane, const f32x4* acc,
                                         const float* bv, float* __restrict__ gout,
                                         int tile, double* ssum, double* ssq) {
    const int m = lane & 15, quad = lane >> 4;
#pragma unroll
    for (int ct = 0; ct < 4; ct++)
#pragma unroll
        for (int i = 0; i < 4; i++) {
            float val = acc[ct][i] + bv[ct];
            if (RELU) val = fmaxf(val, 0.f);
            wl[(quad * 4 + i) * 68 + ct * 16 + m] = val;
            if (STATS) { ssum[ct] += (double)val; ssq[ct] += (double)val * (double)val; }
        }
    asm volatile("s_waitcnt lgkmcnt(0)" ::: "memory");
#pragma unroll
    for (int j = 0; j < 4; j++) {
        int row = j * 4 + quad;
        f32x4 vv = *reinterpret_cast<const f32x4*>(wl + row * 68 + m * 4);
        *reinterpret_cast<f32x4*>(gout + ((size_t)(tile << 4) + row) * 64 + m * 4) = vv;
    }
}

// ---------- degree counts ----------
__global__ void k_deg(const int* __restrict__ ei, int* __restrict__ od, int* __restrict__ id) {
    int e = blockIdx.x * 256 + threadIdx.x;   // covers EE exactly
    atomAddI(&od[ei[e]], 1);
    atomAddI(&id[ei[EE + e]], 1);
}

// ---------- dual exclusive scan (block 0: dst-CSR, block 1: src-CSR) ----------
__global__ void __launch_bounds__(1024) k_scan2(const int* __restrict__ id, int* __restrict__ off,
                                                int* __restrict__ cursor,
                                                const int* __restrict__ od, int* __restrict__ off_s,
                                                int* __restrict__ cursor_s) {
    const int* cnt = (blockIdx.x == 0) ? id : od;
    int* o  = (blockIdx.x == 0) ? off : off_s;
    int* cu = (blockIdx.x == 0) ? cursor : cursor_s;
    __shared__ int part[1024];
    const int t = threadIdx.x;
    const int CH = (NN + 1023) / 1024;
    int base = t * CH, s = 0;
    for (int i = 0; i < CH; i++) { int idx = base + i; if (idx < NN) s += cnt[idx]; }
    part[t] = s;
    __syncthreads();
    if (t == 0) {
        int run = 0;
        for (int i = 0; i < 1024; i++) { int x = part[i]; part[i] = run; run += x; }
    }
    __syncthreads();
    int run = part[t];
    for (int i = 0; i < CH; i++) {
        int idx = base + i;
        if (idx < NN) { o[idx] = run; cu[idx] = run; run += cnt[idx]; }
    }
    if (t == 0) o[NN] = EE;
}

// ---------- fill dst-sorted packed edge array: sd = src | (dst<<16) ----------
__global__ void k_fill(const int* __restrict__ ei, int* __restrict__ cursor,
                       unsigned int* __restrict__ sd_s) {
    int e = blockIdx.x * 256 + threadIdx.x;   // covers EE exactly
    int s = ei[e], d = ei[EE + e];
    int p = atomAddI(&cursor[d], 1);
    sd_s[p] = (unsigned int)s | ((unsigned int)d << 16);
}

// ---------- fill src-CSR permutation + permuted-dst table ----------
__global__ void k_fill2(const unsigned int* __restrict__ sd_s, int* __restrict__ cursor_s,
                        int* __restrict__ perm_s, unsigned short* __restrict__ pdst) {
    int p = blockIdx.x * 256 + threadIdx.x;   // covers EE exactly
    unsigned int sd = sd_s[p];
    int s = (int)(sd & 0xFFFFu);
    int q = atomAddI(&cursor_s[s], 1);
    perm_s[q] = p;
    pdst[q] = (unsigned short)(sd >> 16);
}

// ---------- dsum[n] = x[n] + sum_{e: dst=n} x[src_e]  (CSR, no atomics, 16-way MLP) ----------
__global__ void k_dsum_csr(const float* __restrict__ x, const int* __restrict__ off,
                           const unsigned int* __restrict__ sd_s, float* __restrict__ dsum) {
    int team = (blockIdx.x * 256 + threadIdx.x) >> 6;   // 12500 blocks x 4 = NN
    int c = threadIdx.x & 63;
    float a[16];
#pragma unroll
    for (int j = 0; j < 16; j++) a[j] = 0.f;
    a[0] = x[(size_t)team * 64 + c];
    int e = off[team], e1 = off[team + 1];
    for (; e + 15 < e1; e += 16)
#pragma unroll
        for (int j = 0; j < 16; j++) a[j] += x[(size_t)(sd_s[e + j] & 0xFFFFu) * 64 + c];
    for (; e + 3 < e1; e += 4)
#pragma unroll
        for (int j = 0; j < 4; j++) a[j] += x[(size_t)(sd_s[e + j] & 0xFFFFu) * 64 + c];
    for (; e < e1; e++) a[0] += x[(size_t)(sd_s[e] & 0xFFFFu) * 64 + c];
#pragma unroll
    for (int j = 0; j < 8; j++) a[j] += a[j + 8];
#pragma unroll
    for (int j = 0; j < 4; j++) a[j] += a[j + 4];
    dsum[(size_t)team * 64 + c] = (a[0] + a[1]) + (a[2] + a[3]);
}

// ---------- u = x@W_top, v = dsum@W_bot, u2 = dsum@W_top ----------
__global__ void k_uv3(const float* __restrict__ x, const float* __restrict__ dsum,
                      const float* __restrict__ W, float* __restrict__ u,
                      float* __restrict__ v, float* __restrict__ u2) {
    __shared__ float lds[4][16 * 68];
    const int lane = threadIdx.x & 63;
    const int wid = threadIdx.x >> 6;
    const int m = lane & 15, quad = lane >> 4;
    const int gwave = (blockIdx.x * blockDim.x + threadIdx.x) >> 6;
    const int nwaves = (gridDim.x * blockDim.x) >> 6;
    float* wl = lds[wid];

    bf16x8 wfh[4][4], wfl[4][4];
#pragma unroll
    for (int kk = 0; kk < 4; kk++)
#pragma unroll
        for (int ct = 0; ct < 4; ct++) {
            float wv[8];
#pragma unroll
            for (int j = 0; j < 8; j++)
                wv[j] = W[(kk * 32 + quad * 8 + j) * 64 + ct * 16 + m];
            split8r(wv, wfh[kk][ct], wfl[kk][ct]);
        }
    float zb[4] = {0.f, 0.f, 0.f, 0.f};

    for (int tile = gwave; tile < NT_N; tile += nwaves) {
        const int r = (tile << 4) + m;
        bf16x8 ah[4], al[4];
        split8(x    + (size_t)r * 64 + quad * 8,      ah[0], al[0]);
        split8(x    + (size_t)r * 64 + 32 + quad * 8, ah[1], al[1]);
        split8(dsum + (size_t)r * 64 + quad * 8,      ah[2], al[2]);
        split8(dsum + (size_t)r * 64 + 32 + quad * 8, ah[3], al[3]);

        f32x4 zero = {0.f, 0.f, 0.f, 0.f};
        f32x4 aU[4], aV[4], aU2[4];
#pragma unroll
        for (int ct = 0; ct < 4; ct++) {
            aU[ct] = zero; aV[ct] = zero; aU2[ct] = zero;
#pragma unroll
            for (int kk = 0; kk < 2; kk++) {
                aU[ct]  = __builtin_amdgcn_mfma_f32_16x16x32_bf16(al[kk],   wfh[kk][ct],   aU[ct],  0, 0, 0);
                aU[ct]  = __builtin_amdgcn_mfma_f32_16x16x32_bf16(ah[kk],   wfl[kk][ct],   aU[ct],  0, 0, 0);
                aU[ct]  = __builtin_amdgcn_mfma_f32_16x16x32_bf16(ah[kk],   wfh[kk][ct],   aU[ct],  0, 0, 0);
                aV[ct]  = __builtin_amdgcn_mfma_f32_16x16x32_bf16(al[kk+2], wfh[kk+2][ct], aV[ct],  0, 0, 0);
                aV[ct]  = __builtin_amdgcn_mfma_f32_16x16x32_bf16(ah[kk+2], wfl[kk+2][ct], aV[ct],  0, 0, 0);
                aV[ct]  = __builtin_amdgcn_mfma_f32_16x16x32_bf16(ah[kk+2], wfh[kk+2][ct], aV[ct],  0, 0, 0);
                aU2[ct] = __builtin_amdgcn_mfma_f32_16x16x32_bf16(al[kk+2], wfh[kk][ct],   aU2[ct], 0, 0, 0);
                aU2[ct] = __builtin_amdgcn_mfma_f32_16x16x32_bf16(ah[kk+2], wfl[kk][ct],   aU2[ct], 0, 0, 0);
                aU2[ct] = __builtin_amdgcn_mfma_f32_16x16x32_bf16(ah[kk+2], wfh[kk][ct],   aU2[ct], 0, 0, 0);
            }
        }
        epi_tile<false, false>(wl, lane, aU,  zb, u,  tile, nullptr, nullptr);
        epi_tile<false, false>(wl, lane, aV,  zb, v,  tile, nullptr, nullptr);
        epi_tile<false, false>(wl, lane, aU2, zb, u2, tile, nullptr, nullptr);
    }
}

// ---------- analytic stage-1 stats ----------
__global__ void k_stats1a(const float* __restrict__ u, const float* __restrict__ v,
                          const float* __restrict__ u2, const int* __restrict__ od,
                          const int* __restrict__ id, double* __restrict__ stats_raw) {
    __shared__ double lsum[4][64], lsq[4][64];
    int tid = threadIdx.x, c = tid & 63, w = tid >> 6;
    double a1 = 0.0, a2 = 0.0;
    for (int n = blockIdx.x * 4 + w; n < NN; n += gridDim.x * 4) {
        double uu = u[(size_t)n * 64 + c], vv = v[(size_t)n * 64 + c];
        double uu2 = u2[(size_t)n * 64 + c];
        double wod = 1.0 + od[n], wid = 1.0 + id[n];
        a1 += wod * uu + wid * vv;
        a2 += wod * uu * uu + wid * vv * vv + 2.0 * vv * uu2;
    }
    lsum[w][c] = a1; lsq[w][c] = a2;
    __syncthreads();
    if (w == 0) {
        a1 = lsum[0][c] + lsum[1][c] + lsum[2][c] + lsum[3][c];
        a2 = lsq[0][c] + lsq[1][c] + lsq[2][c] + lsq[3][c];
        atomAddD(&stats_raw[c], a1);
        atomAddD(&stats_raw[64 + c], a2);
    }
}

__global__ void k_fin1(const double* __restrict__ raw, const float* __restrict__ b,
                       float* __restrict__ fin, double inv_cnt) {
    int c = threadIdx.x;
    double m1 = raw[c] * inv_cnt;
    double var = raw[64 + c] * inv_cnt - m1 * m1;
    if (var < 0.0) var = 0.0;
    fin[c] = (float)(m1 + (double)b[c]);
    fin[64 + c] = (float)(1.0 / sqrt(var + 1e-5));
}

__global__ void k_fin(const double* __restrict__ raw, float* __restrict__ fin, double inv_cnt) {
    int c = threadIdx.x;
    double mean = raw[c] * inv_cnt;
    double var = raw[64 + c] * inv_cnt - mean * mean;
    if (var < 0.0) var = 0.0;
    fin[c] = (float)mean;
    fin[64 + c] = (float)(1.0 / sqrt(var + 1e-5));
}

// ---------- FUSED stage-1 reduce + stage-2 matmul (replaces k_s1_csr + k_ph0) ----------
// Per node d (one wave): rows = {self} U {in-edges}. For each row:
//   h = relu(bn1(u[src]+v[d]))            (the ONLY u-gather for this row in the whole net)
//   s_tab[d]   += h                       (stage-1 domain reduce, registers)
//   a_row      = h @ Wtop2                (16-row LDS-transpose batches -> MFMA)
//   h2a[row]   = a_row  (mb NOT added — separable; added by consumers)
//   Sa, Sa2    += a_row (zero-padded tail rows contribute exactly 0)
__global__ void k_s1ph(const float* __restrict__ u, const float* __restrict__ v,
                       const int* __restrict__ off, const unsigned int* __restrict__ sd_s,
                       const float* __restrict__ b_un, const float* __restrict__ fin,
                       const float* __restrict__ g1, const float* __restrict__ be1,
                       const float* __restrict__ W, float* __restrict__ s_tab,
                       float* __restrict__ h2a, double* __restrict__ stats_raw) {
    __shared__ float lds[4][16 * 68];
    const int lane = threadIdx.x & 63;
    const int wid = threadIdx.x >> 6;
    const int team = (blockIdx.x * 256 + threadIdx.x) >> 6;   // node id, 12500*4 = NN
    const int c = lane;
    const int m = lane & 15, quad = lane >> 4;
    float* wl = lds[wid];

    bf16x8 wfh[2][4], wfl[2][4];
#pragma unroll
    for (int kk = 0; kk < 2; kk++)
#pragma unroll
        for (int ct = 0; ct < 4; ct++) {
            float wv[8];
#pragma unroll
            for (int j = 0; j < 8; j++)
                wv[j] = W[(kk * 32 + quad * 8 + j) * 64 + ct * 16 + m];
            split8r(wv, wfh[kk][ct], wfl[kk][ct]);
        }

    const float sc  = fin[64 + c] * g1[c];
    const float tsh = (b_un[c] - fin[c]) * sc + be1[c];
    const float vn  = v[(size_t)team * 64 + c];
    const int e0 = off[team];
    const int nrows = off[team + 1] - e0 + 1;     // self + in-degree

    float s_acc = 0.f;
    double ssum[4] = {0,0,0,0}, ssq[4] = {0,0,0,0};

    for (int b = 0; b < nrows; b += 16) {
        // phase 1: per-channel gather + bn1 + relu (lane = channel), stage rows in LDS
        float hv[16];
#pragma unroll
        for (int j = 0; j < 16; j++) {
            int ridx = b + j;
            int s = team;
            if (ridx > 0 && ridx < nrows) s = (int)(sd_s[e0 + ridx - 1] & 0xFFFFu);
            float h = fmaxf((u[(size_t)s * 64 + c] + vn) * sc + tsh, 0.f);
            hv[j] = (ridx < nrows) ? h : 0.f;
        }
#pragma unroll
        for (int j = 0; j < 16; j++) { s_acc += hv[j]; wl[j * 68 + c] = hv[j]; }

        // phase 2: transpose-read into MFMA A-frag layout (lane(m,quad) = row m, ch quad*8..)
        bf16x8 ah[2], al[2];
#pragma unroll
        for (int kk = 0; kk < 2; kk++) {
            float tv[8];
#pragma unroll
            for (int j = 0; j < 8; j++) tv[j] = wl[m * 68 + kk * 32 + quad * 8 + j];
            split8r(tv, ah[kk], al[kk]);
        }

        f32x4 zero = {0.f, 0.f, 0.f, 0.f};
        f32x4 acc[4];
#pragma unroll
        for (int ct = 0; ct < 4; ct++) {
            acc[ct] = zero;
#pragma unroll
            for (int kk = 0; kk < 2; kk++) {
                acc[ct] = __builtin_amdgcn_mfma_f32_16x16x32_bf16(al[kk], wfh[kk][ct], acc[ct], 0, 0, 0);
                acc[ct] = __builtin_amdgcn_mfma_f32_16x16x32_bf16(ah[kk], wfl[kk][ct], acc[ct], 0, 0, 0);
                acc[ct] = __builtin_amdgcn_mfma_f32_16x16x32_bf16(ah[kk], wfh[kk][ct], acc[ct], 0, 0, 0);
            }
        }

        // phase 3: stats + LDS-staged coalesced store (row 0 of batch 0 -> self slot)
#pragma unroll
        for (int ct = 0; ct < 4; ct++)
#pragma unroll
            for (int i = 0; i < 4; i++) {
                float val = acc[ct][i];
                wl[(quad * 4 + i) * 68 + ct * 16 + m] = val;
                ssum[ct] += (double)val;
                ssq[ct]  += (double)val * (double)val;
            }
        asm volatile("s_waitcnt lgkmcnt(0)" ::: "memory");
#pragma unroll
        for (int j = 0; j < 4; j++) {
            int jr = j * 4 + quad;
            int ridx = b + jr;
            if (ridx < nrows) {
                f32x4 vv = *reinterpret_cast<const f32x4*>(wl + jr * 68 + m * 4);
                size_t base = (ridx == 0) ? (size_t)team * 64
                                          : (size_t)(NN + e0 + ridx - 1) * 64;
                __builtin_nontemporal_store(vv, reinterpret_cast<f32x4*>(h2a + base + m * 4));
            }
        }
    }

    s_tab[(size_t)team * 64 + c] = s_acc;

#pragma unroll
    for (int ct = 0; ct < 4; ct++) {
        double sv = ssum[ct], qv = ssq[ct];
        sv += __shfl_xor(sv, 16, 64); sv += __shfl_xor(sv, 32, 64);
        qv += __shfl_xor(qv, 16, 64); qv += __shfl_xor(qv, 32, 64);
        if (quad == 0) {
            atomAddD(&stats_raw[ct * 16 + m], sv);
            atomAddD(&stats_raw[64 + ct * 16 + m], qv);
        }
    }
}

// ---------- msg[n] = sum_{e:dst=n} s_tab[src_e] ----------
__global__ void k_msg_csr(const int* __restrict__ off, const unsigned int* __restrict__ sd_s,
                          const float* __restrict__ s_tab, float* __restrict__ msg) {
    int team = (blockIdx.x * 256 + threadIdx.x) >> 6;
    int c = threadIdx.x & 63;
    float a[16];
#pragma unroll
    for (int j = 0; j < 16; j++) a[j] = 0.f;
    int e = off[team], e1 = off[team + 1];
    for (; e + 15 < e1; e += 16)
#pragma unroll
        for (int j = 0; j < 16; j++) a[j] += s_tab[(size_t)(sd_s[e + j] & 0xFFFFu) * 64 + c];
    for (; e + 3 < e1; e += 4)
#pragma unroll
        for (int j = 0; j < 4; j++) a[j] += s_tab[(size_t)(sd_s[e + j] & 0xFFFFu) * 64 + c];
    for (; e < e1; e++) a[0] += s_tab[(size_t)(sd_s[e] & 0xFFFFu) * 64 + c];
#pragma unroll
    for (int j = 0; j < 8; j++) a[j] += a[j + 8];
#pragma unroll
    for (int j = 0; j < 4; j++) a[j] += a[j + 4];
    msg[(size_t)team * 64 + c] = (a[0] + a[1]) + (a[2] + a[3]);
}

// ---------- generic node-level matmul: out = in @ W (+ bias). in==out allowed. ----------
__global__ void k_nmm(const float* __restrict__ in, const float* __restrict__ W,
                      const float* __restrict__ bias, float* __restrict__ outp) {
    __shared__ float lds[4][16 * 68];
    const int lane = threadIdx.x & 63;
    const int wid = threadIdx.x >> 6;
    const int m = lane & 15, quad = lane >> 4;
    const int gwave = (blockIdx.x * blockDim.x + threadIdx.x) >> 6;
    const int nwaves = (gridDim.x * blockDim.x) >> 6;
    float* wl = lds[wid];

    bf16x8 wfh[2][4], wfl[2][4];
#pragma unroll
    for (int kk = 0; kk < 2; kk++)
#pragma unroll
        for (int ct = 0; ct < 4; ct++) {
            float wv[8];
#pragma unroll
            for (int j = 0; j < 8; j++)
                wv[j] = W[(kk * 32 + quad * 8 + j) * 64 + ct * 16 + m];
            split8r(wv, wfh[kk][ct], wfl[kk][ct]);
        }
    float bv[4];
#pragma unroll
    for (int ct = 0; ct < 4; ct++) bv[ct] = bias ? bias[ct * 16 + m] : 0.f;

    for (int tile = gwave; tile < NT_N; tile += nwaves) {
        const int r = (tile << 4) + m;
        bf16x8 ah[2], al[2];
        split8(in + (size_t)r * 64 + quad * 8,      ah[0], al[0]);
        split8(in + (size_t)r * 64 + 32 + quad * 8, ah[1], al[1]);

        f32x4 zero = {0.f, 0.f, 0.f, 0.f};
        f32x4 acc[4];
#pragma unroll
        for (int ct = 0; ct < 4; ct++) {
            acc[ct] = zero;
#pragma unroll
            for (int kk = 0; kk < 2; kk++) {
                acc[ct] = __builtin_amdgcn_mfma_f32_16x16x32_bf16(al[kk], wfh[kk][ct], acc[ct], 0, 0, 0);
                acc[ct] = __builtin_amdgcn_mfma_f32_16x16x32_bf16(ah[kk], wfl[kk][ct], acc[ct], 0, 0, 0);
                acc[ct] = __builtin_amdgcn_mfma_f32_16x16x32_bf16(ah[kk], wfh[kk][ct], acc[ct], 0, 0, 0);
            }
        }
        epi_tile<false, false>(wl, lane, acc, bv, outp, tile, nullptr, nullptr);
    }
}

// ---------- analytic stage-2 stat terms from mb' (=mb+b_gc) and sA (=s_tab@Wtop2) ----------
// adds: S1 += sum_d cnt_d*mb'_d ; S2 += sum_d (2*mb'_d*sA_d + cnt_d*mb'_d^2)
__global__ void k_stats2a(const float* __restrict__ mb, const float* __restrict__ sA,
                          const int* __restrict__ id, double* __restrict__ stats_raw) {
    __shared__ double lsum[4][64], lsq[4][64];
    int tid = threadIdx.x, c = tid & 63, w = tid >> 6;
    double a1 = 0.0, a2 = 0.0;
    for (int n = blockIdx.x * 4 + w; n < NN; n += gridDim.x * 4) {
        double mv = mb[(size_t)n * 64 + c];
        double sa = sA[(size_t)n * 64 + c];
        double cnt = 1.0 + id[n];
        a1 += cnt * mv;
        a2 += 2.0 * mv * sa + cnt * mv * mv;
    }
    lsum[w][c] = a1; lsq[w][c] = a2;
    __syncthreads();
    if (w == 0) {
        a1 = lsum[0][c] + lsum[1][c] + lsum[2][c] + lsum[3][c];
        a2 = lsq[0][c] + lsq[1][c] + lsq[2][c] + lsq[3][c];
        atomAddD(&stats_raw[c], a1);
        atomAddD(&stats_raw[64 + c], a2);
    }
}

// ---------- agg[n] = relu(bn2(h2a[n]+mb'[n])) + sum_{q in src-CSR} relu(bn2(h2a[NN+p]+mb'[pdst[q]])) ----------
__global__ void k_agg2(const float* __restrict__ h2a, const float* __restrict__ mb,
                       const int* __restrict__ off_s, const int* __restrict__ perm_s,
                       const unsigned short* __restrict__ pdst,
                       const float* __restrict__ fin2, const float* __restrict__ g2,
                       const float* __restrict__ be2, float* __restrict__ agg) {
    int n = (blockIdx.x * 256 + threadIdx.x) >> 6;
    int c = threadIdx.x & 63;
    float sc = fin2[64 + c] * g2[c];
    float sh = be2[c] - fin2[c] * sc;
    float a[16];
#pragma unroll
    for (int j = 0; j < 16; j++) a[j] = 0.f;
    a[0] = fmaxf((h2a[(size_t)n * 64 + c] + mb[(size_t)n * 64 + c]) * sc + sh, 0.f);  // self
    int q = off_s[n], q1 = off_s[n + 1];
    for (; q + 15 < q1; q += 16)
#pragma unroll
        for (int j = 0; j < 16; j++) {
            int p = perm_s[q + j];
            int dn = (int)pdst[q + j];
            float hv = __builtin_nontemporal_load(h2a + (size_t)(NN + p) * 64 + c)
                     + mb[(size_t)dn * 64 + c];
            a[j] += fmaxf(hv * sc + sh, 0.f);
        }
    for (; q + 3 < q1; q += 4)
#pragma unroll
        for (int j = 0; j < 4; j++) {
            int p = perm_s[q + j];
            int dn = (int)pdst[q + j];
            float hv = __builtin_nontemporal_load(h2a + (size_t)(NN + p) * 64 + c)
                     + mb[(size_t)dn * 64 + c];
            a[j] += fmaxf(hv * sc + sh, 0.f);
        }
    for (; q < q1; q++) {
        int p = perm_s[q];
        int dn = (int)pdst[q];
        float hv = __builtin_nontemporal_load(h2a + (size_t)(NN + p) * 64 + c)
                 + mb[(size_t)dn * 64 + c];
        a[0] += fmaxf(hv * sc + sh, 0.f);
    }
#pragma unroll
    for (int j = 0; j < 8; j++) a[j] += a[j + 8];
#pragma unroll
    for (int j = 0; j < 4; j++) a[j] += a[j + 4];
    agg[(size_t)n * 64 + c] = (a[0] + a[1]) + (a[2] + a[3]);
}

// ---------- stage 3: t_pre = [relu(bn2(h2a[:N]+mb')), agg] @ W_tr + b_tr, stats3 ----------
__global__ void k_mm3(const float* __restrict__ h2a, const float* __restrict__ mb,
                      const float* __restrict__ agg,
                      const float* __restrict__ W, const float* __restrict__ bias,
                      const float* __restrict__ fin2, const float* __restrict__ g2,
                      const float* __restrict__ be2,
                      float* __restrict__ outp, double* __restrict__ stats_raw) {
    __shared__ float lds[4][16 * 68];
    const int lane = threadIdx.x & 63;
    const int wid = threadIdx.x >> 6;
    const int m = lane & 15, quad = lane >> 4;
    const int gwave = (blockIdx.x * blockDim.x + threadIdx.x) >> 6;
    const int nwaves = (gridDim.x * blockDim.x) >> 6;
    float* wl = lds[wid];

    bf16x8 wfh[4][4], wfl[4][4];
#pragma unroll
    for (int kk = 0; kk < 4; kk++)
#pragma unroll
        for (int ct = 0; ct < 4; ct++) {
            float wv[8];
#pragma unroll
            for (int j = 0; j < 8; j++)
                wv[j] = W[(kk * 32 + quad * 8 + j) * 64 + ct * 16 + m];
            split8r(wv, wfh[kk][ct], wfl[kk][ct]);
        }

    float bv[4];
#pragma unroll
    for (int ct = 0; ct < 4; ct++) bv[ct] = bias[ct * 16 + m];

    float s2f[2][8], t2f[2][8];
#pragma unroll
    for (int kk = 0; kk < 2; kk++)
#pragma unroll
        for (int j = 0; j < 8; j++) {
            int c = kk * 32 + quad * 8 + j;
            float sc = fin2[64 + c] * g2[c];
            s2f[kk][j] = sc;
            t2f[kk][j] = be2[c] - fin2[c] * sc;
        }

    double ssum[4] = {0,0,0,0}, ssq[4] = {0,0,0,0};

    for (int tile = gwave; tile < NT_N; tile += nwaves) {
        const int r = (tile << 4) + m;
        bf16x8 ah[4], al[4];
#pragma unroll
        for (int kk = 0; kk < 2; kk++) {
            f32x4 v0 = __builtin_nontemporal_load(
                reinterpret_cast<const f32x4*>(h2a + (size_t)r * 64 + kk * 32 + quad * 8));
            f32x4 v1 = __builtin_nontemporal_load(
                reinterpret_cast<const f32x4*>(h2a + (size_t)r * 64 + kk * 32 + quad * 8 + 4));
            f32x4 m0 = *reinterpret_cast<const f32x4*>(mb + (size_t)r * 64 + kk * 32 + quad * 8);
            f32x4 m1 = *reinterpret_cast<const f32x4*>(mb + (size_t)r * 64 + kk * 32 + quad * 8 + 4);
            float tv[8];
#pragma unroll
            for (int j = 0; j < 4; j++) {
                tv[j]     = fmaxf((v0[j] + m0[j]) * s2f[kk][j]     + t2f[kk][j],     0.f);
                tv[4 + j] = fmaxf((v1[j] + m1[j]) * s2f[kk][4 + j] + t2f[kk][4 + j], 0.f);
            }
            split8r(tv, ah[kk], al[kk]);
        }
        split8(agg + (size_t)r * 64 + quad * 8,      ah[2], al[2]);
        split8(agg + (size_t)r * 64 + 32 + quad * 8, ah[3], al[3]);

        f32x4 zero = {0.f, 0.f, 0.f, 0.f};
        f32x4 acc[4];
#pragma unroll
        for (int ct = 0; ct < 4; ct++) {
            acc[ct] = zero;
#pragma unroll
            for (int kk = 0; kk < 4; kk++)
                acc[ct] = __builtin_amdgcn_mfma_f32_16x16x32_bf16(al[kk], wfh[kk][ct], acc[ct], 0, 0, 0);
#pragma unroll
            for (int kk = 0; kk < 4; kk++)
                acc[ct] = __builtin_amdgcn_mfma_f32_16x16x32_bf16(ah[kk], wfl[kk][ct], acc[ct], 0, 0, 0);
#pragma unroll
            for (int kk = 0; kk < 4; kk++)
                acc[ct] = __builtin_amdgcn_mfma_f32_16x16x32_bf16(ah[kk], wfh[kk][ct], acc[ct], 0, 0, 0);
        }

        epi_tile<false, true>(wl, lane, acc, bv, outp, tile, ssum, ssq);
    }

#pragma unroll
    for (int ct = 0; ct < 4; ct++) {
        double sv = ssum[ct], qv = ssq[ct];
        sv += __shfl_xor(sv, 16, 64); sv += __shfl_xor(sv, 32, 64);
        qv += __shfl_xor(qv, 16, 64); qv += __shfl_xor(qv, 32, 64);
        if (quad == 0) {
            atomAddD(&stats_raw[ct * 16 + m], sv);
            atomAddD(&stats_raw[64 + ct * 16 + m], qv);
        }
    }
}

// ---------- stage 4 ----------
__global__ void k_mm4(const float* __restrict__ tpre, const float* __restrict__ W,
                      const float* __restrict__ bias, const float* __restrict__ fin3,
                      const float* __restrict__ g2, const float* __restrict__ be2,
                      float* __restrict__ outp, double* __restrict__ stats_raw) {
    __shared__ float lds[4][16 * 68];
    const int lane = threadIdx.x & 63;
    const int wid = threadIdx.x >> 6;
    const int m = lane & 15, quad = lane >> 4;
    const int gwave = (blockIdx.x * blockDim.x + threadIdx.x) >> 6;
    const int nwaves = (gridDim.x * blockDim.x) >> 6;
    float* wl = lds[wid];

    bf16x8 wfh[2][4], wfl[2][4];
#pragma unroll
    for (int kk = 0; kk < 2; kk++)
#pragma unroll
        for (int ct = 0; ct < 4; ct++) {
            float wv[8];
#pragma unroll
            for (int j = 0; j < 8; j++)
                wv[j] = W[(kk * 32 + quad * 8 + j) * 64 + ct * 16 + m];
            split8r(wv, wfh[kk][ct], wfl[kk][ct]);
        }

    float bv[4];
#pragma unroll
    for (int ct = 0; ct < 4; ct++) bv[ct] = bias[ct * 16 + m];

    float sc[2][8], sh[2][8];
#pragma unroll
    for (int kk = 0; kk < 2; kk++)
#pragma unroll
        for (int j = 0; j < 8; j++) {
            int c = kk * 32 + quad * 8 + j;
            float s = fin3[64 + c] * g2[c];
            sc[kk][j] = s;
            sh[kk][j] = be2[c] - fin3[c] * s;
        }

    double ssum[4] = {0,0,0,0}, ssq[4] = {0,0,0,0};

    for (int tile = gwave; tile < NT_N; tile += nwaves) {
        const int r = (tile << 4) + m;
        bf16x8 ah[2], al[2];
#pragma unroll
        for (int kk = 0; kk < 2; kk++) {
            f32x4 v0 = *reinterpret_cast<const f32x4*>(tpre + (size_t)r * 64 + kk * 32 + quad * 8);
            f32x4 v1 = *reinterpret_cast<const f32x4*>(tpre + (size_t)r * 64 + kk * 32 + quad * 8 + 4);
            float tv[8];
#pragma unroll
            for (int j = 0; j < 4; j++) {
                tv[j]     = fmaxf(v0[j] * sc[kk][j]     + sh[kk][j],     0.f);
                tv[4 + j] = fmaxf(v1[j] * sc[kk][4 + j] + sh[kk][4 + j], 0.f);
            }
            split8r(tv, ah[kk], al[kk]);
        }

        f32x4 zero = {0.f, 0.f, 0.f, 0.f};
        f32x4 acc[4];
#pragma unroll
        for (int ct = 0; ct < 4; ct++) {
            acc[ct] = zero;
#pragma unroll
            for (int kk = 0; kk < 2; kk++) {
                acc[ct] = __builtin_amdgcn_mfma_f32_16x16x32_bf16(al[kk], wfh[kk][ct], acc[ct], 0, 0, 0);
                acc[ct] = __builtin_amdgcn_mfma_f32_16x16x32_bf16(ah[kk], wfl[kk][ct], acc[ct], 0, 0, 0);
                acc[ct] = __builtin_amdgcn_mfma_f32_16x16x32_bf16(ah[kk], wfh[kk][ct], acc[ct], 0, 0, 0);
            }
        }

        epi_tile<true, true>(wl, lane, acc, bv, outp, tile, ssum, ssq);
    }

#pragma unroll
    for (int ct = 0; ct < 4; ct++) {
        double sv = ssum[ct], qv = ssq[ct];
        sv += __shfl_xor(sv, 16, 64); sv += __shfl_xor(sv, 32, 64);
        qv += __shfl_xor(qv, 16, 64); qv += __shfl_xor(qv, 32, 64);
        if (quad == 0) {
            atomAddD(&stats_raw[ct * 16 + m], sv);
            atomAddD(&stats_raw[64 + ct * 16 + m], qv);
        }
    }
}

// out = relu(bn(out_pre; stats4, g3, be3)) -> f32
__global__ void k_out(const float* __restrict__ op, const float* __restrict__ fin,
                      const float* __restrict__ g, const float* __restrict__ be,
                      float* __restrict__ out) {
    int i = blockIdx.x * 256 + threadIdx.x;   // covers NN*64 exactly
    int c = i & 63;
    out[i] = fmaxf((op[i] - fin[c]) * fin[64 + c] * g[c] + be[c], 0.f);
}

extern "C" void kernel_launch(void* const* d_in, const int* in_sizes, int n_in,
                              void* d_out, int out_size, void* d_ws, size_t ws_size,
                              hipStream_t stream) {
    const float* x    = (const float*)d_in[0];
    const int*   ei   = (const int*)d_in[1];
    const float* W_un = (const float*)d_in[2];
    const float* b_un = (const float*)d_in[3];
    const float* g1   = (const float*)d_in[4];
    const float* be1  = (const float*)d_in[5];
    const float* W_gc = (const float*)d_in[6];
    const float* b_gc = (const float*)d_in[7];
    const float* g2   = (const float*)d_in[8];
    const float* be2  = (const float*)d_in[9];
    const float* W_tr = (const float*)d_in[10];
    const float* b_tr = (const float*)d_in[11];
    const float* W_li = (const float*)d_in[12];
    const float* b_li = (const float*)d_in[13];
    const float* g3   = (const float*)d_in[14];
    const float* be3  = (const float*)d_in[15];

    float* ws = (float*)d_ws;
    const size_t FN = (size_t)NN * 64;           // 3.2M floats (12.8 MB)
    const size_t FR = (size_t)RR * 64;           // 54.4M floats (217.6 MB)
    // Region plan (lifetime-packed, no net growth vs previous layout except pdst):
    //  P0: u -> msg/mb' -> (dead after k_mm3)
    //  P1: v -> sA -> tpre
    //  P2: s_tab -> agg -> outpre
    //  H (FR floats): dsum(H), u2(H+FN) [both dead before k_s1ph] -> h2a(H, full FR)
    float* P0 = ws;
    float* P1 = ws + FN;
    float* P2 = ws + 2 * FN;
    float* H  = ws + 3 * FN;
    float* u      = P0;
    float* v      = P1;
    float* s_tab  = P2;
    float* dsum   = H;
    float* u2     = H + FN;
    float* h2a    = H;
    float* msg    = P0;           // becomes mb' = msg@Wb2 + b_gc (in place)
    float* sA     = P1;           // s_tab @ Wtop2
    float* agg    = P2;
    float* tpre   = P1;
    float* outpre = P2;
    double*         stats_raw = (double*)(H + FR);
    int*            od        = (int*)(stats_raw + 512);
    int*            id        = od + NN;
    int*            off       = id + NN;
    int*            cursor    = off + NN + 1;
    int*            off_s     = cursor + NN;
    int*            cursor_s  = off_s + NN + 1;
    unsigned int*   sd_s      = (unsigned int*)(cursor_s + NN);   // packed src|dst<<16, dst-sorted
    int*            perm_s    = (int*)(sd_s + EE);
    unsigned short* pdst      = (unsigned short*)(perm_s + EE);   // dst of src-CSR slot (fits u16)
    float*          stats_fin = (float*)(pdst + EE);

    // zero: stats_raw + od + id (contiguous)
    hipMemsetAsync(stats_raw, 0, 512 * sizeof(double) + 2 * NN * sizeof(int), stream);

    // build dst-sorted packed edge list + src-CSR permutation (+ permuted dst)
    k_deg  <<<3125, 256,  0, stream>>>(ei, od, id);
    k_scan2<<<2,    1024, 0, stream>>>(id, off, cursor, od, off_s, cursor_s);
    k_fill <<<3125, 256,  0, stream>>>(ei, cursor, sd_s);
    k_fill2<<<3125, 256,  0, stream>>>(sd_s, cursor_s, perm_s, pdst);

    // stage 0 + per-node tables
    k_dsum_csr<<<12500, 256, 0, stream>>>(x, off, sd_s, dsum);
    k_uv3<<<512, 256, 0, stream>>>(x, dsum, W_un, u, v, u2);

    // stage-1: analytic stats
    k_stats1a<<<256, 256, 0, stream>>>(u, v, u2, od, id, stats_raw + 0);
    k_fin1<<<1, 64, 0, stream>>>(stats_raw + 0, b_un, stats_fin + 0, 1.0 / (double)RR);

    // FUSED stage-1 reduce + stage-2 matmul: s_tab, h2a (=a rows, no mb), Sa/Sa2
    k_s1ph<<<12500, 256, 0, stream>>>(u, v, off, sd_s, b_un, stats_fin + 0, g1, be1,
                                      W_gc, s_tab, h2a, stats_raw + 128);

    // msg -> mb' (=msg@Wb2 + b_gc, in place), sA = s_tab@Wtop2, analytic stage-2 stats
    k_msg_csr<<<12500, 256, 0, stream>>>(off, sd_s, s_tab, msg);
    k_nmm<<<512, 256, 0, stream>>>(msg, W_gc + 64 * 64, b_gc, msg);
    k_nmm<<<512, 256, 0, stream>>>(s_tab, W_gc, nullptr, sA);
    k_stats2a<<<256, 256, 0, stream>>>(msg, sA, id, stats_raw + 128);
    k_fin<<<1, 64, 0, stream>>>(stats_raw + 128, stats_fin + 128, 1.0 / (double)RR);

    // src-CSR aggregate (adds mb'[dst] per edge row)
    k_agg2<<<12500, 256, 0, stream>>>(h2a, msg, off_s, perm_s, pdst,
                                      stats_fin + 128, g2, be2, agg);

    // stage 3
    k_mm3<<<512, 256, 0, stream>>>(h2a, msg, agg, W_tr, b_tr, stats_fin + 128, g2, be2,
                                   tpre, stats_raw + 256);
    k_fin<<<1, 64, 0, stream>>>(stats_raw + 256, stats_fin + 256, 1.0 / (double)NN);

    // stage 4
    k_mm4<<<512, 256, 0, stream>>>(tpre, W_li, b_li, stats_fin + 256, g2, be2,
                                   outpre, stats_raw + 384);
    k_fin<<<1, 64, 0, stream>>>(stats_raw + 384, stats_fin + 384, 1.0 / (double)NN);

    k_out<<<12500, 256, 0, stream>>>(outpre, stats_fin + 384, g3, be3, (float*)d_out);
}

// Round 3
// 1026.544 us; speedup vs baseline: 1.8119x; 1.8119x over previous
//
#include <hip/hip_runtime.h>
#include <cstdint>
#include <math.h>

// Problem sizes (fixed by the reference).
#define NN 50000
#define EE 800000
#define RR 850000      // NN + EE rows
#define NT_N 3125      // NN/16
#define NT_R 53125     // RR/16

typedef short  bf16x8 __attribute__((ext_vector_type(8)));
typedef float  f32x4  __attribute__((ext_vector_type(4)));

__device__ __forceinline__ float bf2f(unsigned short b) {
    unsigned int u = ((unsigned int)b) << 16;
    return __builtin_bit_cast(float, u);
}
__device__ __forceinline__ unsigned short f2bf(float f) {
    unsigned int u = __builtin_bit_cast(unsigned int, f);
    u = u + 0x7fffu + ((u >> 16) & 1u);
    return (unsigned short)(u >> 16);
}
__device__ __forceinline__ void atomAddF(float* p, float v) { unsafeAtomicAdd(p, v); }
__device__ __forceinline__ void atomAddD(double* p, double v) { unsafeAtomicAdd(p, v); }
__device__ __forceinline__ int atomAddI(int* p, int v) { return atomicAdd(p, v); }

// split 8 consecutive f32 into hi/lo bf16 fragments: hi+lo == v to ~2^-16 rel
__device__ __forceinline__ void split8(const float* p, bf16x8& hi, bf16x8& lo) {
    f32x4 v0 = *reinterpret_cast<const f32x4*>(p);
    f32x4 v1 = *reinterpret_cast<const f32x4*>(p + 4);
#pragma unroll
    for (int j = 0; j < 4; j++) {
        unsigned short h0 = f2bf(v0[j]);
        hi[j] = (short)h0; lo[j] = (short)f2bf(v0[j] - bf2f(h0));
        unsigned short h1 = f2bf(v1[j]);
        hi[4 + j] = (short)h1; lo[4 + j] = (short)f2bf(v1[j] - bf2f(h1));
    }
}
__device__ __forceinline__ void split8r(const float* v, bf16x8& hi, bf16x8& lo) {
#pragma unroll
    for (int j = 0; j < 8; j++) {
        unsigned short h = f2bf(v[j]);
        hi[j] = (short)h; lo[j] = (short)f2bf(v[j] - bf2f(h));
    }
}

// LDS-staged coalesced tile store: MFMA C-layout -> 4x 1KB contiguous dwordx4 stores.
template <bool RELU, bool STATS>
__device__ __forceinline__ void epi_tile(float* wl, int lane, const f32x4* acc,
                                         const float* bv, float* __restrict__ gout,
                                         int tile, double* ssum, double* ssq) {
    const int m = lane & 15, quad = lane >> 4;
#pragma unroll
    for (int ct = 0; ct < 4; ct++)
#pragma unroll
        for (int i = 0; i < 4; i++) {
            float val = acc[ct][i] + bv[ct];
            if (RELU) val = fmaxf(val, 0.f);
            wl[(quad * 4 + i) * 68 + ct * 16 + m] = val;
            if (STATS) { ssum[ct] += (double)val; ssq[ct] += (double)val * (double)val; }
        }
    asm volatile("s_waitcnt lgkmcnt(0)" ::: "memory");
#pragma unroll
    for (int j = 0; j < 4; j++) {
        int row = j * 4 + quad;
        f32x4 vv = *reinterpret_cast<const f32x4*>(wl + row * 68 + m * 4);
        *reinterpret_cast<f32x4*>(gout + ((size_t)(tile << 4) + row) * 64 + m * 4) = vv;
    }
}

// ---------- degree counts ----------
__global__ void k_deg(const int* __restrict__ ei, int* __restrict__ od, int* __restrict__ id) {
    int e = blockIdx.x * 256 + threadIdx.x;   // covers EE exactly
    atomAddI(&od[ei[e]], 1);
    atomAddI(&id[ei[EE + e]], 1);
}

// ---------- dual exclusive scan (block 0: dst-CSR, block 1: src-CSR) ----------
__global__ void __launch_bounds__(1024) k_scan2(const int* __restrict__ id, int* __restrict__ off,
                                                int* __restrict__ cursor,
                                                const int* __restrict__ od, int* __restrict__ off_s,
                                                int* __restrict__ cursor_s) {
    const int* cnt = (blockIdx.x == 0) ? id : od;
    int* o  = (blockIdx.x == 0) ? off : off_s;
    int* cu = (blockIdx.x == 0) ? cursor : cursor_s;
    __shared__ int part[1024];
    const int t = threadIdx.x;
    const int CH = (NN + 1023) / 1024;
    int base = t * CH, s = 0;
    for (int i = 0; i < CH; i++) { int idx = base + i; if (idx < NN) s += cnt[idx]; }
    part[t] = s;
    __syncthreads();
    if (t == 0) {
        int run = 0;
        for (int i = 0; i < 1024; i++) { int x = part[i]; part[i] = run; run += x; }
    }
    __syncthreads();
    int run = part[t];
    for (int i = 0; i < CH; i++) {
        int idx = base + i;
        if (idx < NN) { o[idx] = run; cu[idx] = run; run += cnt[idx]; }
    }
    if (t == 0) o[NN] = EE;
}

// ---------- fill dst-sorted packed edge array: sd = src | (dst<<16) ----------
__global__ void k_fill(const int* __restrict__ ei, int* __restrict__ cursor,
                       unsigned int* __restrict__ sd_s) {
    int e = blockIdx.x * 256 + threadIdx.x;   // covers EE exactly
    int s = ei[e], d = ei[EE + e];
    int p = atomAddI(&cursor[d], 1);
    sd_s[p] = (unsigned int)s | ((unsigned int)d << 16);
}

// ---------- fill src-CSR permutation: perm_s[q] = dst-order position p ----------
__global__ void k_fill2(const unsigned int* __restrict__ sd_s, int* __restrict__ cursor_s,
                        int* __restrict__ perm_s) {
    int p = blockIdx.x * 256 + threadIdx.x;   // covers EE exactly
    int s = (int)(sd_s[p] & 0xFFFFu);
    int q = atomAddI(&cursor_s[s], 1);
    perm_s[q] = p;
}

// ---------- dsum[n] = x[n] + sum_{e: dst=n} x[src_e]  (CSR, no atomics, 16-way MLP) ----------
__global__ void k_dsum_csr(const float* __restrict__ x, const int* __restrict__ off,
                           const unsigned int* __restrict__ sd_s, float* __restrict__ dsum) {
    int team = (blockIdx.x * 256 + threadIdx.x) >> 6;   // 12500 blocks x 4 = NN
    int c = threadIdx.x & 63;
    float a[16];
#pragma unroll
    for (int j = 0; j < 16; j++) a[j] = 0.f;
    a[0] = x[(size_t)team * 64 + c];
    int e = off[team], e1 = off[team + 1];
    for (; e + 15 < e1; e += 16)
#pragma unroll
        for (int j = 0; j < 16; j++) a[j] += x[(size_t)(sd_s[e + j] & 0xFFFFu) * 64 + c];
    for (; e + 3 < e1; e += 4)
#pragma unroll
        for (int j = 0; j < 4; j++) a[j] += x[(size_t)(sd_s[e + j] & 0xFFFFu) * 64 + c];
    for (; e < e1; e++) a[0] += x[(size_t)(sd_s[e] & 0xFFFFu) * 64 + c];
#pragma unroll
    for (int j = 0; j < 8; j++) a[j] += a[j + 8];
#pragma unroll
    for (int j = 0; j < 4; j++) a[j] += a[j + 4];
    dsum[(size_t)team * 64 + c] = (a[0] + a[1]) + (a[2] + a[3]);
}

// ---------- u = x@W_top, v = dsum@W_bot, u2 = dsum@W_top ----------
__global__ void k_uv3(const float* __restrict__ x, const float* __restrict__ dsum,
                      const float* __restrict__ W, float* __restrict__ u,
                      float* __restrict__ v, float* __restrict__ u2) {
    __shared__ float lds[4][16 * 68];
    const int lane = threadIdx.x & 63;
    const int wid = threadIdx.x >> 6;
    const int m = lane & 15, quad = lane >> 4;
    const int gwave = (blockIdx.x * blockDim.x + threadIdx.x) >> 6;
    const int nwaves = (gridDim.x * blockDim.x) >> 6;
    float* wl = lds[wid];

    bf16x8 wfh[4][4], wfl[4][4];
#pragma unroll
    for (int kk = 0; kk < 4; kk++)
#pragma unroll
        for (int ct = 0; ct < 4; ct++) {
            float wv[8];
#pragma unroll
            for (int j = 0; j < 8; j++)
                wv[j] = W[(kk * 32 + quad * 8 + j) * 64 + ct * 16 + m];
            split8r(wv, wfh[kk][ct], wfl[kk][ct]);
        }
    float zb[4] = {0.f, 0.f, 0.f, 0.f};

    for (int tile = gwave; tile < NT_N; tile += nwaves) {
        const int r = (tile << 4) + m;
        bf16x8 ah[4], al[4];
        split8(x    + (size_t)r * 64 + quad * 8,      ah[0], al[0]);
        split8(x    + (size_t)r * 64 + 32 + quad * 8, ah[1], al[1]);
        split8(dsum + (size_t)r * 64 + quad * 8,      ah[2], al[2]);
        split8(dsum + (size_t)r * 64 + 32 + quad * 8, ah[3], al[3]);

        f32x4 zero = {0.f, 0.f, 0.f, 0.f};
        f32x4 aU[4], aV[4], aU2[4];
#pragma unroll
        for (int ct = 0; ct < 4; ct++) {
            aU[ct] = zero; aV[ct] = zero; aU2[ct] = zero;
#pragma unroll
            for (int kk = 0; kk < 2; kk++) {
                aU[ct]  = __builtin_amdgcn_mfma_f32_16x16x32_bf16(al[kk],   wfh[kk][ct],   aU[ct],  0, 0, 0);
                aU[ct]  = __builtin_amdgcn_mfma_f32_16x16x32_bf16(ah[kk],   wfl[kk][ct],   aU[ct],  0, 0, 0);
                aU[ct]  = __builtin_amdgcn_mfma_f32_16x16x32_bf16(ah[kk],   wfh[kk][ct],   aU[ct],  0, 0, 0);
                aV[ct]  = __builtin_amdgcn_mfma_f32_16x16x32_bf16(al[kk+2], wfh[kk+2][ct], aV[ct],  0, 0, 0);
                aV[ct]  = __builtin_amdgcn_mfma_f32_16x16x32_bf16(ah[kk+2], wfl[kk+2][ct], aV[ct],  0, 0, 0);
                aV[ct]  = __builtin_amdgcn_mfma_f32_16x16x32_bf16(ah[kk+2], wfh[kk+2][ct], aV[ct],  0, 0, 0);
                aU2[ct] = __builtin_amdgcn_mfma_f32_16x16x32_bf16(al[kk+2], wfh[kk][ct],   aU2[ct], 0, 0, 0);
                aU2[ct] = __builtin_amdgcn_mfma_f32_16x16x32_bf16(ah[kk+2], wfl[kk][ct],   aU2[ct], 0, 0, 0);
                aU2[ct] = __builtin_amdgcn_mfma_f32_16x16x32_bf16(ah[kk+2], wfh[kk][ct],   aU2[ct], 0, 0, 0);
            }
        }
        epi_tile<false, false>(wl, lane, aU,  zb, u,  tile, nullptr, nullptr);
        epi_tile<false, false>(wl, lane, aV,  zb, v,  tile, nullptr, nullptr);
        epi_tile<false, false>(wl, lane, aU2, zb, u2, tile, nullptr, nullptr);
    }
}

// ---------- analytic stage-1 stats ----------
__global__ void k_stats1a(const float* __restrict__ u, const float* __restrict__ v,
                          const float* __restrict__ u2, const int* __restrict__ od,
                          const int* __restrict__ id, double* __restrict__ stats_raw) {
    __shared__ double lsum[4][64], lsq[4][64];
    int tid = threadIdx.x, c = tid & 63, w = tid >> 6;
    double a1 = 0.0, a2 = 0.0;
    for (int n = blockIdx.x * 4 + w; n < NN; n += gridDim.x * 4) {
        double uu = u[(size_t)n * 64 + c], vv = v[(size_t)n * 64 + c];
        double uu2 = u2[(size_t)n * 64 + c];
        double wod = 1.0 + od[n], wid = 1.0 + id[n];
        a1 += wod * uu + wid * vv;
        a2 += wod * uu * uu + wid * vv * vv + 2.0 * vv * uu2;
    }
    lsum[w][c] = a1; lsq[w][c] = a2;
    __syncthreads();
    if (w == 0) {
        a1 = lsum[0][c] + lsum[1][c] + lsum[2][c] + lsum[3][c];
        a2 = lsq[0][c] + lsq[1][c] + lsq[2][c] + lsq[3][c];
        atomAddD(&stats_raw[c], a1);
        atomAddD(&stats_raw[64 + c], a2);
    }
}

__global__ void k_fin1(const double* __restrict__ raw, const float* __restrict__ b,
                       float* __restrict__ fin, double inv_cnt) {
    int c = threadIdx.x;
    double m1 = raw[c] * inv_cnt;
    double var = raw[64 + c] * inv_cnt - m1 * m1;
    if (var < 0.0) var = 0.0;
    fin[c] = (float)(m1 + (double)b[c]);
    fin[64 + c] = (float)(1.0 / sqrt(var + 1e-5));
}

__global__ void k_fin(const double* __restrict__ raw, float* __restrict__ fin, double inv_cnt) {
    int c = threadIdx.x;
    double mean = raw[c] * inv_cnt;
    double var = raw[64 + c] * inv_cnt - mean * mean;
    if (var < 0.0) var = 0.0;
    fin[c] = (float)mean;
    fin[64 + c] = (float)(1.0 / sqrt(var + 1e-5));
}

// ---------- stage-1 reduce + per-row h store (16-way MLP gather preserved) ----------
// h = relu(bn1(u[src]+v[dst])) per row; s_tab[d] = sum over domain rows of h;
// hrows[row] = h  (row layout: [0..NN) self rows, [NN..RR) dst-sorted edge rows).
__global__ void k_s1h(const float* __restrict__ u, const float* __restrict__ v,
                      const int* __restrict__ off, const unsigned int* __restrict__ sd_s,
                      const float* __restrict__ b_un, const float* __restrict__ fin,
                      const float* __restrict__ g1, const float* __restrict__ be1,
                      float* __restrict__ s_tab, float* __restrict__ hrows) {
    int team = (blockIdx.x * 256 + threadIdx.x) >> 6;
    int c = threadIdx.x & 63;
    float sc = fin[64 + c] * g1[c];
    float tsh = (b_un[c] - fin[c]) * sc + be1[c];
    float vn = v[(size_t)team * 64 + c];
    float a[16];
#pragma unroll
    for (int j = 0; j < 16; j++) a[j] = 0.f;
    float hs = fmaxf((u[(size_t)team * 64 + c] + vn) * sc + tsh, 0.f);   // self row
    a[0] = hs;
    hrows[(size_t)team * 64 + c] = hs;
    int e = off[team], e1 = off[team + 1];
    for (; e + 15 < e1; e += 16)
#pragma unroll
        for (int j = 0; j < 16; j++) {
            float h = fmaxf((u[(size_t)(sd_s[e + j] & 0xFFFFu) * 64 + c] + vn) * sc + tsh, 0.f);
            a[j] += h;
            hrows[(size_t)(NN + e + j) * 64 + c] = h;
        }
    for (; e + 3 < e1; e += 4)
#pragma unroll
        for (int j = 0; j < 4; j++) {
            float h = fmaxf((u[(size_t)(sd_s[e + j] & 0xFFFFu) * 64 + c] + vn) * sc + tsh, 0.f);
            a[j] += h;
            hrows[(size_t)(NN + e + j) * 64 + c] = h;
        }
    for (; e < e1; e++) {
        float h = fmaxf((u[(size_t)(sd_s[e] & 0xFFFFu) * 64 + c] + vn) * sc + tsh, 0.f);
        a[0] += h;
        hrows[(size_t)(NN + e) * 64 + c] = h;
    }
#pragma unroll
    for (int j = 0; j < 8; j++) a[j] += a[j + 8];
#pragma unroll
    for (int j = 0; j < 4; j++) a[j] += a[j + 4];
    s_tab[(size_t)team * 64 + c] = (a[0] + a[1]) + (a[2] + a[3]);
}

// ---------- msg[n] = sum_{e:dst=n} s_tab[src_e] ----------
__global__ void k_msg_csr(const int* __restrict__ off, const unsigned int* __restrict__ sd_s,
                          const float* __restrict__ s_tab, float* __restrict__ msg) {
    int team = (blockIdx.x * 256 + threadIdx.x) >> 6;
    int c = threadIdx.x & 63;
    float a[16];
#pragma unroll
    for (int j = 0; j < 16; j++) a[j] = 0.f;
    int e = off[team], e1 = off[team + 1];
    for (; e + 15 < e1; e += 16)
#pragma unroll
        for (int j = 0; j < 16; j++) a[j] += s_tab[(size_t)(sd_s[e + j] & 0xFFFFu) * 64 + c];
    for (; e + 3 < e1; e += 4)
#pragma unroll
        for (int j = 0; j < 4; j++) a[j] += s_tab[(size_t)(sd_s[e + j] & 0xFFFFu) * 64 + c];
    for (; e < e1; e++) a[0] += s_tab[(size_t)(sd_s[e] & 0xFFFFu) * 64 + c];
#pragma unroll
    for (int j = 0; j < 8; j++) a[j] += a[j + 8];
#pragma unroll
    for (int j = 0; j < 4; j++) a[j] += a[j + 4];
    msg[(size_t)team * 64 + c] = (a[0] + a[1]) + (a[2] + a[3]);
}

// ---------- mb = msg @ W_gc[64:128]  (streaming; in/out may differ) ----------
__global__ void k_mb(const float* __restrict__ in, float* __restrict__ outp,
                     const float* __restrict__ W) {
    __shared__ float lds[4][16 * 68];
    const int lane = threadIdx.x & 63;
    const int wid = threadIdx.x >> 6;
    const int m = lane & 15, quad = lane >> 4;
    const int gwave = (blockIdx.x * blockDim.x + threadIdx.x) >> 6;
    const int nwaves = (gridDim.x * blockDim.x) >> 6;
    float* wl = lds[wid];

    bf16x8 wfh[2][4], wfl[2][4];
#pragma unroll
    for (int kk = 0; kk < 2; kk++)
#pragma unroll
        for (int ct = 0; ct < 4; ct++) {
            float wv[8];
#pragma unroll
            for (int j = 0; j < 8; j++)
                wv[j] = W[(kk * 32 + quad * 8 + j) * 64 + ct * 16 + m];
            split8r(wv, wfh[kk][ct], wfl[kk][ct]);
        }
    float zb[4] = {0.f, 0.f, 0.f, 0.f};

    for (int tile = gwave; tile < NT_N; tile += nwaves) {
        const int r = (tile << 4) + m;
        bf16x8 ah[2], al[2];
        split8(in + (size_t)r * 64 + quad * 8,      ah[0], al[0]);
        split8(in + (size_t)r * 64 + 32 + quad * 8, ah[1], al[1]);

        f32x4 zero = {0.f, 0.f, 0.f, 0.f};
        f32x4 acc[4];
#pragma unroll
        for (int ct = 0; ct < 4; ct++) {
            acc[ct] = zero;
#pragma unroll
            for (int kk = 0; kk < 2; kk++) {
                acc[ct] = __builtin_amdgcn_mfma_f32_16x16x32_bf16(al[kk], wfh[kk][ct], acc[ct], 0, 0, 0);
                acc[ct] = __builtin_amdgcn_mfma_f32_16x16x32_bf16(ah[kk], wfl[kk][ct], acc[ct], 0, 0, 0);
                acc[ct] = __builtin_amdgcn_mfma_f32_16x16x32_bf16(ah[kk], wfh[kk][ct], acc[ct], 0, 0, 0);
            }
        }
        epi_tile<false, false>(wl, lane, acc, zb, outp, tile, nullptr, nullptr);
    }
}

// ---------- stage-2 streaming matmul (replaces k_ph0's random gather):
// h2pre[r] = hrows[r] @ Wtop2 + mb[dst(r)] + b_gc, IN PLACE over hrows; + stage-2 stats.
__global__ void k_h2(float* __restrict__ hr, const float* __restrict__ mb,
                     const unsigned int* __restrict__ sd_s,
                     const float* __restrict__ W, const float* __restrict__ b_gc,
                     double* __restrict__ stats_raw) {
    __shared__ float lds[4][16 * 68];
    const int lane = threadIdx.x & 63;
    const int wid = threadIdx.x >> 6;
    const int m = lane & 15, quad = lane >> 4;
    const int gwave = (blockIdx.x * blockDim.x + threadIdx.x) >> 6;
    const int nwaves = (gridDim.x * blockDim.x) >> 6;
    float* wl = lds[wid];

    bf16x8 wfh[2][4], wfl[2][4];
#pragma unroll
    for (int kk = 0; kk < 2; kk++)
#pragma unroll
        for (int ct = 0; ct < 4; ct++) {
            float wv[8];
#pragma unroll
            for (int j = 0; j < 8; j++)
                wv[j] = W[(kk * 32 + quad * 8 + j) * 64 + ct * 16 + m];
            split8r(wv, wfh[kk][ct], wfl[kk][ct]);
        }

    float bv[4];
#pragma unroll
    for (int ct = 0; ct < 4; ct++) bv[ct] = b_gc[ct * 16 + m];

    double ssum[4] = {0,0,0,0}, ssq[4] = {0,0,0,0};

    for (int tile = gwave; tile < NT_R; tile += nwaves) {
        const int r = (tile << 4) + m;
        int dm = (tile < NT_N) ? r : (int)(sd_s[r - NN] >> 16);

        bf16x8 ah[2], al[2];
        split8(hr + (size_t)r * 64 + quad * 8,      ah[0], al[0]);
        split8(hr + (size_t)r * 64 + 32 + quad * 8, ah[1], al[1]);

        f32x4 zero = {0.f, 0.f, 0.f, 0.f};
        f32x4 acc[4];
#pragma unroll
        for (int ct = 0; ct < 4; ct++) {
            acc[ct] = zero;
#pragma unroll
            for (int kk = 0; kk < 2; kk++) {
                acc[ct] = __builtin_amdgcn_mfma_f32_16x16x32_bf16(al[kk], wfh[kk][ct], acc[ct], 0, 0, 0);
                acc[ct] = __builtin_amdgcn_mfma_f32_16x16x32_bf16(ah[kk], wfl[kk][ct], acc[ct], 0, 0, 0);
                acc[ct] = __builtin_amdgcn_mfma_f32_16x16x32_bf16(ah[kk], wfh[kk][ct], acc[ct], 0, 0, 0);
            }
        }

        // add mb[dst_of_row] + b_gc per element, then stats + LDS-coalesced in-place store
#pragma unroll
        for (int i = 0; i < 4; i++) {
            int dmv = __shfl(dm, (lane & 48) + quad * 4 + i, 64);   // dm of row quad*4+i
#pragma unroll
            for (int ct = 0; ct < 4; ct++) {
                float val = acc[ct][i] + bv[ct] + mb[(size_t)dmv * 64 + ct * 16 + m];
                wl[(quad * 4 + i) * 68 + ct * 16 + m] = val;
                ssum[ct] += (double)val;
                ssq[ct]  += (double)val * (double)val;
            }
        }
        asm volatile("s_waitcnt lgkmcnt(0)" ::: "memory");
#pragma unroll
        for (int j = 0; j < 4; j++) {
            int row = j * 4 + quad;
            f32x4 vv = *reinterpret_cast<const f32x4*>(wl + row * 68 + m * 4);
            *reinterpret_cast<f32x4*>(hr + ((size_t)(tile << 4) + row) * 64 + m * 4) = vv;
        }
    }

#pragma unroll
    for (int ct = 0; ct < 4; ct++) {
        double sv = ssum[ct], qv = ssq[ct];
        sv += __shfl_xor(sv, 16, 64); sv += __shfl_xor(sv, 32, 64);
        qv += __shfl_xor(qv, 16, 64); qv += __shfl_xor(qv, 32, 64);
        if (quad == 0) {
            atomAddD(&stats_raw[ct * 16 + m], sv);
            atomAddD(&stats_raw[64 + ct * 16 + m], qv);
        }
    }
}

// ---------- agg[n] = relu(bn2(h2pre[n])) + sum_{q in src-CSR} relu(bn2(h2pre[NN+perm_s[q]])) ----------
__global__ void k_agg_csr(const float* __restrict__ h2pre, const int* __restrict__ off_s,
                          const int* __restrict__ perm_s, const float* __restrict__ fin2,
                          const float* __restrict__ g2, const float* __restrict__ be2,
                          float* __restrict__ agg) {
    int n = (blockIdx.x * 256 + threadIdx.x) >> 6;
    int c = threadIdx.x & 63;
    float sc = fin2[64 + c] * g2[c];
    float sh = be2[c] - fin2[c] * sc;
    float a[16];
#pragma unroll
    for (int j = 0; j < 16; j++) a[j] = 0.f;
    a[0] = fmaxf(h2pre[(size_t)n * 64 + c] * sc + sh, 0.f);   // self row
    int q = off_s[n], q1 = off_s[n + 1];
    for (; q + 15 < q1; q += 16)
#pragma unroll
        for (int j = 0; j < 16; j++) {
            float hv = __builtin_nontemporal_load(
                h2pre + (size_t)(NN + perm_s[q + j]) * 64 + c);
            a[j] += fmaxf(hv * sc + sh, 0.f);
        }
    for (; q + 3 < q1; q += 4)
#pragma unroll
        for (int j = 0; j < 4; j++) {
            float hv = __builtin_nontemporal_load(
                h2pre + (size_t)(NN + perm_s[q + j]) * 64 + c);
            a[j] += fmaxf(hv * sc + sh, 0.f);
        }
    for (; q < q1; q++) {
        float hv = __builtin_nontemporal_load(h2pre + (size_t)(NN + perm_s[q]) * 64 + c);
        a[0] += fmaxf(hv * sc + sh, 0.f);
    }
#pragma unroll
    for (int j = 0; j < 8; j++) a[j] += a[j + 8];
#pragma unroll
    for (int j = 0; j < 4; j++) a[j] += a[j + 4];
    agg[(size_t)n * 64 + c] = (a[0] + a[1]) + (a[2] + a[3]);
}

// ---------- stage 3: t_pre = [relu(bn2(h2pre[:N])), agg] @ W_tr + b_tr, stats3 ----------
__global__ void k_mm3(const float* __restrict__ h2pre, const float* __restrict__ agg,
                      const float* __restrict__ W, const float* __restrict__ bias,
                      const float* __restrict__ fin2, const float* __restrict__ g2,
                      const float* __restrict__ be2,
                      float* __restrict__ outp, double* __restrict__ stats_raw) {
    __shared__ float lds[4][16 * 68];
    const int lane = threadIdx.x & 63;
    const int wid = threadIdx.x >> 6;
    const int m = lane & 15, quad = lane >> 4;
    const int gwave = (blockIdx.x * blockDim.x + threadIdx.x) >> 6;
    const int nwaves = (gridDim.x * blockDim.x) >> 6;
    float* wl = lds[wid];

    bf16x8 wfh[4][4], wfl[4][4];
#pragma unroll
    for (int kk = 0; kk < 4; kk++)
#pragma unroll
        for (int ct = 0; ct < 4; ct++) {
            float wv[8];
#pragma unroll
            for (int j = 0; j < 8; j++)
                wv[j] = W[(kk * 32 + quad * 8 + j) * 64 + ct * 16 + m];
            split8r(wv, wfh[kk][ct], wfl[kk][ct]);
        }

    float bv[4];
#pragma unroll
    for (int ct = 0; ct < 4; ct++) bv[ct] = bias[ct * 16 + m];

    float s2f[2][8], t2f[2][8];
#pragma unroll
    for (int kk = 0; kk < 2; kk++)
#pragma unroll
        for (int j = 0; j < 8; j++) {
            int c = kk * 32 + quad * 8 + j;
            float sc = fin2[64 + c] * g2[c];
            s2f[kk][j] = sc;
            t2f[kk][j] = be2[c] - fin2[c] * sc;
        }

    double ssum[4] = {0,0,0,0}, ssq[4] = {0,0,0,0};

    for (int tile = gwave; tile < NT_N; tile += nwaves) {
        const int r = (tile << 4) + m;
        bf16x8 ah[4], al[4];
#pragma unroll
        for (int kk = 0; kk < 2; kk++) {
            f32x4 v0 = __builtin_nontemporal_load(
                reinterpret_cast<const f32x4*>(h2pre + (size_t)r * 64 + kk * 32 + quad * 8));
            f32x4 v1 = __builtin_nontemporal_load(
                reinterpret_cast<const f32x4*>(h2pre + (size_t)r * 64 + kk * 32 + quad * 8 + 4));
            float tv[8];
#pragma unroll
            for (int j = 0; j < 4; j++) {
                tv[j]     = fmaxf(v0[j] * s2f[kk][j]     + t2f[kk][j],     0.f);
                tv[4 + j] = fmaxf(v1[j] * s2f[kk][4 + j] + t2f[kk][4 + j], 0.f);
            }
            split8r(tv, ah[kk], al[kk]);
        }
        split8(agg + (size_t)r * 64 + quad * 8,      ah[2], al[2]);
        split8(agg + (size_t)r * 64 + 32 + quad * 8, ah[3], al[3]);

        f32x4 zero = {0.f, 0.f, 0.f, 0.f};
        f32x4 acc[4];
#pragma unroll
        for (int ct = 0; ct < 4; ct++) {
            acc[ct] = zero;
#pragma unroll
            for (int kk = 0; kk < 4; kk++)
                acc[ct] = __builtin_amdgcn_mfma_f32_16x16x32_bf16(al[kk], wfh[kk][ct], acc[ct], 0, 0, 0);
#pragma unroll
            for (int kk = 0; kk < 4; kk++)
                acc[ct] = __builtin_amdgcn_mfma_f32_16x16x32_bf16(ah[kk], wfl[kk][ct], acc[ct], 0, 0, 0);
#pragma unroll
            for (int kk = 0; kk < 4; kk++)
                acc[ct] = __builtin_amdgcn_mfma_f32_16x16x32_bf16(ah[kk], wfh[kk][ct], acc[ct], 0, 0, 0);
        }

        epi_tile<false, true>(wl, lane, acc, bv, outp, tile, ssum, ssq);
    }

#pragma unroll
    for (int ct = 0; ct < 4; ct++) {
        double sv = ssum[ct], qv = ssq[ct];
        sv += __shfl_xor(sv, 16, 64); sv += __shfl_xor(sv, 32, 64);
        qv += __shfl_xor(qv, 16, 64); qv += __shfl_xor(qv, 32, 64);
        if (quad == 0) {
            atomAddD(&stats_raw[ct * 16 + m], sv);
            atomAddD(&stats_raw[64 + ct * 16 + m], qv);
        }
    }
}

// ---------- stage 4 ----------
__global__ void k_mm4(const float* __restrict__ tpre, const float* __restrict__ W,
                      const float* __restrict__ bias, const float* __restrict__ fin3,
                      const float* __restrict__ g2, const float* __restrict__ be2,
                      float* __restrict__ outp, double* __restrict__ stats_raw) {
    __shared__ float lds[4][16 * 68];
    const int lane = threadIdx.x & 63;
    const int wid = threadIdx.x >> 6;
    const int m = lane & 15, quad = lane >> 4;
    const int gwave = (blockIdx.x * blockDim.x + threadIdx.x) >> 6;
    const int nwaves = (gridDim.x * blockDim.x) >> 6;
    float* wl = lds[wid];

    bf16x8 wfh[2][4], wfl[2][4];
#pragma unroll
    for (int kk = 0; kk < 2; kk++)
#pragma unroll
        for (int ct = 0; ct < 4; ct++) {
            float wv[8];
#pragma unroll
            for (int j = 0; j < 8; j++)
                wv[j] = W[(kk * 32 + quad * 8 + j) * 64 + ct * 16 + m];
            split8r(wv, wfh[kk][ct], wfl[kk][ct]);
        }

    float bv[4];
#pragma unroll
    for (int ct = 0; ct < 4; ct++) bv[ct] = bias[ct * 16 + m];

    float sc[2][8], sh[2][8];
#pragma unroll
    for (int kk = 0; kk < 2; kk++)
#pragma unroll
        for (int j = 0; j < 8; j++) {
            int c = kk * 32 + quad * 8 + j;
            float s = fin3[64 + c] * g2[c];
            sc[kk][j] = s;
            sh[kk][j] = be2[c] - fin3[c] * s;
        }

    double ssum[4] = {0,0,0,0}, ssq[4] = {0,0,0,0};

    for (int tile = gwave; tile < NT_N; tile += nwaves) {
        const int r = (tile << 4) + m;
        bf16x8 ah[2], al[2];
#pragma unroll
        for (int kk = 0; kk < 2; kk++) {
            f32x4 v0 = *reinterpret_cast<const f32x4*>(tpre + (size_t)r * 64 + kk * 32 + quad * 8);
            f32x4 v1 = *reinterpret_cast<const f32x4*>(tpre + (size_t)r * 64 + kk * 32 + quad * 8 + 4);
            float tv[8];
#pragma unroll
            for (int j = 0; j < 4; j++) {
                tv[j]     = fmaxf(v0[j] * sc[kk][j]     + sh[kk][j],     0.f);
                tv[4 + j] = fmaxf(v1[j] * sc[kk][4 + j] + sh[kk][4 + j], 0.f);
            }
            split8r(tv, ah[kk], al[kk]);
        }

        f32x4 zero = {0.f, 0.f, 0.f, 0.f};
        f32x4 acc[4];
#pragma unroll
        for (int ct = 0; ct < 4; ct++) {
            acc[ct] = zero;
#pragma unroll
            for (int kk = 0; kk < 2; kk++) {
                acc[ct] = __builtin_amdgcn_mfma_f32_16x16x32_bf16(al[kk], wfh[kk][ct], acc[ct], 0, 0, 0);
                acc[ct] = __builtin_amdgcn_mfma_f32_16x16x32_bf16(ah[kk], wfl[kk][ct], acc[ct], 0, 0, 0);
                acc[ct] = __builtin_amdgcn_mfma_f32_16x16x32_bf16(ah[kk], wfh[kk][ct], acc[ct], 0, 0, 0);
            }
        }

        epi_tile<true, true>(wl, lane, acc, bv, outp, tile, ssum, ssq);
    }

#pragma unroll
    for (int ct = 0; ct < 4; ct++) {
        double sv = ssum[ct], qv = ssq[ct];
        sv += __shfl_xor(sv, 16, 64); sv += __shfl_xor(sv, 32, 64);
        qv += __shfl_xor(qv, 16, 64); qv += __shfl_xor(qv, 32, 64);
        if (quad == 0) {
            atomAddD(&stats_raw[ct * 16 + m], sv);
            atomAddD(&stats_raw[64 + ct * 16 + m], qv);
        }
    }
}

// out = relu(bn(out_pre; stats4, g3, be3)) -> f32
__global__ void k_out(const float* __restrict__ op, const float* __restrict__ fin,
                      const float* __restrict__ g, const float* __restrict__ be,
                      float* __restrict__ out) {
    int i = blockIdx.x * 256 + threadIdx.x;   // covers NN*64 exactly
    int c = i & 63;
    out[i] = fmaxf((op[i] - fin[c]) * fin[64 + c] * g[c] + be[c], 0.f);
}

extern "C" void kernel_launch(void* const* d_in, const int* in_sizes, int n_in,
                              void* d_out, int out_size, void* d_ws, size_t ws_size,
                              hipStream_t stream) {
    const float* x    = (const float*)d_in[0];
    const int*   ei   = (const int*)d_in[1];
    const float* W_un = (const float*)d_in[2];
    const float* b_un = (const float*)d_in[3];
    const float* g1   = (const float*)d_in[4];
    const float* be1  = (const float*)d_in[5];
    const float* W_gc = (const float*)d_in[6];
    const float* b_gc = (const float*)d_in[7];
    const float* g2   = (const float*)d_in[8];
    const float* be2  = (const float*)d_in[9];
    const float* W_tr = (const float*)d_in[10];
    const float* b_tr = (const float*)d_in[11];
    const float* W_li = (const float*)d_in[12];
    const float* b_li = (const float*)d_in[13];
    const float* g3   = (const float*)d_in[14];
    const float* be3  = (const float*)d_in[15];

    float* ws = (float*)d_ws;
    const size_t FN = (size_t)NN * 64;           // 3.2M floats (12.8 MB)
    const size_t FR = (size_t)RR * 64;           // 54.4M floats (217.6 MB)
    // Region plan (zero growth vs R0 footprint; lifetimes verified):
    //  P0: u  -> msg/mb (after k_s1h, u dead)  -> outpre (after k_h2, mb dead)
    //  P1: v  -> agg    (after k_s1h, v dead)
    //  P2: s_tab (written by k_s1h; dead after k_msg_csr) -> tpre
    //  H (FR): dsum(H), u2(H+FN) [dead after k_stats1a] -> hrows -> h2pre (in place)
    float* P0 = ws;
    float* P1 = ws + FN;
    float* P2 = ws + 2 * FN;
    float* H  = ws + 3 * FN;
    float* u      = P0;
    float* v      = P1;
    float* s_tab  = P2;
    float* dsum   = H;
    float* u2     = H + FN;
    float* hrows  = H;            // per-row h (f32), then h2pre in place
    float* h2pre  = H;
    float* msg    = P0;           // becomes mb after k_mb (in place)
    float* agg    = P1;
    float* tpre   = P2;
    float* outpre = P0;
    double*       stats_raw = (double*)(H + FR);
    int*          od        = (int*)(stats_raw + 512);
    int*          id        = od + NN;
    int*          off       = id + NN;
    int*          cursor    = off + NN + 1;
    int*          off_s     = cursor + NN;
    int*          cursor_s  = off_s + NN + 1;
    unsigned int* sd_s      = (unsigned int*)(cursor_s + NN);   // packed src|dst<<16, dst-sorted
    int*          perm_s    = (int*)(sd_s + EE);
    float*        stats_fin = (float*)(perm_s + EE);

    // zero: stats_raw + od + id (contiguous)
    hipMemsetAsync(stats_raw, 0, 512 * sizeof(double) + 2 * NN * sizeof(int), stream);

    // build dst-sorted packed edge list + src-CSR permutation
    k_deg  <<<3125, 256,  0, stream>>>(ei, od, id);
    k_scan2<<<2,    1024, 0, stream>>>(id, off, cursor, od, off_s, cursor_s);
    k_fill <<<3125, 256,  0, stream>>>(ei, cursor, sd_s);
    k_fill2<<<3125, 256,  0, stream>>>(sd_s, cursor_s, perm_s);

    // stage 0 + per-node tables
    k_dsum_csr<<<12500, 256, 0, stream>>>(x, off, sd_s, dsum);
    k_uv3<<<512, 256, 0, stream>>>(x, dsum, W_un, u, v, u2);

    // stage-1: analytic stats, then CSR reduce + per-row h store
    k_stats1a<<<256, 256, 0, stream>>>(u, v, u2, od, id, stats_raw + 0);
    k_fin1<<<1, 64, 0, stream>>>(stats_raw + 0, b_un, stats_fin + 0, 1.0 / (double)RR);
    k_s1h<<<12500, 256, 0, stream>>>(u, v, off, sd_s, b_un, stats_fin + 0, g1, be1,
                                     s_tab, hrows);
    k_msg_csr<<<12500, 256, 0, stream>>>(off, sd_s, s_tab, msg);
    k_mb<<<512, 256, 0, stream>>>(msg, msg, W_gc + 64 * 64);   // msg -> mb in place

    // stage-2: streaming matmul over materialized h rows (in place), stats
    k_h2<<<2048, 256, 0, stream>>>(hrows, msg, sd_s, W_gc, b_gc, stats_raw + 128);
    k_fin<<<1, 64, 0, stream>>>(stats_raw + 128, stats_fin + 128, 1.0 / (double)RR);
    k_agg_csr<<<12500, 256, 0, stream>>>(h2pre, off_s, perm_s, stats_fin + 128, g2, be2, agg);

    // stage 3
    k_mm3<<<512, 256, 0, stream>>>(h2pre, agg, W_tr, b_tr, stats_fin + 128, g2, be2,
                                   tpre, stats_raw + 256);
    k_fin<<<1, 64, 0, stream>>>(stats_raw + 256, stats_fin + 256, 1.0 / (double)NN);

    // stage 4
    k_mm4<<<512, 256, 0, stream>>>(tpre, W_li, b_li, stats_fin + 256, g2, be2,
                                   outpre, stats_raw + 384);
    k_fin<<<1, 64, 0, stream>>>(stats_raw + 384, stats_fin + 384, 1.0 / (double)NN);

    k_out<<<12500, 256, 0, stream>>>(outpre, stats_fin + 384, g3, be3, (float*)d_out);
}

// Round 5
// 987.927 us; speedup vs baseline: 1.8827x; 1.0391x over previous
//
#include <hip/hip_runtime.h>
#include <cstdint>
#include <math.h>

// Problem sizes (fixed by the reference).
#define NN 50000
#define EE 800000
#define RR 850000      // NN + EE rows
#define NT_N 3125      // NN/16
#define NT_R 53125     // RR/16

typedef short  bf16x8 __attribute__((ext_vector_type(8)));
typedef float  f32x4  __attribute__((ext_vector_type(4)));

__device__ __forceinline__ float bf2f(unsigned short b) {
    unsigned int u = ((unsigned int)b) << 16;
    return __builtin_bit_cast(float, u);
}
__device__ __forceinline__ unsigned short f2bf(float f) {
    unsigned int u = __builtin_bit_cast(unsigned int, f);
    u = u + 0x7fffu + ((u >> 16) & 1u);
    return (unsigned short)(u >> 16);
}
__device__ __forceinline__ void atomAddD(double* p, double v) { unsafeAtomicAdd(p, v); }
__device__ __forceinline__ int atomAddI(int* p, int v) { return atomicAdd(p, v); }

// split 8 consecutive f32 into hi/lo bf16 fragments: hi+lo == v to ~2^-16 rel
__device__ __forceinline__ void split8(const float* p, bf16x8& hi, bf16x8& lo) {
    f32x4 v0 = *reinterpret_cast<const f32x4*>(p);
    f32x4 v1 = *reinterpret_cast<const f32x4*>(p + 4);
#pragma unroll
    for (int j = 0; j < 4; j++) {
        unsigned short h0 = f2bf(v0[j]);
        hi[j] = (short)h0; lo[j] = (short)f2bf(v0[j] - bf2f(h0));
        unsigned short h1 = f2bf(v1[j]);
        hi[4 + j] = (short)h1; lo[4 + j] = (short)f2bf(v1[j] - bf2f(h1));
    }
}
__device__ __forceinline__ void split8r(const float* v, bf16x8& hi, bf16x8& lo) {
#pragma unroll
    for (int j = 0; j < 8; j++) {
        unsigned short h = f2bf(v[j]);
        hi[j] = (short)h; lo[j] = (short)f2bf(v[j] - bf2f(h));
    }
}

// LDS-staged coalesced tile store: MFMA C-layout -> 4x 1KB contiguous dwordx4 stores.
template <bool RELU, bool STATS>
__device__ __forceinline__ void epi_tile(float* wl, int lane, const f32x4* acc,
                                         const float* bv, float* __restrict__ gout,
                                         int tile, double* ssum, double* ssq) {
    const int m = lane & 15, quad = lane >> 4;
#pragma unroll
    for (int ct = 0; ct < 4; ct++)
#pragma unroll
        for (int i = 0; i < 4; i++) {
            float val = acc[ct][i] + bv[ct];
            if (RELU) val = fmaxf(val, 0.f);
            wl[(quad * 4 + i) * 68 + ct * 16 + m] = val;
            if (STATS) { ssum[ct] += (double)val; ssq[ct] += (double)val * (double)val; }
        }
    asm volatile("s_waitcnt lgkmcnt(0)" ::: "memory");
#pragma unroll
    for (int j = 0; j < 4; j++) {
        int row = j * 4 + quad;
        f32x4 vv = *reinterpret_cast<const f32x4*>(wl + row * 68 + m * 4);
        *reinterpret_cast<f32x4*>(gout + ((size_t)(tile << 4) + row) * 64 + m * 4) = vv;
    }
}

// ---------- degree counts ----------
__global__ void k_deg(const int* __restrict__ ei, int* __restrict__ od, int* __restrict__ id) {
    int e = blockIdx.x * 256 + threadIdx.x;   // covers EE exactly
    atomAddI(&od[ei[e]], 1);
    atomAddI(&id[ei[EE + e]], 1);
}

// ---------- dual exclusive scan (block 0: dst-CSR, block 1: src-CSR) ----------
__global__ void __launch_bounds__(1024) k_scan2(const int* __restrict__ id, int* __restrict__ off,
                                                int* __restrict__ cursor,
                                                const int* __restrict__ od, int* __restrict__ off_s,
                                                int* __restrict__ cursor_s) {
    const int* cnt = (blockIdx.x == 0) ? id : od;
    int* o  = (blockIdx.x == 0) ? off : off_s;
    int* cu = (blockIdx.x == 0) ? cursor : cursor_s;
    __shared__ int part[1024];
    const int t = threadIdx.x;
    const int CH = (NN + 1023) / 1024;
    int base = t * CH, s = 0;
    for (int i = 0; i < CH; i++) { int idx = base + i; if (idx < NN) s += cnt[idx]; }
    part[t] = s;
    __syncthreads();
    if (t == 0) {
        int run = 0;
        for (int i = 0; i < 1024; i++) { int x = part[i]; part[i] = run; run += x; }
    }
    __syncthreads();
    int run = part[t];
    for (int i = 0; i < CH; i++) {
        int idx = base + i;
        if (idx < NN) { o[idx] = run; cu[idx] = run; run += cnt[idx]; }
    }
    if (t == 0) o[NN] = EE;
}

// ---------- fill dst-sorted packed edge array: sd = src | (dst<<16) ----------
__global__ void k_fill(const int* __restrict__ ei, int* __restrict__ cursor,
                       unsigned int* __restrict__ sd_s) {
    int e = blockIdx.x * 256 + threadIdx.x;   // covers EE exactly
    int s = ei[e], d = ei[EE + e];
    int p = atomAddI(&cursor[d], 1);
    sd_s[p] = (unsigned int)s | ((unsigned int)d << 16);
}

// ---------- fill src-CSR permutation: perm_s[q] = dst-order position p ----------
__global__ void k_fill2(const unsigned int* __restrict__ sd_s, int* __restrict__ cursor_s,
                        int* __restrict__ perm_s) {
    int p = blockIdx.x * 256 + threadIdx.x;   // covers EE exactly
    int s = (int)(sd_s[p] & 0xFFFFu);
    int q = atomAddI(&cursor_s[s], 1);
    perm_s[q] = p;
}

// ---------- dsum[n] = x[n] + sum_{e: dst=n} x[src_e]  (CSR, no atomics, 16-way MLP) ----------
__global__ void k_dsum_csr(const float* __restrict__ x, const int* __restrict__ off,
                           const unsigned int* __restrict__ sd_s, float* __restrict__ dsum) {
    int team = (blockIdx.x * 256 + threadIdx.x) >> 6;   // 12500 blocks x 4 = NN
    int c = threadIdx.x & 63;
    float a[16];
#pragma unroll
    for (int j = 0; j < 16; j++) a[j] = 0.f;
    a[0] = x[(size_t)team * 64 + c];
    int e = off[team], e1 = off[team + 1];
    for (; e + 15 < e1; e += 16)
#pragma unroll
        for (int j = 0; j < 16; j++) a[j] += x[(size_t)(sd_s[e + j] & 0xFFFFu) * 64 + c];
    for (; e + 3 < e1; e += 4)
#pragma unroll
        for (int j = 0; j < 4; j++) a[j] += x[(size_t)(sd_s[e + j] & 0xFFFFu) * 64 + c];
    for (; e < e1; e++) a[0] += x[(size_t)(sd_s[e] & 0xFFFFu) * 64 + c];
#pragma unroll
    for (int j = 0; j < 8; j++) a[j] += a[j + 8];
#pragma unroll
    for (int j = 0; j < 4; j++) a[j] += a[j + 4];
    dsum[(size_t)team * 64 + c] = (a[0] + a[1]) + (a[2] + a[3]);
}

// ---------- u = x@W_top, v = dsum@W_bot, u2 = dsum@W_top ----------
__global__ void k_uv3(const float* __restrict__ x, const float* __restrict__ dsum,
                      const float* __restrict__ W, float* __restrict__ u,
                      float* __restrict__ v, float* __restrict__ u2) {
    __shared__ float lds[4][16 * 68];
    const int lane = threadIdx.x & 63;
    const int wid = threadIdx.x >> 6;
    const int m = lane & 15, quad = lane >> 4;
    const int gwave = (blockIdx.x * blockDim.x + threadIdx.x) >> 6;
    const int nwaves = (gridDim.x * blockDim.x) >> 6;
    float* wl = lds[wid];

    bf16x8 wfh[4][4], wfl[4][4];
#pragma unroll
    for (int kk = 0; kk < 4; kk++)
#pragma unroll
        for (int ct = 0; ct < 4; ct++) {
            float wv[8];
#pragma unroll
            for (int j = 0; j < 8; j++)
                wv[j] = W[(kk * 32 + quad * 8 + j) * 64 + ct * 16 + m];
            split8r(wv, wfh[kk][ct], wfl[kk][ct]);
        }
    float zb[4] = {0.f, 0.f, 0.f, 0.f};

    for (int tile = gwave; tile < NT_N; tile += nwaves) {
        const int r = (tile << 4) + m;
        bf16x8 ah[4], al[4];
        split8(x    + (size_t)r * 64 + quad * 8,      ah[0], al[0]);
        split8(x    + (size_t)r * 64 + 32 + quad * 8, ah[1], al[1]);
        split8(dsum + (size_t)r * 64 + quad * 8,      ah[2], al[2]);
        split8(dsum + (size_t)r * 64 + 32 + quad * 8, ah[3], al[3]);

        f32x4 zero = {0.f, 0.f, 0.f, 0.f};
        f32x4 aU[4], aV[4], aU2[4];
#pragma unroll
        for (int ct = 0; ct < 4; ct++) {
            aU[ct] = zero; aV[ct] = zero; aU2[ct] = zero;
#pragma unroll
            for (int kk = 0; kk < 2; kk++) {
                aU[ct]  = __builtin_amdgcn_mfma_f32_16x16x32_bf16(al[kk],   wfh[kk][ct],   aU[ct],  0, 0, 0);
                aU[ct]  = __builtin_amdgcn_mfma_f32_16x16x32_bf16(ah[kk],   wfl[kk][ct],   aU[ct],  0, 0, 0);
                aU[ct]  = __builtin_amdgcn_mfma_f32_16x16x32_bf16(ah[kk],   wfh[kk][ct],   aU[ct],  0, 0, 0);
                aV[ct]  = __builtin_amdgcn_mfma_f32_16x16x32_bf16(al[kk+2], wfh[kk+2][ct], aV[ct],  0, 0, 0);
                aV[ct]  = __builtin_amdgcn_mfma_f32_16x16x32_bf16(ah[kk+2], wfl[kk+2][ct], aV[ct],  0, 0, 0);
                aV[ct]  = __builtin_amdgcn_mfma_f32_16x16x32_bf16(ah[kk+2], wfh[kk+2][ct], aV[ct],  0, 0, 0);
                aU2[ct] = __builtin_amdgcn_mfma_f32_16x16x32_bf16(al[kk+2], wfh[kk][ct],   aU2[ct], 0, 0, 0);
                aU2[ct] = __builtin_amdgcn_mfma_f32_16x16x32_bf16(ah[kk+2], wfl[kk][ct],   aU2[ct], 0, 0, 0);
                aU2[ct] = __builtin_amdgcn_mfma_f32_16x16x32_bf16(ah[kk+2], wfh[kk][ct],   aU2[ct], 0, 0, 0);
            }
        }
        epi_tile<false, false>(wl, lane, aU,  zb, u,  tile, nullptr, nullptr);
        epi_tile<false, false>(wl, lane, aV,  zb, v,  tile, nullptr, nullptr);
        epi_tile<false, false>(wl, lane, aU2, zb, u2, tile, nullptr, nullptr);
    }
}

// ---------- analytic stage-1 stats ----------
__global__ void k_stats1a(const float* __restrict__ u, const float* __restrict__ v,
                          const float* __restrict__ u2, const int* __restrict__ od,
                          const int* __restrict__ id, double* __restrict__ stats_raw) {
    __shared__ double lsum[4][64], lsq[4][64];
    int tid = threadIdx.x, c = tid & 63, w = tid >> 6;
    double a1 = 0.0, a2 = 0.0;
    for (int n = blockIdx.x * 4 + w; n < NN; n += gridDim.x * 4) {
        double uu = u[(size_t)n * 64 + c], vv = v[(size_t)n * 64 + c];
        double uu2 = u2[(size_t)n * 64 + c];
        double wod = 1.0 + od[n], wid = 1.0 + id[n];
        a1 += wod * uu + wid * vv;
        a2 += wod * uu * uu + wid * vv * vv + 2.0 * vv * uu2;
    }
    lsum[w][c] = a1; lsq[w][c] = a2;
    __syncthreads();
    if (w == 0) {
        a1 = lsum[0][c] + lsum[1][c] + lsum[2][c] + lsum[3][c];
        a2 = lsq[0][c] + lsq[1][c] + lsq[2][c] + lsq[3][c];
        atomAddD(&stats_raw[c], a1);
        atomAddD(&stats_raw[64 + c], a2);
    }
}

__global__ void k_fin1(const double* __restrict__ raw, const float* __restrict__ b,
                       float* __restrict__ fin, double inv_cnt) {
    int c = threadIdx.x;
    double m1 = raw[c] * inv_cnt;
    double var = raw[64 + c] * inv_cnt - m1 * m1;
    if (var < 0.0) var = 0.0;
    fin[c] = (float)(m1 + (double)b[c]);
    fin[64 + c] = (float)(1.0 / sqrt(var + 1e-5));
}

__global__ void k_fin(const double* __restrict__ raw, float* __restrict__ fin, double inv_cnt) {
    int c = threadIdx.x;
    double mean = raw[c] * inv_cnt;
    double var = raw[64 + c] * inv_cnt - mean * mean;
    if (var < 0.0) var = 0.0;
    fin[c] = (float)mean;
    fin[64 + c] = (float)(1.0 / sqrt(var + 1e-5));
}

// ---------- stage-1 reduce + per-row h store in BF16 (16-way MLP gather preserved) ----------
// h = relu(bn1(u[src]+v[dst])) per row; s_tab[d] = sum over domain rows of h (f32);
// hb[row] = bf16(h)  (row layout: [0..NN) self rows, [NN..RR) dst-sorted edge rows).
__global__ void k_s1h(const float* __restrict__ u, const float* __restrict__ v,
                      const int* __restrict__ off, const unsigned int* __restrict__ sd_s,
                      const float* __restrict__ b_un, const float* __restrict__ fin,
                      const float* __restrict__ g1, const float* __restrict__ be1,
                      float* __restrict__ s_tab, unsigned short* __restrict__ hb) {
    int team = (blockIdx.x * 256 + threadIdx.x) >> 6;
    int c = threadIdx.x & 63;
    float sc = fin[64 + c] * g1[c];
    float tsh = (b_un[c] - fin[c]) * sc + be1[c];
    float vn = v[(size_t)team * 64 + c];
    float a[16];
#pragma unroll
    for (int j = 0; j < 16; j++) a[j] = 0.f;
    float hs = fmaxf((u[(size_t)team * 64 + c] + vn) * sc + tsh, 0.f);   // self row
    a[0] = hs;
    hb[(size_t)team * 64 + c] = f2bf(hs);
    int e = off[team], e1 = off[team + 1];
    for (; e + 15 < e1; e += 16)
#pragma unroll
        for (int j = 0; j < 16; j++) {
            float h = fmaxf((u[(size_t)(sd_s[e + j] & 0xFFFFu) * 64 + c] + vn) * sc + tsh, 0.f);
            a[j] += h;
            hb[(size_t)(NN + e + j) * 64 + c] = f2bf(h);
        }
    for (; e + 3 < e1; e += 4)
#pragma unroll
        for (int j = 0; j < 4; j++) {
            float h = fmaxf((u[(size_t)(sd_s[e + j] & 0xFFFFu) * 64 + c] + vn) * sc + tsh, 0.f);
            a[j] += h;
            hb[(size_t)(NN + e + j) * 64 + c] = f2bf(h);
        }
    for (; e < e1; e++) {
        float h = fmaxf((u[(size_t)(sd_s[e] & 0xFFFFu) * 64 + c] + vn) * sc + tsh, 0.f);
        a[0] += h;
        hb[(size_t)(NN + e) * 64 + c] = f2bf(h);
    }
#pragma unroll
    for (int j = 0; j < 8; j++) a[j] += a[j + 8];
#pragma unroll
    for (int j = 0; j < 4; j++) a[j] += a[j + 4];
    s_tab[(size_t)team * 64 + c] = (a[0] + a[1]) + (a[2] + a[3]);
}

// ---------- msg[n] = sum_{e:dst=n} s_tab[src_e] ----------
__global__ void k_msg_csr(const int* __restrict__ off, const unsigned int* __restrict__ sd_s,
                          const float* __restrict__ s_tab, float* __restrict__ msg) {
    int team = (blockIdx.x * 256 + threadIdx.x) >> 6;
    int c = threadIdx.x & 63;
    float a[16];
#pragma unroll
    for (int j = 0; j < 16; j++) a[j] = 0.f;
    int e = off[team], e1 = off[team + 1];
    for (; e + 15 < e1; e += 16)
#pragma unroll
        for (int j = 0; j < 16; j++) a[j] += s_tab[(size_t)(sd_s[e + j] & 0xFFFFu) * 64 + c];
    for (; e + 3 < e1; e += 4)
#pragma unroll
        for (int j = 0; j < 4; j++) a[j] += s_tab[(size_t)(sd_s[e + j] & 0xFFFFu) * 64 + c];
    for (; e < e1; e++) a[0] += s_tab[(size_t)(sd_s[e] & 0xFFFFu) * 64 + c];
#pragma unroll
    for (int j = 0; j < 8; j++) a[j] += a[j + 8];
#pragma unroll
    for (int j = 0; j < 4; j++) a[j] += a[j + 4];
    msg[(size_t)team * 64 + c] = (a[0] + a[1]) + (a[2] + a[3]);
}

// ---------- mb = msg @ W_gc[64:128]  (streaming; in/out may differ) ----------
__global__ void k_mb(const float* __restrict__ in, float* __restrict__ outp,
                     const float* __restrict__ W) {
    __shared__ float lds[4][16 * 68];
    const int lane = threadIdx.x & 63;
    const int wid = threadIdx.x >> 6;
    const int m = lane & 15, quad = lane >> 4;
    const int gwave = (blockIdx.x * blockDim.x + threadIdx.x) >> 6;
    const int nwaves = (gridDim.x * blockDim.x) >> 6;
    float* wl = lds[wid];

    bf16x8 wfh[2][4], wfl[2][4];
#pragma unroll
    for (int kk = 0; kk < 2; kk++)
#pragma unroll
        for (int ct = 0; ct < 4; ct++) {
            float wv[8];
#pragma unroll
            for (int j = 0; j < 8; j++)
                wv[j] = W[(kk * 32 + quad * 8 + j) * 64 + ct * 16 + m];
            split8r(wv, wfh[kk][ct], wfl[kk][ct]);
        }
    float zb[4] = {0.f, 0.f, 0.f, 0.f};

    for (int tile = gwave; tile < NT_N; tile += nwaves) {
        const int r = (tile << 4) + m;
        bf16x8 ah[2], al[2];
        split8(in + (size_t)r * 64 + quad * 8,      ah[0], al[0]);
        split8(in + (size_t)r * 64 + 32 + quad * 8, ah[1], al[1]);

        f32x4 zero = {0.f, 0.f, 0.f, 0.f};
        f32x4 acc[4];
#pragma unroll
        for (int ct = 0; ct < 4; ct++) {
            acc[ct] = zero;
#pragma unroll
            for (int kk = 0; kk < 2; kk++) {
                acc[ct] = __builtin_amdgcn_mfma_f32_16x16x32_bf16(al[kk], wfh[kk][ct], acc[ct], 0, 0, 0);
                acc[ct] = __builtin_amdgcn_mfma_f32_16x16x32_bf16(ah[kk], wfl[kk][ct], acc[ct], 0, 0, 0);
                acc[ct] = __builtin_amdgcn_mfma_f32_16x16x32_bf16(ah[kk], wfh[kk][ct], acc[ct], 0, 0, 0);
            }
        }
        epi_tile<false, false>(wl, lane, acc, zb, outp, tile, nullptr, nullptr);
    }
}

// ---------- stage-2 streaming matmul over bf16 h rows:
// h2b[r] = bf16( hb[r]@Wtop2 + mb[dst(r)] + b_gc ); + stage-2 stats (on f32 values).
__global__ void k_h2(const unsigned short* __restrict__ hb, unsigned short* __restrict__ h2b,
                     const float* __restrict__ mb, const unsigned int* __restrict__ sd_s,
                     const float* __restrict__ W, const float* __restrict__ b_gc,
                     double* __restrict__ stats_raw) {
    __shared__ float lds[4][16 * 68];
    const int lane = threadIdx.x & 63;
    const int wid = threadIdx.x >> 6;
    const int m = lane & 15, quad = lane >> 4;
    const int gwave = (blockIdx.x * blockDim.x + threadIdx.x) >> 6;
    const int nwaves = (gridDim.x * blockDim.x) >> 6;
    float* wl = lds[wid];

    bf16x8 wfh[2][4], wfl[2][4];
#pragma unroll
    for (int kk = 0; kk < 2; kk++)
#pragma unroll
        for (int ct = 0; ct < 4; ct++) {
            float wv[8];
#pragma unroll
            for (int j = 0; j < 8; j++)
                wv[j] = W[(kk * 32 + quad * 8 + j) * 64 + ct * 16 + m];
            split8r(wv, wfh[kk][ct], wfl[kk][ct]);
        }

    float bv[4];
#pragma unroll
    for (int ct = 0; ct < 4; ct++) bv[ct] = b_gc[ct * 16 + m];

    double ssum[4] = {0,0,0,0}, ssq[4] = {0,0,0,0};

    for (int tile = gwave; tile < NT_R; tile += nwaves) {
        const int r = (tile << 4) + m;
        int dm = (tile < NT_N) ? r : (int)(sd_s[r - NN] >> 16);

        bf16x8 ah[2];
        ah[0] = *reinterpret_cast<const bf16x8*>(hb + (size_t)r * 64 + quad * 8);
        ah[1] = *reinterpret_cast<const bf16x8*>(hb + (size_t)r * 64 + 32 + quad * 8);

        f32x4 zero = {0.f, 0.f, 0.f, 0.f};
        f32x4 acc[4];
#pragma unroll
        for (int ct = 0; ct < 4; ct++) {
            acc[ct] = zero;
#pragma unroll
            for (int kk = 0; kk < 2; kk++) {
                acc[ct] = __builtin_amdgcn_mfma_f32_16x16x32_bf16(ah[kk], wfl[kk][ct], acc[ct], 0, 0, 0);
                acc[ct] = __builtin_amdgcn_mfma_f32_16x16x32_bf16(ah[kk], wfh[kk][ct], acc[ct], 0, 0, 0);
            }
        }

        // add mb[dst_of_row] + b_gc per element, then stats + LDS-coalesced bf16 store
#pragma unroll
        for (int i = 0; i < 4; i++) {
            int dmv = __shfl(dm, (lane & 48) + quad * 4 + i, 64);   // dm of row quad*4+i
#pragma unroll
            for (int ct = 0; ct < 4; ct++) {
                float val = acc[ct][i] + bv[ct] + mb[(size_t)dmv * 64 + ct * 16 + m];
                wl[(quad * 4 + i) * 68 + ct * 16 + m] = val;
                ssum[ct] += (double)val;
                ssq[ct]  += (double)val * (double)val;
            }
        }
        asm volatile("s_waitcnt lgkmcnt(0)" ::: "memory");
#pragma unroll
        for (int j = 0; j < 4; j++) {
            int row = j * 4 + quad;
            f32x4 vv = *reinterpret_cast<const f32x4*>(wl + row * 68 + m * 4);
            unsigned int p0 = (unsigned int)f2bf(vv[0]) | ((unsigned int)f2bf(vv[1]) << 16);
            unsigned int p1 = (unsigned int)f2bf(vv[2]) | ((unsigned int)f2bf(vv[3]) << 16);
            uint2 pk; pk.x = p0; pk.y = p1;
            *reinterpret_cast<uint2*>(h2b + ((size_t)(tile << 4) + row) * 64 + m * 4) = pk;
        }
    }

#pragma unroll
    for (int ct = 0; ct < 4; ct++) {
        double sv = ssum[ct], qv = ssq[ct];
        sv += __shfl_xor(sv, 16, 64); sv += __shfl_xor(sv, 32, 64);
        qv += __shfl_xor(qv, 16, 64); qv += __shfl_xor(qv, 32, 64);
        if (quad == 0) {
            atomAddD(&stats_raw[ct * 16 + m], sv);
            atomAddD(&stats_raw[64 + ct * 16 + m], qv);
        }
    }
}

// ---------- agg[n] = relu(bn2(h2b[n])) + sum_{q in src-CSR} relu(bn2(h2b[NN+perm_s[q]])) ----------
__global__ void k_agg_csr(const unsigned short* __restrict__ h2b, const int* __restrict__ off_s,
                          const int* __restrict__ perm_s, const float* __restrict__ fin2,
                          const float* __restrict__ g2, const float* __restrict__ be2,
                          float* __restrict__ agg) {
    int n = (blockIdx.x * 256 + threadIdx.x) >> 6;
    int c = threadIdx.x & 63;
    float sc = fin2[64 + c] * g2[c];
    float sh = be2[c] - fin2[c] * sc;
    float a[16];
#pragma unroll
    for (int j = 0; j < 16; j++) a[j] = 0.f;
    a[0] = fmaxf(bf2f(h2b[(size_t)n * 64 + c]) * sc + sh, 0.f);   // self row
    int q = off_s[n], q1 = off_s[n + 1];
    for (; q + 15 < q1; q += 16)
#pragma unroll
        for (int j = 0; j < 16; j++) {
            float hv = bf2f(h2b[(size_t)(NN + perm_s[q + j]) * 64 + c]);
            a[j] += fmaxf(hv * sc + sh, 0.f);
        }
    for (; q + 3 < q1; q += 4)
#pragma unroll
        for (int j = 0; j < 4; j++) {
            float hv = bf2f(h2b[(size_t)(NN + perm_s[q + j]) * 64 + c]);
            a[j] += fmaxf(hv * sc + sh, 0.f);
        }
    for (; q < q1; q++) {
        float hv = bf2f(h2b[(size_t)(NN + perm_s[q]) * 64 + c]);
        a[0] += fmaxf(hv * sc + sh, 0.f);
    }
#pragma unroll
    for (int j = 0; j < 8; j++) a[j] += a[j + 8];
#pragma unroll
    for (int j = 0; j < 4; j++) a[j] += a[j + 4];
    agg[(size_t)n * 64 + c] = (a[0] + a[1]) + (a[2] + a[3]);
}

// ---------- stage 3: t_pre = [relu(bn2(h2b[:N])), agg] @ W_tr + b_tr, stats3 ----------
__global__ void k_mm3(const unsigned short* __restrict__ h2b, const float* __restrict__ agg,
                      const float* __restrict__ W, const float* __restrict__ bias,
                      const float* __restrict__ fin2, const float* __restrict__ g2,
                      const float* __restrict__ be2,
                      float* __restrict__ outp, double* __restrict__ stats_raw) {
    __shared__ float lds[4][16 * 68];
    const int lane = threadIdx.x & 63;
    const int wid = threadIdx.x >> 6;
    const int m = lane & 15, quad = lane >> 4;
    const int gwave = (blockIdx.x * blockDim.x + threadIdx.x) >> 6;
    const int nwaves = (gridDim.x * blockDim.x) >> 6;
    float* wl = lds[wid];

    bf16x8 wfh[4][4], wfl[4][4];
#pragma unroll
    for (int kk = 0; kk < 4; kk++)
#pragma unroll
        for (int ct = 0; ct < 4; ct++) {
            float wv[8];
#pragma unroll
            for (int j = 0; j < 8; j++)
                wv[j] = W[(kk * 32 + quad * 8 + j) * 64 + ct * 16 + m];
            split8r(wv, wfh[kk][ct], wfl[kk][ct]);
        }

    float bv[4];
#pragma unroll
    for (int ct = 0; ct < 4; ct++) bv[ct] = bias[ct * 16 + m];

    float s2f[2][8], t2f[2][8];
#pragma unroll
    for (int kk = 0; kk < 2; kk++)
#pragma unroll
        for (int j = 0; j < 8; j++) {
            int c = kk * 32 + quad * 8 + j;
            float sc = fin2[64 + c] * g2[c];
            s2f[kk][j] = sc;
            t2f[kk][j] = be2[c] - fin2[c] * sc;
        }

    double ssum[4] = {0,0,0,0}, ssq[4] = {0,0,0,0};

    for (int tile = gwave; tile < NT_N; tile += nwaves) {
        const int r = (tile << 4) + m;
        bf16x8 ah[4], al[4];
#pragma unroll
        for (int kk = 0; kk < 2; kk++) {
            bf16x8 hv = *reinterpret_cast<const bf16x8*>(h2b + (size_t)r * 64 + kk * 32 + quad * 8);
            float tv[8];
#pragma unroll
            for (int j = 0; j < 8; j++) {
                float f = bf2f((unsigned short)hv[j]);
                tv[j] = fmaxf(f * s2f[kk][j] + t2f[kk][j], 0.f);
            }
            split8r(tv, ah[kk], al[kk]);
        }
        split8(agg + (size_t)r * 64 + quad * 8,      ah[2], al[2]);
        split8(agg + (size_t)r * 64 + 32 + quad * 8, ah[3], al[3]);

        f32x4 zero = {0.f, 0.f, 0.f, 0.f};
        f32x4 acc[4];
#pragma unroll
        for (int ct = 0; ct < 4; ct++) {
            acc[ct] = zero;
#pragma unroll
            for (int kk = 0; kk < 4; kk++)
                acc[ct] = __builtin_amdgcn_mfma_f32_16x16x32_bf16(al[kk], wfh[kk][ct], acc[ct], 0, 0, 0);
#pragma unroll
            for (int kk = 0; kk < 4; kk++)
                acc[ct] = __builtin_amdgcn_mfma_f32_16x16x32_bf16(ah[kk], wfl[kk][ct], acc[ct], 0, 0, 0);
#pragma unroll
            for (int kk = 0; kk < 4; kk++)
                acc[ct] = __builtin_amdgcn_mfma_f32_16x16x32_bf16(ah[kk], wfh[kk][ct], acc[ct], 0, 0, 0);
        }

        epi_tile<false, true>(wl, lane, acc, bv, outp, tile, ssum, ssq);
    }

#pragma unroll
    for (int ct = 0; ct < 4; ct++) {
        double sv = ssum[ct], qv = ssq[ct];
        sv += __shfl_xor(sv, 16, 64); sv += __shfl_xor(sv, 32, 64);
        qv += __shfl_xor(qv, 16, 64); qv += __shfl_xor(qv, 32, 64);
        if (quad == 0) {
            atomAddD(&stats_raw[ct * 16 + m], sv);
            atomAddD(&stats_raw[64 + ct * 16 + m], qv);
        }
    }
}

// ---------- stage 4 ----------
__global__ void k_mm4(const float* __restrict__ tpre, const float* __restrict__ W,
                      const float* __restrict__ bias, const float* __restrict__ fin3,
                      const float* __restrict__ g2, const float* __restrict__ be2,
                      float* __restrict__ outp, double* __restrict__ stats_raw) {
    __shared__ float lds[4][16 * 68];
    const int lane = threadIdx.x & 63;
    const int wid = threadIdx.x >> 6;
    const int m = lane & 15, quad = lane >> 4;
    const int gwave = (blockIdx.x * blockDim.x + threadIdx.x) >> 6;
    const int nwaves = (gridDim.x * blockDim.x) >> 6;
    float* wl = lds[wid];

    bf16x8 wfh[2][4], wfl[2][4];
#pragma unroll
    for (int kk = 0; kk < 2; kk++)
#pragma unroll
        for (int ct = 0; ct < 4; ct++) {
            float wv[8];
#pragma unroll
            for (int j = 0; j < 8; j++)
                wv[j] = W[(kk * 32 + quad * 8 + j) * 64 + ct * 16 + m];
            split8r(wv, wfh[kk][ct], wfl[kk][ct]);
        }

    float bv[4];
#pragma unroll
    for (int ct = 0; ct < 4; ct++) bv[ct] = bias[ct * 16 + m];

    float sc[2][8], sh[2][8];
#pragma unroll
    for (int kk = 0; kk < 2; kk++)
#pragma unroll
        for (int j = 0; j < 8; j++) {
            int c = kk * 32 + quad * 8 + j;
            float s = fin3[64 + c] * g2[c];
            sc[kk][j] = s;
            sh[kk][j] = be2[c] - fin3[c] * s;
        }

    double ssum[4] = {0,0,0,0}, ssq[4] = {0,0,0,0};

    for (int tile = gwave; tile < NT_N; tile += nwaves) {
        const int r = (tile << 4) + m;
        bf16x8 ah[2], al[2];
#pragma unroll
        for (int kk = 0; kk < 2; kk++) {
            f32x4 v0 = *reinterpret_cast<const f32x4*>(tpre + (size_t)r * 64 + kk * 32 + quad * 8);
            f32x4 v1 = *reinterpret_cast<const f32x4*>(tpre + (size_t)r * 64 + kk * 32 + quad * 8 + 4);
            float tv[8];
#pragma unroll
            for (int j = 0; j < 4; j++) {
                tv[j]     = fmaxf(v0[j] * sc[kk][j]     + sh[kk][j],     0.f);
                tv[4 + j] = fmaxf(v1[j] * sc[kk][4 + j] + sh[kk][4 + j], 0.f);
            }
            split8r(tv, ah[kk], al[kk]);
        }

        f32x4 zero = {0.f, 0.f, 0.f, 0.f};
        f32x4 acc[4];
#pragma unroll
        for (int ct = 0; ct < 4; ct++) {
            acc[ct] = zero;
#pragma unroll
            for (int kk = 0; kk < 2; kk++) {
                acc[ct] = __builtin_amdgcn_mfma_f32_16x16x32_bf16(al[kk], wfh[kk][ct], acc[ct], 0, 0, 0);
                acc[ct] = __builtin_amdgcn_mfma_f32_16x16x32_bf16(ah[kk], wfl[kk][ct], acc[ct], 0, 0, 0);
                acc[ct] = __builtin_amdgcn_mfma_f32_16x16x32_bf16(ah[kk], wfh[kk][ct], acc[ct], 0, 0, 0);
            }
        }

        epi_tile<true, true>(wl, lane, acc, bv, outp, tile, ssum, ssq);
    }

#pragma unroll
    for (int ct = 0; ct < 4; ct++) {
        double sv = ssum[ct], qv = ssq[ct];
        sv += __shfl_xor(sv, 16, 64); sv += __shfl_xor(sv, 32, 64);
        qv += __shfl_xor(qv, 16, 64); qv += __shfl_xor(qv, 32, 64);
        if (quad == 0) {
            atomAddD(&stats_raw[ct * 16 + m], sv);
            atomAddD(&stats_raw[64 + ct * 16 + m], qv);
        }
    }
}

// out = relu(bn(out_pre; stats4, g3, be3)) -> f32
__global__ void k_out(const float* __restrict__ op, const float* __restrict__ fin,
                      const float* __restrict__ g, const float* __restrict__ be,
                      float* __restrict__ out) {
    int i = blockIdx.x * 256 + threadIdx.x;   // covers NN*64 exactly
    int c = i & 63;
    out[i] = fmaxf((op[i] - fin[c]) * fin[64 + c] * g[c] + be[c], 0.f);
}

extern "C" void kernel_launch(void* const* d_in, const int* in_sizes, int n_in,
                              void* d_out, int out_size, void* d_ws, size_t ws_size,
                              hipStream_t stream) {
    const float* x    = (const float*)d_in[0];
    const int*   ei   = (const int*)d_in[1];
    const float* W_un = (const float*)d_in[2];
    const float* b_un = (const float*)d_in[3];
    const float* g1   = (const float*)d_in[4];
    const float* be1  = (const float*)d_in[5];
    const float* W_gc = (const float*)d_in[6];
    const float* b_gc = (const float*)d_in[7];
    const float* g2   = (const float*)d_in[8];
    const float* be2  = (const float*)d_in[9];
    const float* W_tr = (const float*)d_in[10];
    const float* b_tr = (const float*)d_in[11];
    const float* W_li = (const float*)d_in[12];
    const float* b_li = (const float*)d_in[13];
    const float* g3   = (const float*)d_in[14];
    const float* be3  = (const float*)d_in[15];

    float* ws = (float*)d_ws;
    const size_t FN = (size_t)NN * 64;           // 3.2M floats (12.8 MB)
    const size_t FR = (size_t)RR * 64;           // 54.4M floats (217.6 MB)
    // Region plan (zero growth vs R3; lifetimes verified):
    //  P0: u  -> msg/mb (after k_s1h, u dead)  -> outpre (after k_h2/k_mm3, mb dead)
    //  P1: v  -> agg    (after k_s1h, v dead)
    //  P2: s_tab (written by k_s1h; dead after k_msg_csr) -> tpre
    //  H (FR floats = FR*4 bytes): dsum(H), u2(H+FN) [dead after k_stats1a]
    //      -> hb (FR ushorts, bytes [0, 2FR)) + h2b (FR ushorts, bytes [2FR, 4FR))
    float* P0 = ws;
    float* P1 = ws + FN;
    float* P2 = ws + 2 * FN;
    float* H  = ws + 3 * FN;
    float* u      = P0;
    float* v      = P1;
    float* s_tab  = P2;
    float* dsum   = H;
    float* u2     = H + FN;
    unsigned short* hb  = (unsigned short*)H;        // bf16 h rows
    unsigned short* h2b = (unsigned short*)H + FR;   // bf16 h2pre rows
    float* msg    = P0;           // becomes mb after k_mb (in place)
    float* agg    = P1;
    float* tpre   = P2;
    float* outpre = P0;
    double*       stats_raw = (double*)(H + FR);
    int*          od        = (int*)(stats_raw + 512);
    int*          id        = od + NN;
    int*          off       = id + NN;
    int*          cursor    = off + NN + 1;
    int*          off_s     = cursor + NN;
    int*          cursor_s  = off_s + NN + 1;
    unsigned int* sd_s      = (unsigned int*)(cursor_s + NN);   // packed src|dst<<16, dst-sorted
    int*          perm_s    = (int*)(sd_s + EE);
    float*        stats_fin = (float*)(perm_s + EE);

    // zero: stats_raw + od + id (contiguous)
    hipMemsetAsync(stats_raw, 0, 512 * sizeof(double) + 2 * NN * sizeof(int), stream);

    // build dst-sorted packed edge list + src-CSR permutation
    k_deg  <<<3125, 256,  0, stream>>>(ei, od, id);
    k_scan2<<<2,    1024, 0, stream>>>(id, off, cursor, od, off_s, cursor_s);
    k_fill <<<3125, 256,  0, stream>>>(ei, cursor, sd_s);
    k_fill2<<<3125, 256,  0, stream>>>(sd_s, cursor_s, perm_s);

    // stage 0 + per-node tables
    k_dsum_csr<<<12500, 256, 0, stream>>>(x, off, sd_s, dsum);
    k_uv3<<<512, 256, 0, stream>>>(x, dsum, W_un, u, v, u2);

    // stage-1: analytic stats, then CSR reduce + per-row bf16 h store
    k_stats1a<<<256, 256, 0, stream>>>(u, v, u2, od, id, stats_raw + 0);
    k_fin1<<<1, 64, 0, stream>>>(stats_raw + 0, b_un, stats_fin + 0, 1.0 / (double)RR);
    k_s1h<<<12500, 256, 0, stream>>>(u, v, off, sd_s, b_un, stats_fin + 0, g1, be1,
                                     s_tab, hb);
    k_msg_csr<<<12500, 256, 0, stream>>>(off, sd_s, s_tab, msg);
    k_mb<<<512, 256, 0, stream>>>(msg, msg, W_gc + 64 * 64);   // msg -> mb in place

    // stage-2: streaming matmul over bf16 h rows -> bf16 h2 rows, stats
    k_h2<<<2048, 256, 0, stream>>>(hb, h2b, msg, sd_s, W_gc, b_gc, stats_raw + 128);
    k_fin<<<1, 64, 0, stream>>>(stats_raw + 128, stats_fin + 128, 1.0 / (double)RR);
    k_agg_csr<<<12500, 256, 0, stream>>>(h2b, off_s, perm_s, stats_fin + 128, g2, be2, agg);

    // stage 3
    k_mm3<<<512, 256, 0, stream>>>(h2b, agg, W_tr, b_tr, stats_fin + 128, g2, be2,
                                   tpre, stats_raw + 256);
    k_fin<<<1, 64, 0, stream>>>(stats_raw + 256, stats_fin + 256, 1.0 / (double)NN);

    // stage 4
    k_mm4<<<512, 256, 0, stream>>>(tpre, W_li, b_li, stats_fin + 256, g2, be2,
                                   outpre, stats_raw + 384);
    k_fin<<<1, 64, 0, stream>>>(stats_raw + 384, stats_fin + 384, 1.0 / (double)NN);

    k_out<<<12500, 256, 0, stream>>>(outpre, stats_fin + 384, g3, be3, (float*)d_out);
}

// Round 6
// 842.738 us; speedup vs baseline: 2.2070x; 1.1723x over previous
//
#include <hip/hip_runtime.h>
#include <cstdint>
#include <math.h>

// Problem sizes (fixed by the reference).
#define NN 50000
#define EE 800000
#define RR 850000      // NN + EE rows
#define NT_N 3125      // NN/16
#define NT_R 53125     // RR/16
#define NBLK_H2 2048
#define NBLK_MM 512

typedef short  bf16x8 __attribute__((ext_vector_type(8)));
typedef float  f32x4  __attribute__((ext_vector_type(4)));

__device__ __forceinline__ float bf2f(unsigned short b) {
    unsigned int u = ((unsigned int)b) << 16;
    return __builtin_bit_cast(float, u);
}
__device__ __forceinline__ unsigned short f2bf(float f) {
    unsigned int u = __builtin_bit_cast(unsigned int, f);
    u = u + 0x7fffu + ((u >> 16) & 1u);
    return (unsigned short)(u >> 16);
}
__device__ __forceinline__ void atomAddD(double* p, double v) { unsafeAtomicAdd(p, v); }
__device__ __forceinline__ int atomAddI(int* p, int v) { return atomicAdd(p, v); }

// split 8 consecutive f32 into hi/lo bf16 fragments: hi+lo == v to ~2^-16 rel
__device__ __forceinline__ void split8(const float* p, bf16x8& hi, bf16x8& lo) {
    f32x4 v0 = *reinterpret_cast<const f32x4*>(p);
    f32x4 v1 = *reinterpret_cast<const f32x4*>(p + 4);
#pragma unroll
    for (int j = 0; j < 4; j++) {
        unsigned short h0 = f2bf(v0[j]);
        hi[j] = (short)h0; lo[j] = (short)f2bf(v0[j] - bf2f(h0));
        unsigned short h1 = f2bf(v1[j]);
        hi[4 + j] = (short)h1; lo[4 + j] = (short)f2bf(v1[j] - bf2f(h1));
    }
}
__device__ __forceinline__ void split8r(const float* v, bf16x8& hi, bf16x8& lo) {
#pragma unroll
    for (int j = 0; j < 8; j++) {
        unsigned short h = f2bf(v[j]);
        hi[j] = (short)h; lo[j] = (short)f2bf(v[j] - bf2f(h));
    }
}

// LDS-staged coalesced tile store: MFMA C-layout -> 4x 1KB contiguous dwordx4 stores.
template <bool RELU, bool STATS>
__device__ __forceinline__ void epi_tile(float* wl, int lane, const f32x4* acc,
                                         const float* bv, float* __restrict__ gout,
                                         int tile, double* ssum, double* ssq) {
    const int m = lane & 15, quad = lane >> 4;
#pragma unroll
    for (int ct = 0; ct < 4; ct++)
#pragma unroll
        for (int i = 0; i < 4; i++) {
            float val = acc[ct][i] + bv[ct];
            if (RELU) val = fmaxf(val, 0.f);
            wl[(quad * 4 + i) * 68 + ct * 16 + m] = val;
            if (STATS) { ssum[ct] += (double)val; ssq[ct] += (double)val * (double)val; }
        }
    asm volatile("s_waitcnt lgkmcnt(0)" ::: "memory");
#pragma unroll
    for (int j = 0; j < 4; j++) {
        int row = j * 4 + quad;
        f32x4 vv = *reinterpret_cast<const f32x4*>(wl + row * 68 + m * 4);
        *reinterpret_cast<f32x4*>(gout + ((size_t)(tile << 4) + row) * 64 + m * 4) = vv;
    }
}

// block-level stats reduce: wave shfl-reduce -> LDS -> one coalesced 1KB store per block.
// ldsbase must be >= 512 doubles (reuses the tile-staging LDS). No global atomics.
__device__ __forceinline__ void stats_block_out(float* ldsbase, int lane, int wid,
                                                const double* ssum, const double* ssq,
                                                double* __restrict__ part) {
    const int m = lane & 15, quad = lane >> 4;
    double* dl = (double*)ldsbase;
    __syncthreads();
#pragma unroll
    for (int ct = 0; ct < 4; ct++) {
        double sv = ssum[ct], qv = ssq[ct];
        sv += __shfl_xor(sv, 16, 64); sv += __shfl_xor(sv, 32, 64);
        qv += __shfl_xor(qv, 16, 64); qv += __shfl_xor(qv, 32, 64);
        if (quad == 0) {
            dl[wid * 128 + ct * 16 + m]      = sv;
            dl[wid * 128 + 64 + ct * 16 + m] = qv;
        }
    }
    __syncthreads();
    int tid = wid * 64 + lane;
    if (tid < 128) {
        double tot = dl[tid] + dl[128 + tid] + dl[256 + tid] + dl[384 + tid];
        part[(size_t)blockIdx.x * 128 + tid] = tot;
    }
}

// reduce block partials into raw[0..127] (few spread atomics only)
__global__ void k_red(const double* __restrict__ p, int nblk, double* __restrict__ raw) {
    int t = threadIdx.x;   // 128
    double acc = 0.0;
    for (int b = blockIdx.x; b < nblk; b += gridDim.x)
        acc += p[(size_t)b * 128 + t];
    atomAddD(&raw[t], acc);
}

// ---------- degree counts ----------
__global__ void k_deg(const int* __restrict__ ei, int* __restrict__ od, int* __restrict__ id) {
    int e = blockIdx.x * 256 + threadIdx.x;   // covers EE exactly
    atomAddI(&od[ei[e]], 1);
    atomAddI(&id[ei[EE + e]], 1);
}

// ---------- dual exclusive scan (block 0: dst-CSR, block 1: src-CSR) ----------
__global__ void __launch_bounds__(1024) k_scan2(const int* __restrict__ id, int* __restrict__ off,
                                                int* __restrict__ cursor,
                                                const int* __restrict__ od, int* __restrict__ off_s,
                                                int* __restrict__ cursor_s) {
    const int* cnt = (blockIdx.x == 0) ? id : od;
    int* o  = (blockIdx.x == 0) ? off : off_s;
    int* cu = (blockIdx.x == 0) ? cursor : cursor_s;
    __shared__ int part[1024];
    const int t = threadIdx.x;
    const int CH = (NN + 1023) / 1024;
    int base = t * CH, s = 0;
    for (int i = 0; i < CH; i++) { int idx = base + i; if (idx < NN) s += cnt[idx]; }
    part[t] = s;
    __syncthreads();
    if (t == 0) {
        int run = 0;
        for (int i = 0; i < 1024; i++) { int x = part[i]; part[i] = run; run += x; }
    }
    __syncthreads();
    int run = part[t];
    for (int i = 0; i < CH; i++) {
        int idx = base + i;
        if (idx < NN) { o[idx] = run; cu[idx] = run; run += cnt[idx]; }
    }
    if (t == 0) o[NN] = EE;
}

// ---------- fill dst-sorted packed edge array: sd = src | (dst<<16) ----------
__global__ void k_fill(const int* __restrict__ ei, int* __restrict__ cursor,
                       unsigned int* __restrict__ sd_s) {
    int e = blockIdx.x * 256 + threadIdx.x;   // covers EE exactly
    int s = ei[e], d = ei[EE + e];
    int p = atomAddI(&cursor[d], 1);
    sd_s[p] = (unsigned int)s | ((unsigned int)d << 16);
}

// ---------- fill src-CSR permutation: perm_s[q] = dst-order position p ----------
__global__ void k_fill2(const unsigned int* __restrict__ sd_s, int* __restrict__ cursor_s,
                        int* __restrict__ perm_s) {
    int p = blockIdx.x * 256 + threadIdx.x;   // covers EE exactly
    int s = (int)(sd_s[p] & 0xFFFFu);
    int q = atomAddI(&cursor_s[s], 1);
    perm_s[q] = p;
}

// ---------- dsum[n] = x[n] + sum_{e: dst=n} x[src_e]  (CSR, no atomics, 16-way MLP) ----------
__global__ void k_dsum_csr(const float* __restrict__ x, const int* __restrict__ off,
                           const unsigned int* __restrict__ sd_s, float* __restrict__ dsum) {
    int team = (blockIdx.x * 256 + threadIdx.x) >> 6;   // 12500 blocks x 4 = NN
    int c = threadIdx.x & 63;
    float a[16];
#pragma unroll
    for (int j = 0; j < 16; j++) a[j] = 0.f;
    a[0] = x[(size_t)team * 64 + c];
    int e = off[team], e1 = off[team + 1];
    for (; e + 15 < e1; e += 16)
#pragma unroll
        for (int j = 0; j < 16; j++) a[j] += x[(size_t)(sd_s[e + j] & 0xFFFFu) * 64 + c];
    for (; e + 3 < e1; e += 4)
#pragma unroll
        for (int j = 0; j < 4; j++) a[j] += x[(size_t)(sd_s[e + j] & 0xFFFFu) * 64 + c];
    for (; e < e1; e++) a[0] += x[(size_t)(sd_s[e] & 0xFFFFu) * 64 + c];
#pragma unroll
    for (int j = 0; j < 8; j++) a[j] += a[j + 8];
#pragma unroll
    for (int j = 0; j < 4; j++) a[j] += a[j + 4];
    dsum[(size_t)team * 64 + c] = (a[0] + a[1]) + (a[2] + a[3]);
}

// ---------- u = x@W_top, v = dsum@W_bot, u2 = dsum@W_top ----------
__global__ void k_uv3(const float* __restrict__ x, const float* __restrict__ dsum,
                      const float* __restrict__ W, float* __restrict__ u,
                      float* __restrict__ v, float* __restrict__ u2) {
    __shared__ float lds[4][16 * 68];
    const int lane = threadIdx.x & 63;
    const int wid = threadIdx.x >> 6;
    const int m = lane & 15, quad = lane >> 4;
    const int gwave = (blockIdx.x * blockDim.x + threadIdx.x) >> 6;
    const int nwaves = (gridDim.x * blockDim.x) >> 6;
    float* wl = lds[wid];

    bf16x8 wfh[4][4], wfl[4][4];
#pragma unroll
    for (int kk = 0; kk < 4; kk++)
#pragma unroll
        for (int ct = 0; ct < 4; ct++) {
            float wv[8];
#pragma unroll
            for (int j = 0; j < 8; j++)
                wv[j] = W[(kk * 32 + quad * 8 + j) * 64 + ct * 16 + m];
            split8r(wv, wfh[kk][ct], wfl[kk][ct]);
        }
    float zb[4] = {0.f, 0.f, 0.f, 0.f};

    for (int tile = gwave; tile < NT_N; tile += nwaves) {
        const int r = (tile << 4) + m;
        bf16x8 ah[4], al[4];
        split8(x    + (size_t)r * 64 + quad * 8,      ah[0], al[0]);
        split8(x    + (size_t)r * 64 + 32 + quad * 8, ah[1], al[1]);
        split8(dsum + (size_t)r * 64 + quad * 8,      ah[2], al[2]);
        split8(dsum + (size_t)r * 64 + 32 + quad * 8, ah[3], al[3]);

        f32x4 zero = {0.f, 0.f, 0.f, 0.f};
        f32x4 aU[4], aV[4], aU2[4];
#pragma unroll
        for (int ct = 0; ct < 4; ct++) {
            aU[ct] = zero; aV[ct] = zero; aU2[ct] = zero;
#pragma unroll
            for (int kk = 0; kk < 2; kk++) {
                aU[ct]  = __builtin_amdgcn_mfma_f32_16x16x32_bf16(al[kk],   wfh[kk][ct],   aU[ct],  0, 0, 0);
                aU[ct]  = __builtin_amdgcn_mfma_f32_16x16x32_bf16(ah[kk],   wfl[kk][ct],   aU[ct],  0, 0, 0);
                aU[ct]  = __builtin_amdgcn_mfma_f32_16x16x32_bf16(ah[kk],   wfh[kk][ct],   aU[ct],  0, 0, 0);
                aV[ct]  = __builtin_amdgcn_mfma_f32_16x16x32_bf16(al[kk+2], wfh[kk+2][ct], aV[ct],  0, 0, 0);
                aV[ct]  = __builtin_amdgcn_mfma_f32_16x16x32_bf16(ah[kk+2], wfl[kk+2][ct], aV[ct],  0, 0, 0);
                aV[ct]  = __builtin_amdgcn_mfma_f32_16x16x32_bf16(ah[kk+2], wfh[kk+2][ct], aV[ct],  0, 0, 0);
                aU2[ct] = __builtin_amdgcn_mfma_f32_16x16x32_bf16(al[kk+2], wfh[kk][ct],   aU2[ct], 0, 0, 0);
                aU2[ct] = __builtin_amdgcn_mfma_f32_16x16x32_bf16(ah[kk+2], wfl[kk][ct],   aU2[ct], 0, 0, 0);
                aU2[ct] = __builtin_amdgcn_mfma_f32_16x16x32_bf16(ah[kk+2], wfh[kk][ct],   aU2[ct], 0, 0, 0);
            }
        }
        epi_tile<false, false>(wl, lane, aU,  zb, u,  tile, nullptr, nullptr);
        epi_tile<false, false>(wl, lane, aV,  zb, v,  tile, nullptr, nullptr);
        epi_tile<false, false>(wl, lane, aU2, zb, u2, tile, nullptr, nullptr);
    }
}

// ---------- analytic stage-1 stats ----------
__global__ void k_stats1a(const float* __restrict__ u, const float* __restrict__ v,
                          const float* __restrict__ u2, const int* __restrict__ od,
                          const int* __restrict__ id, double* __restrict__ stats_raw) {
    __shared__ double lsum[4][64], lsq[4][64];
    int tid = threadIdx.x, c = tid & 63, w = tid >> 6;
    double a1 = 0.0, a2 = 0.0;
    for (int n = blockIdx.x * 4 + w; n < NN; n += gridDim.x * 4) {
        double uu = u[(size_t)n * 64 + c], vv = v[(size_t)n * 64 + c];
        double uu2 = u2[(size_t)n * 64 + c];
        double wod = 1.0 + od[n], wid = 1.0 + id[n];
        a1 += wod * uu + wid * vv;
        a2 += wod * uu * uu + wid * vv * vv + 2.0 * vv * uu2;
    }
    lsum[w][c] = a1; lsq[w][c] = a2;
    __syncthreads();
    if (w == 0) {
        a1 = lsum[0][c] + lsum[1][c] + lsum[2][c] + lsum[3][c];
        a2 = lsq[0][c] + lsq[1][c] + lsq[2][c] + lsq[3][c];
        atomAddD(&stats_raw[c], a1);
        atomAddD(&stats_raw[64 + c], a2);
    }
}

__global__ void k_fin1(const double* __restrict__ raw, const float* __restrict__ b,
                       float* __restrict__ fin, double inv_cnt) {
    int c = threadIdx.x;
    double m1 = raw[c] * inv_cnt;
    double var = raw[64 + c] * inv_cnt - m1 * m1;
    if (var < 0.0) var = 0.0;
    fin[c] = (float)(m1 + (double)b[c]);
    fin[64 + c] = (float)(1.0 / sqrt(var + 1e-5));
}

__global__ void k_fin(const double* __restrict__ raw, float* __restrict__ fin, double inv_cnt) {
    int c = threadIdx.x;
    double mean = raw[c] * inv_cnt;
    double var = raw[64 + c] * inv_cnt - mean * mean;
    if (var < 0.0) var = 0.0;
    fin[c] = (float)mean;
    fin[64 + c] = (float)(1.0 / sqrt(var + 1e-5));
}

// ---------- stage-1 reduce + per-row h store in BF16 (16-way MLP gather preserved) ----------
__global__ void k_s1h(const float* __restrict__ u, const float* __restrict__ v,
                      const int* __restrict__ off, const unsigned int* __restrict__ sd_s,
                      const float* __restrict__ b_un, const float* __restrict__ fin,
                      const float* __restrict__ g1, const float* __restrict__ be1,
                      float* __restrict__ s_tab, unsigned short* __restrict__ hb) {
    int team = (blockIdx.x * 256 + threadIdx.x) >> 6;
    int c = threadIdx.x & 63;
    float sc = fin[64 + c] * g1[c];
    float tsh = (b_un[c] - fin[c]) * sc + be1[c];
    float vn = v[(size_t)team * 64 + c];
    float a[16];
#pragma unroll
    for (int j = 0; j < 16; j++) a[j] = 0.f;
    float hs = fmaxf((u[(size_t)team * 64 + c] + vn) * sc + tsh, 0.f);   // self row
    a[0] = hs;
    hb[(size_t)team * 64 + c] = f2bf(hs);
    int e = off[team], e1 = off[team + 1];
    for (; e + 15 < e1; e += 16)
#pragma unroll
        for (int j = 0; j < 16; j++) {
            float h = fmaxf((u[(size_t)(sd_s[e + j] & 0xFFFFu) * 64 + c] + vn) * sc + tsh, 0.f);
            a[j] += h;
            hb[(size_t)(NN + e + j) * 64 + c] = f2bf(h);
        }
    for (; e + 3 < e1; e += 4)
#pragma unroll
        for (int j = 0; j < 4; j++) {
            float h = fmaxf((u[(size_t)(sd_s[e + j] & 0xFFFFu) * 64 + c] + vn) * sc + tsh, 0.f);
            a[j] += h;
            hb[(size_t)(NN + e + j) * 64 + c] = f2bf(h);
        }
    for (; e < e1; e++) {
        float h = fmaxf((u[(size_t)(sd_s[e] & 0xFFFFu) * 64 + c] + vn) * sc + tsh, 0.f);
        a[0] += h;
        hb[(size_t)(NN + e) * 64 + c] = f2bf(h);
    }
#pragma unroll
    for (int j = 0; j < 8; j++) a[j] += a[j + 8];
#pragma unroll
    for (int j = 0; j < 4; j++) a[j] += a[j + 4];
    s_tab[(size_t)team * 64 + c] = (a[0] + a[1]) + (a[2] + a[3]);
}

// ---------- msg[n] = sum_{e:dst=n} s_tab[src_e] ----------
__global__ void k_msg_csr(const int* __restrict__ off, const unsigned int* __restrict__ sd_s,
                          const float* __restrict__ s_tab, float* __restrict__ msg) {
    int team = (blockIdx.x * 256 + threadIdx.x) >> 6;
    int c = threadIdx.x & 63;
    float a[16];
#pragma unroll
    for (int j = 0; j < 16; j++) a[j] = 0.f;
    int e = off[team], e1 = off[team + 1];
    for (; e + 15 < e1; e += 16)
#pragma unroll
        for (int j = 0; j < 16; j++) a[j] += s_tab[(size_t)(sd_s[e + j] & 0xFFFFu) * 64 + c];
    for (; e + 3 < e1; e += 4)
#pragma unroll
        for (int j = 0; j < 4; j++) a[j] += s_tab[(size_t)(sd_s[e + j] & 0xFFFFu) * 64 + c];
    for (; e < e1; e++) a[0] += s_tab[(size_t)(sd_s[e] & 0xFFFFu) * 64 + c];
#pragma unroll
    for (int j = 0; j < 8; j++) a[j] += a[j + 8];
#pragma unroll
    for (int j = 0; j < 4; j++) a[j] += a[j + 4];
    msg[(size_t)team * 64 + c] = (a[0] + a[1]) + (a[2] + a[3]);
}

// ---------- mb = msg @ W_gc[64:128]  (streaming; in/out may differ) ----------
__global__ void k_mb(const float* __restrict__ in, float* __restrict__ outp,
                     const float* __restrict__ W) {
    __shared__ float lds[4][16 * 68];
    const int lane = threadIdx.x & 63;
    const int wid = threadIdx.x >> 6;
    const int m = lane & 15, quad = lane >> 4;
    const int gwave = (blockIdx.x * blockDim.x + threadIdx.x) >> 6;
    const int nwaves = (gridDim.x * blockDim.x) >> 6;
    float* wl = lds[wid];

    bf16x8 wfh[2][4], wfl[2][4];
#pragma unroll
    for (int kk = 0; kk < 2; kk++)
#pragma unroll
        for (int ct = 0; ct < 4; ct++) {
            float wv[8];
#pragma unroll
            for (int j = 0; j < 8; j++)
                wv[j] = W[(kk * 32 + quad * 8 + j) * 64 + ct * 16 + m];
            split8r(wv, wfh[kk][ct], wfl[kk][ct]);
        }
    float zb[4] = {0.f, 0.f, 0.f, 0.f};

    for (int tile = gwave; tile < NT_N; tile += nwaves) {
        const int r = (tile << 4) + m;
        bf16x8 ah[2], al[2];
        split8(in + (size_t)r * 64 + quad * 8,      ah[0], al[0]);
        split8(in + (size_t)r * 64 + 32 + quad * 8, ah[1], al[1]);

        f32x4 zero = {0.f, 0.f, 0.f, 0.f};
        f32x4 acc[4];
#pragma unroll
        for (int ct = 0; ct < 4; ct++) {
            acc[ct] = zero;
#pragma unroll
            for (int kk = 0; kk < 2; kk++) {
                acc[ct] = __builtin_amdgcn_mfma_f32_16x16x32_bf16(al[kk], wfh[kk][ct], acc[ct], 0, 0, 0);
                acc[ct] = __builtin_amdgcn_mfma_f32_16x16x32_bf16(ah[kk], wfl[kk][ct], acc[ct], 0, 0, 0);
                acc[ct] = __builtin_amdgcn_mfma_f32_16x16x32_bf16(ah[kk], wfh[kk][ct], acc[ct], 0, 0, 0);
            }
        }
        epi_tile<false, false>(wl, lane, acc, zb, outp, tile, nullptr, nullptr);
    }
}

// ---------- stage-2 streaming matmul over bf16 h rows:
// h2b[r] = bf16( hb[r]@Wtop2 + mb[dst(r)] + b_gc ); stats via block partials (no atomics).
__global__ void k_h2(const unsigned short* __restrict__ hb, unsigned short* __restrict__ h2b,
                     const float* __restrict__ mb, const unsigned int* __restrict__ sd_s,
                     const float* __restrict__ W, const float* __restrict__ b_gc,
                     double* __restrict__ part) {
    __shared__ float lds[4][16 * 68];
    const int lane = threadIdx.x & 63;
    const int wid = threadIdx.x >> 6;
    const int m = lane & 15, quad = lane >> 4;
    const int gwave = (blockIdx.x * blockDim.x + threadIdx.x) >> 6;
    const int nwaves = (gridDim.x * blockDim.x) >> 6;
    float* wl = lds[wid];

    bf16x8 wfh[2][4], wfl[2][4];
#pragma unroll
    for (int kk = 0; kk < 2; kk++)
#pragma unroll
        for (int ct = 0; ct < 4; ct++) {
            float wv[8];
#pragma unroll
            for (int j = 0; j < 8; j++)
                wv[j] = W[(kk * 32 + quad * 8 + j) * 64 + ct * 16 + m];
            split8r(wv, wfh[kk][ct], wfl[kk][ct]);
        }

    float bv[4];
#pragma unroll
    for (int ct = 0; ct < 4; ct++) bv[ct] = b_gc[ct * 16 + m];

    double ssum[4] = {0,0,0,0}, ssq[4] = {0,0,0,0};

    for (int tile = gwave; tile < NT_R; tile += nwaves) {
        const int r = (tile << 4) + m;
        int dm = (tile < NT_N) ? r : (int)(sd_s[r - NN] >> 16);

        bf16x8 ah[2];
        ah[0] = *reinterpret_cast<const bf16x8*>(hb + (size_t)r * 64 + quad * 8);
        ah[1] = *reinterpret_cast<const bf16x8*>(hb + (size_t)r * 64 + 32 + quad * 8);

        f32x4 zero = {0.f, 0.f, 0.f, 0.f};
        f32x4 acc[4];
#pragma unroll
        for (int ct = 0; ct < 4; ct++) {
            acc[ct] = zero;
#pragma unroll
            for (int kk = 0; kk < 2; kk++) {
                acc[ct] = __builtin_amdgcn_mfma_f32_16x16x32_bf16(ah[kk], wfl[kk][ct], acc[ct], 0, 0, 0);
                acc[ct] = __builtin_amdgcn_mfma_f32_16x16x32_bf16(ah[kk], wfh[kk][ct], acc[ct], 0, 0, 0);
            }
        }

        // add mb[dst_of_row] + b_gc per element, then stats + LDS-coalesced bf16 store
#pragma unroll
        for (int i = 0; i < 4; i++) {
            int dmv = __shfl(dm, (lane & 48) + quad * 4 + i, 64);   // dm of row quad*4+i
#pragma unroll
            for (int ct = 0; ct < 4; ct++) {
                float val = acc[ct][i] + bv[ct] + mb[(size_t)dmv * 64 + ct * 16 + m];
                wl[(quad * 4 + i) * 68 + ct * 16 + m] = val;
                ssum[ct] += (double)val;
                ssq[ct]  += (double)val * (double)val;
            }
        }
        asm volatile("s_waitcnt lgkmcnt(0)" ::: "memory");
#pragma unroll
        for (int j = 0; j < 4; j++) {
            int row = j * 4 + quad;
            f32x4 vv = *reinterpret_cast<const f32x4*>(wl + row * 68 + m * 4);
            unsigned int p0 = (unsigned int)f2bf(vv[0]) | ((unsigned int)f2bf(vv[1]) << 16);
            unsigned int p1 = (unsigned int)f2bf(vv[2]) | ((unsigned int)f2bf(vv[3]) << 16);
            uint2 pk; pk.x = p0; pk.y = p1;
            *reinterpret_cast<uint2*>(h2b + ((size_t)(tile << 4) + row) * 64 + m * 4) = pk;
        }
    }

    stats_block_out(&lds[0][0], lane, wid, ssum, ssq, part);
}

// ---------- agg[n] = relu(bn2(h2b[n])) + sum_{q in src-CSR} relu(bn2(h2b[NN+perm_s[q]])) ----------
__global__ void k_agg_csr(const unsigned short* __restrict__ h2b, const int* __restrict__ off_s,
                          const int* __restrict__ perm_s, const float* __restrict__ fin2,
                          const float* __restrict__ g2, const float* __restrict__ be2,
                          float* __restrict__ agg) {
    int n = (blockIdx.x * 256 + threadIdx.x) >> 6;
    int c = threadIdx.x & 63;
    float sc = fin2[64 + c] * g2[c];
    float sh = be2[c] - fin2[c] * sc;
    float a[16];
#pragma unroll
    for (int j = 0; j < 16; j++) a[j] = 0.f;
    a[0] = fmaxf(bf2f(h2b[(size_t)n * 64 + c]) * sc + sh, 0.f);   // self row
    int q = off_s[n], q1 = off_s[n + 1];
    for (; q + 15 < q1; q += 16)
#pragma unroll
        for (int j = 0; j < 16; j++) {
            float hv = bf2f(h2b[(size_t)(NN + perm_s[q + j]) * 64 + c]);
            a[j] += fmaxf(hv * sc + sh, 0.f);
        }
    for (; q + 3 < q1; q += 4)
#pragma unroll
        for (int j = 0; j < 4; j++) {
            float hv = bf2f(h2b[(size_t)(NN + perm_s[q + j]) * 64 + c]);
            a[j] += fmaxf(hv * sc + sh, 0.f);
        }
    for (; q < q1; q++) {
        float hv = bf2f(h2b[(size_t)(NN + perm_s[q]) * 64 + c]);
        a[0] += fmaxf(hv * sc + sh, 0.f);
    }
#pragma unroll
    for (int j = 0; j < 8; j++) a[j] += a[j + 8];
#pragma unroll
    for (int j = 0; j < 4; j++) a[j] += a[j + 4];
    agg[(size_t)n * 64 + c] = (a[0] + a[1]) + (a[2] + a[3]);
}

// ---------- stage 3: t_pre = [relu(bn2(h2b[:N])), agg] @ W_tr + b_tr, stats3 ----------
__global__ void k_mm3(const unsigned short* __restrict__ h2b, const float* __restrict__ agg,
                      const float* __restrict__ W, const float* __restrict__ bias,
                      const float* __restrict__ fin2, const float* __restrict__ g2,
                      const float* __restrict__ be2,
                      float* __restrict__ outp, double* __restrict__ part) {
    __shared__ float lds[4][16 * 68];
    const int lane = threadIdx.x & 63;
    const int wid = threadIdx.x >> 6;
    const int m = lane & 15, quad = lane >> 4;
    const int gwave = (blockIdx.x * blockDim.x + threadIdx.x) >> 6;
    const int nwaves = (gridDim.x * blockDim.x) >> 6;
    float* wl = lds[wid];

    bf16x8 wfh[4][4], wfl[4][4];
#pragma unroll
    for (int kk = 0; kk < 4; kk++)
#pragma unroll
        for (int ct = 0; ct < 4; ct++) {
            float wv[8];
#pragma unroll
            for (int j = 0; j < 8; j++)
                wv[j] = W[(kk * 32 + quad * 8 + j) * 64 + ct * 16 + m];
            split8r(wv, wfh[kk][ct], wfl[kk][ct]);
        }

    float bv[4];
#pragma unroll
    for (int ct = 0; ct < 4; ct++) bv[ct] = bias[ct * 16 + m];

    float s2f[2][8], t2f[2][8];
#pragma unroll
    for (int kk = 0; kk < 2; kk++)
#pragma unroll
        for (int j = 0; j < 8; j++) {
            int c = kk * 32 + quad * 8 + j;
            float sc = fin2[64 + c] * g2[c];
            s2f[kk][j] = sc;
            t2f[kk][j] = be2[c] - fin2[c] * sc;
        }

    double ssum[4] = {0,0,0,0}, ssq[4] = {0,0,0,0};

    for (int tile = gwave; tile < NT_N; tile += nwaves) {
        const int r = (tile << 4) + m;
        bf16x8 ah[4], al[4];
#pragma unroll
        for (int kk = 0; kk < 2; kk++) {
            bf16x8 hv = *reinterpret_cast<const bf16x8*>(h2b + (size_t)r * 64 + kk * 32 + quad * 8);
            float tv[8];
#pragma unroll
            for (int j = 0; j < 8; j++) {
                float f = bf2f((unsigned short)hv[j]);
                tv[j] = fmaxf(f * s2f[kk][j] + t2f[kk][j], 0.f);
            }
            split8r(tv, ah[kk], al[kk]);
        }
        split8(agg + (size_t)r * 64 + quad * 8,      ah[2], al[2]);
        split8(agg + (size_t)r * 64 + 32 + quad * 8, ah[3], al[3]);

        f32x4 zero = {0.f, 0.f, 0.f, 0.f};
        f32x4 acc[4];
#pragma unroll
        for (int ct = 0; ct < 4; ct++) {
            acc[ct] = zero;
#pragma unroll
            for (int kk = 0; kk < 4; kk++)
                acc[ct] = __builtin_amdgcn_mfma_f32_16x16x32_bf16(al[kk], wfh[kk][ct], acc[ct], 0, 0, 0);
#pragma unroll
            for (int kk = 0; kk < 4; kk++)
                acc[ct] = __builtin_amdgcn_mfma_f32_16x16x32_bf16(ah[kk], wfl[kk][ct], acc[ct], 0, 0, 0);
#pragma unroll
            for (int kk = 0; kk < 4; kk++)
                acc[ct] = __builtin_amdgcn_mfma_f32_16x16x32_bf16(ah[kk], wfh[kk][ct], acc[ct], 0, 0, 0);
        }

        epi_tile<false, true>(wl, lane, acc, bv, outp, tile, ssum, ssq);
    }

    stats_block_out(&lds[0][0], lane, wid, ssum, ssq, part);
}

// ---------- stage 4 ----------
__global__ void k_mm4(const float* __restrict__ tpre, const float* __restrict__ W,
                      const float* __restrict__ bias, const float* __restrict__ fin3,
                      const float* __restrict__ g2, const float* __restrict__ be2,
                      float* __restrict__ outp, double* __restrict__ part) {
    __shared__ float lds[4][16 * 68];
    const int lane = threadIdx.x & 63;
    const int wid = threadIdx.x >> 6;
    const int m = lane & 15, quad = lane >> 4;
    const int gwave = (blockIdx.x * blockDim.x + threadIdx.x) >> 6;
    const int nwaves = (gridDim.x * blockDim.x) >> 6;
    float* wl = lds[wid];

    bf16x8 wfh[2][4], wfl[2][4];
#pragma unroll
    for (int kk = 0; kk < 2; kk++)
#pragma unroll
        for (int ct = 0; ct < 4; ct++) {
            float wv[8];
#pragma unroll
            for (int j = 0; j < 8; j++)
                wv[j] = W[(kk * 32 + quad * 8 + j) * 64 + ct * 16 + m];
            split8r(wv, wfh[kk][ct], wfl[kk][ct]);
        }

    float bv[4];
#pragma unroll
    for (int ct = 0; ct < 4; ct++) bv[ct] = bias[ct * 16 + m];

    float sc[2][8], sh[2][8];
#pragma unroll
    for (int kk = 0; kk < 2; kk++)
#pragma unroll
        for (int j = 0; j < 8; j++) {
            int c = kk * 32 + quad * 8 + j;
            float s = fin3[64 + c] * g2[c];
            sc[kk][j] = s;
            sh[kk][j] = be2[c] - fin3[c] * s;
        }

    double ssum[4] = {0,0,0,0}, ssq[4] = {0,0,0,0};

    for (int tile = gwave; tile < NT_N; tile += nwaves) {
        const int r = (tile << 4) + m;
        bf16x8 ah[2], al[2];
#pragma unroll
        for (int kk = 0; kk < 2; kk++) {
            f32x4 v0 = *reinterpret_cast<const f32x4*>(tpre + (size_t)r * 64 + kk * 32 + quad * 8);
            f32x4 v1 = *reinterpret_cast<const f32x4*>(tpre + (size_t)r * 64 + kk * 32 + quad * 8 + 4);
            float tv[8];
#pragma unroll
            for (int j = 0; j < 4; j++) {
                tv[j]     = fmaxf(v0[j] * sc[kk][j]     + sh[kk][j],     0.f);
                tv[4 + j] = fmaxf(v1[j] * sc[kk][4 + j] + sh[kk][4 + j], 0.f);
            }
            split8r(tv, ah[kk], al[kk]);
        }

        f32x4 zero = {0.f, 0.f, 0.f, 0.f};
        f32x4 acc[4];
#pragma unroll
        for (int ct = 0; ct < 4; ct++) {
            acc[ct] = zero;
#pragma unroll
            for (int kk = 0; kk < 2; kk++) {
                acc[ct] = __builtin_amdgcn_mfma_f32_16x16x32_bf16(al[kk], wfh[kk][ct], acc[ct], 0, 0, 0);
                acc[ct] = __builtin_amdgcn_mfma_f32_16x16x32_bf16(ah[kk], wfl[kk][ct], acc[ct], 0, 0, 0);
                acc[ct] = __builtin_amdgcn_mfma_f32_16x16x32_bf16(ah[kk], wfh[kk][ct], acc[ct], 0, 0, 0);
            }
        }

        epi_tile<true, true>(wl, lane, acc, bv, outp, tile, ssum, ssq);
    }

    stats_block_out(&lds[0][0], lane, wid, ssum, ssq, part);
}

// out = relu(bn(out_pre; stats4, g3, be3)) -> f32
__global__ void k_out(const float* __restrict__ op, const float* __restrict__ fin,
                      const float* __restrict__ g, const float* __restrict__ be,
                      float* __restrict__ out) {
    int i = blockIdx.x * 256 + threadIdx.x;   // covers NN*64 exactly
    int c = i & 63;
    out[i] = fmaxf((op[i] - fin[c]) * fin[64 + c] * g[c] + be[c], 0.f);
}

extern "C" void kernel_launch(void* const* d_in, const int* in_sizes, int n_in,
                              void* d_out, int out_size, void* d_ws, size_t ws_size,
                              hipStream_t stream) {
    const float* x    = (const float*)d_in[0];
    const int*   ei   = (const int*)d_in[1];
    const float* W_un = (const float*)d_in[2];
    const float* b_un = (const float*)d_in[3];
    const float* g1   = (const float*)d_in[4];
    const float* be1  = (const float*)d_in[5];
    const float* W_gc = (const float*)d_in[6];
    const float* b_gc = (const float*)d_in[7];
    const float* g2   = (const float*)d_in[8];
    const float* be2  = (const float*)d_in[9];
    const float* W_tr = (const float*)d_in[10];
    const float* b_tr = (const float*)d_in[11];
    const float* W_li = (const float*)d_in[12];
    const float* b_li = (const float*)d_in[13];
    const float* g3   = (const float*)d_in[14];
    const float* be3  = (const float*)d_in[15];

    float* ws = (float*)d_ws;
    const size_t FN = (size_t)NN * 64;           // 3.2M floats (12.8 MB)
    const size_t FR = (size_t)RR * 64;           // 54.4M floats (217.6 MB)
    // Region plan (zero growth vs R5; lifetimes verified):
    //  P0: u -> msg/mb (u dead after k_s1h) -> part_mm3 (mb dead after k_h2) -> outpre
    //  P1: v -> agg (v dead after k_s1h) -> part_mm4 (agg dead after k_mm3)
    //  P2: s_tab -> part_h2 (s_tab dead after k_msg_csr) -> tpre (partials consumed by k_red)
    //  H (FR floats): dsum(H), u2(H+FN) [dead after k_stats1a]
    //      -> hb (FR ushorts) + h2b (FR ushorts)
    float* P0 = ws;
    float* P1 = ws + FN;
    float* P2 = ws + 2 * FN;
    float* H  = ws + 3 * FN;
    float* u      = P0;
    float* v      = P1;
    float* s_tab  = P2;
    float* dsum   = H;
    float* u2     = H + FN;
    unsigned short* hb  = (unsigned short*)H;        // bf16 h rows
    unsigned short* h2b = (unsigned short*)H + FR;   // bf16 h2pre rows
    float* msg    = P0;           // becomes mb after k_mb (in place)
    float* agg    = P1;
    float* tpre   = P2;
    float* outpre = P0;
    double* part_h2 = (double*)P2;   // 2048*128*8B = 2MB   (before tpre)
    double* part_m3 = (double*)P0;   // 512*128*8B = 512KB  (mb dead, before outpre)
    double* part_m4 = (double*)P1;   // 512KB               (agg dead)
    double*       stats_raw = (double*)(H + FR);
    int*          od        = (int*)(stats_raw + 512);
    int*          id        = od + NN;
    int*          off       = id + NN;
    int*          cursor    = off + NN + 1;
    int*          off_s     = cursor + NN;
    int*          cursor_s  = off_s + NN + 1;
    unsigned int* sd_s      = (unsigned int*)(cursor_s + NN);   // packed src|dst<<16, dst-sorted
    int*          perm_s    = (int*)(sd_s + EE);
    float*        stats_fin = (float*)(perm_s + EE);

    // zero: stats_raw + od + id (contiguous)
    hipMemsetAsync(stats_raw, 0, 512 * sizeof(double) + 2 * NN * sizeof(int), stream);

    // build dst-sorted packed edge list + src-CSR permutation
    k_deg  <<<3125, 256,  0, stream>>>(ei, od, id);
    k_scan2<<<2,    1024, 0, stream>>>(id, off, cursor, od, off_s, cursor_s);
    k_fill <<<3125, 256,  0, stream>>>(ei, cursor, sd_s);
    k_fill2<<<3125, 256,  0, stream>>>(sd_s, cursor_s, perm_s);

    // stage 0 + per-node tables
    k_dsum_csr<<<12500, 256, 0, stream>>>(x, off, sd_s, dsum);
    k_uv3<<<512, 256, 0, stream>>>(x, dsum, W_un, u, v, u2);

    // stage-1: analytic stats, then CSR reduce + per-row bf16 h store
    k_stats1a<<<256, 256, 0, stream>>>(u, v, u2, od, id, stats_raw + 0);
    k_fin1<<<1, 64, 0, stream>>>(stats_raw + 0, b_un, stats_fin + 0, 1.0 / (double)RR);
    k_s1h<<<12500, 256, 0, stream>>>(u, v, off, sd_s, b_un, stats_fin + 0, g1, be1,
                                     s_tab, hb);
    k_msg_csr<<<12500, 256, 0, stream>>>(off, sd_s, s_tab, msg);
    k_mb<<<512, 256, 0, stream>>>(msg, msg, W_gc + 64 * 64);   // msg -> mb in place

    // stage-2: streaming matmul over bf16 h rows -> bf16 h2 rows, block-partial stats
    k_h2<<<NBLK_H2, 256, 0, stream>>>(hb, h2b, msg, sd_s, W_gc, b_gc, part_h2);
    k_red<<<32, 128, 0, stream>>>(part_h2, NBLK_H2, stats_raw + 128);
    k_fin<<<1, 64, 0, stream>>>(stats_raw + 128, stats_fin + 128, 1.0 / (double)RR);
    k_agg_csr<<<12500, 256, 0, stream>>>(h2b, off_s, perm_s, stats_fin + 128, g2, be2, agg);

    // stage 3
    k_mm3<<<NBLK_MM, 256, 0, stream>>>(h2b, agg, W_tr, b_tr, stats_fin + 128, g2, be2,
                                       tpre, part_m3);
    k_red<<<16, 128, 0, stream>>>(part_m3, NBLK_MM, stats_raw + 256);
    k_fin<<<1, 64, 0, stream>>>(stats_raw + 256, stats_fin + 256, 1.0 / (double)NN);

    // stage 4
    k_mm4<<<NBLK_MM, 256, 0, stream>>>(tpre, W_li, b_li, stats_fin + 256, g2, be2,
                                       outpre, part_m4);
    k_red<<<16, 128, 0, stream>>>(part_m4, NBLK_MM, stats_raw + 384);
    k_fin<<<1, 64, 0, stream>>>(stats_raw + 384, stats_fin + 384, 1.0 / (double)NN);

    k_out<<<12500, 256, 0, stream>>>(outpre, stats_fin + 384, g3, be3, (float*)d_out);
}

// Round 7
// 834.163 us; speedup vs baseline: 2.2297x; 1.0103x over previous
//
#include <hip/hip_runtime.h>
#include <cstdint>
#include <math.h>

// Problem sizes (fixed by the reference).
#define NN 50000
#define EE 800000
#define RR 850000      // NN + EE rows
#define NT_N 3125      // NN/16
#define NT_R 53125     // RR/16
#define NBLK_H2 2048
#define NBLK_MM 512

typedef short  bf16x8 __attribute__((ext_vector_type(8)));
typedef float  f32x4  __attribute__((ext_vector_type(4)));

__device__ __forceinline__ float bf2f(unsigned short b) {
    unsigned int u = ((unsigned int)b) << 16;
    return __builtin_bit_cast(float, u);
}
__device__ __forceinline__ unsigned short f2bf(float f) {
    unsigned int u = __builtin_bit_cast(unsigned int, f);
    u = u + 0x7fffu + ((u >> 16) & 1u);
    return (unsigned short)(u >> 16);
}
__device__ __forceinline__ void atomAddD(double* p, double v) { unsafeAtomicAdd(p, v); }
__device__ __forceinline__ int atomAddI(int* p, int v) { return atomicAdd(p, v); }

// split 8 consecutive f32 into hi/lo bf16 fragments: hi+lo == v to ~2^-16 rel
__device__ __forceinline__ void split8(const float* p, bf16x8& hi, bf16x8& lo) {
    f32x4 v0 = *reinterpret_cast<const f32x4*>(p);
    f32x4 v1 = *reinterpret_cast<const f32x4*>(p + 4);
#pragma unroll
    for (int j = 0; j < 4; j++) {
        unsigned short h0 = f2bf(v0[j]);
        hi[j] = (short)h0; lo[j] = (short)f2bf(v0[j] - bf2f(h0));
        unsigned short h1 = f2bf(v1[j]);
        hi[4 + j] = (short)h1; lo[4 + j] = (short)f2bf(v1[j] - bf2f(h1));
    }
}
__device__ __forceinline__ void split8r(const float* v, bf16x8& hi, bf16x8& lo) {
#pragma unroll
    for (int j = 0; j < 8; j++) {
        unsigned short h = f2bf(v[j]);
        hi[j] = (short)h; lo[j] = (short)f2bf(v[j] - bf2f(h));
    }
}

// LDS-staged coalesced tile store: MFMA C-layout -> 4x 1KB contiguous dwordx4 stores.
template <bool RELU, bool STATS>
__device__ __forceinline__ void epi_tile(float* wl, int lane, const f32x4* acc,
                                         const float* bv, float* __restrict__ gout,
                                         int tile, double* ssum, double* ssq) {
    const int m = lane & 15, quad = lane >> 4;
#pragma unroll
    for (int ct = 0; ct < 4; ct++)
#pragma unroll
        for (int i = 0; i < 4; i++) {
            float val = acc[ct][i] + bv[ct];
            if (RELU) val = fmaxf(val, 0.f);
            wl[(quad * 4 + i) * 68 + ct * 16 + m] = val;
            if (STATS) { ssum[ct] += (double)val; ssq[ct] += (double)val * (double)val; }
        }
    asm volatile("s_waitcnt lgkmcnt(0)" ::: "memory");
#pragma unroll
    for (int j = 0; j < 4; j++) {
        int row = j * 4 + quad;
        f32x4 vv = *reinterpret_cast<const f32x4*>(wl + row * 68 + m * 4);
        *reinterpret_cast<f32x4*>(gout + ((size_t)(tile << 4) + row) * 64 + m * 4) = vv;
    }
}

// block-level stats reduce: wave shfl-reduce -> LDS -> one coalesced 1KB store per block.
__device__ __forceinline__ void stats_block_out(float* ldsbase, int lane, int wid,
                                                const double* ssum, const double* ssq,
                                                double* __restrict__ part) {
    const int m = lane & 15, quad = lane >> 4;
    double* dl = (double*)ldsbase;
    __syncthreads();
#pragma unroll
    for (int ct = 0; ct < 4; ct++) {
        double sv = ssum[ct], qv = ssq[ct];
        sv += __shfl_xor(sv, 16, 64); sv += __shfl_xor(sv, 32, 64);
        qv += __shfl_xor(qv, 16, 64); qv += __shfl_xor(qv, 32, 64);
        if (quad == 0) {
            dl[wid * 128 + ct * 16 + m]      = sv;
            dl[wid * 128 + 64 + ct * 16 + m] = qv;
        }
    }
    __syncthreads();
    int tid = wid * 64 + lane;
    if (tid < 128) {
        double tot = dl[tid] + dl[128 + tid] + dl[256 + tid] + dl[384 + tid];
        part[(size_t)blockIdx.x * 128 + tid] = tot;
    }
}

// reduce block partials into raw[0..127] (few spread atomics only)
__global__ void k_red(const double* __restrict__ p, int nblk, double* __restrict__ raw) {
    int t = threadIdx.x;   // 128
    double acc = 0.0;
    for (int b = blockIdx.x; b < nblk; b += gridDim.x)
        acc += p[(size_t)b * 128 + t];
    atomAddD(&raw[t], acc);
}

// ---------- degree counts ----------
__global__ void k_deg(const int* __restrict__ ei, int* __restrict__ od, int* __restrict__ id) {
    int e = blockIdx.x * 256 + threadIdx.x;   // covers EE exactly
    atomAddI(&od[ei[e]], 1);
    atomAddI(&id[ei[EE + e]], 1);
}

// ---------- dual exclusive scan (block 0: dst-CSR, block 1: src-CSR) ----------
// Hillis-Steele parallel scan over 1024 per-thread partials (was: serial loop in t0,
// 1024 dependent LDS RMWs ~ 105us; now 10 log-steps).
__global__ void __launch_bounds__(1024) k_scan2(const int* __restrict__ id, int* __restrict__ off,
                                                int* __restrict__ cursor,
                                                const int* __restrict__ od, int* __restrict__ off_s,
                                                int* __restrict__ cursor_s) {
    const int* cnt = (blockIdx.x == 0) ? id : od;
    int* o  = (blockIdx.x == 0) ? off : off_s;
    int* cu = (blockIdx.x == 0) ? cursor : cursor_s;
    __shared__ int part[1024];
    const int t = threadIdx.x;
    const int CH = (NN + 1023) / 1024;
    int base = t * CH, s = 0;
    for (int i = 0; i < CH; i++) { int idx = base + i; if (idx < NN) s += cnt[idx]; }
    part[t] = s;
    __syncthreads();
#pragma unroll
    for (int d = 1; d < 1024; d <<= 1) {
        int val = (t >= d) ? part[t - d] : 0;
        __syncthreads();
        part[t] += val;
        __syncthreads();
    }
    int run = (t == 0) ? 0 : part[t - 1];   // exclusive prefix of this thread's chunk
    for (int i = 0; i < CH; i++) {
        int idx = base + i;
        if (idx < NN) { o[idx] = run; cu[idx] = run; run += cnt[idx]; }
    }
    if (t == 0) o[NN] = EE;
}

// ---------- fill dst-sorted packed edge array: sd = src | (dst<<16) ----------
__global__ void k_fill(const int* __restrict__ ei, int* __restrict__ cursor,
                       unsigned int* __restrict__ sd_s) {
    int e = blockIdx.x * 256 + threadIdx.x;   // covers EE exactly
    int s = ei[e], d = ei[EE + e];
    int p = atomAddI(&cursor[d], 1);
    sd_s[p] = (unsigned int)s | ((unsigned int)d << 16);
}

// ---------- fill src-CSR permutation: perm_s[q] = dst-order position p ----------
__global__ void k_fill2(const unsigned int* __restrict__ sd_s, int* __restrict__ cursor_s,
                        int* __restrict__ perm_s) {
    int p = blockIdx.x * 256 + threadIdx.x;   // covers EE exactly
    int s = (int)(sd_s[p] & 0xFFFFu);
    int q = atomAddI(&cursor_s[s], 1);
    perm_s[q] = p;
}

// ---------- dsum[n] = x[n] + sum_{e: dst=n} x[src_e]  (CSR, no atomics, 16-way MLP) ----------
__global__ void k_dsum_csr(const float* __restrict__ x, const int* __restrict__ off,
                           const unsigned int* __restrict__ sd_s, float* __restrict__ dsum) {
    int team = (blockIdx.x * 256 + threadIdx.x) >> 6;   // 12500 blocks x 4 = NN
    int c = threadIdx.x & 63;
    float a[16];
#pragma unroll
    for (int j = 0; j < 16; j++) a[j] = 0.f;
    a[0] = x[(size_t)team * 64 + c];
    int e = off[team], e1 = off[team + 1];
    for (; e + 15 < e1; e += 16)
#pragma unroll
        for (int j = 0; j < 16; j++) a[j] += x[(size_t)(sd_s[e + j] & 0xFFFFu) * 64 + c];
    for (; e + 3 < e1; e += 4)
#pragma unroll
        for (int j = 0; j < 4; j++) a[j] += x[(size_t)(sd_s[e + j] & 0xFFFFu) * 64 + c];
    for (; e < e1; e++) a[0] += x[(size_t)(sd_s[e] & 0xFFFFu) * 64 + c];
#pragma unroll
    for (int j = 0; j < 8; j++) a[j] += a[j + 8];
#pragma unroll
    for (int j = 0; j < 4; j++) a[j] += a[j + 4];
    dsum[(size_t)team * 64 + c] = (a[0] + a[1]) + (a[2] + a[3]);
}

// ---------- u = x@W_top, v = dsum@W_bot, u2 = dsum@W_top ----------
__global__ void k_uv3(const float* __restrict__ x, const float* __restrict__ dsum,
                      const float* __restrict__ W, float* __restrict__ u,
                      float* __restrict__ v, float* __restrict__ u2) {
    __shared__ float lds[4][16 * 68];
    const int lane = threadIdx.x & 63;
    const int wid = threadIdx.x >> 6;
    const int m = lane & 15, quad = lane >> 4;
    const int gwave = (blockIdx.x * blockDim.x + threadIdx.x) >> 6;
    const int nwaves = (gridDim.x * blockDim.x) >> 6;
    float* wl = lds[wid];

    bf16x8 wfh[4][4], wfl[4][4];
#pragma unroll
    for (int kk = 0; kk < 4; kk++)
#pragma unroll
        for (int ct = 0; ct < 4; ct++) {
            float wv[8];
#pragma unroll
            for (int j = 0; j < 8; j++)
                wv[j] = W[(kk * 32 + quad * 8 + j) * 64 + ct * 16 + m];
            split8r(wv, wfh[kk][ct], wfl[kk][ct]);
        }
    float zb[4] = {0.f, 0.f, 0.f, 0.f};

    for (int tile = gwave; tile < NT_N; tile += nwaves) {
        const int r = (tile << 4) + m;
        bf16x8 ah[4], al[4];
        split8(x    + (size_t)r * 64 + quad * 8,      ah[0], al[0]);
        split8(x    + (size_t)r * 64 + 32 + quad * 8, ah[1], al[1]);
        split8(dsum + (size_t)r * 64 + quad * 8,      ah[2], al[2]);
        split8(dsum + (size_t)r * 64 + 32 + quad * 8, ah[3], al[3]);

        f32x4 zero = {0.f, 0.f, 0.f, 0.f};
        f32x4 aU[4], aV[4], aU2[4];
#pragma unroll
        for (int ct = 0; ct < 4; ct++) {
            aU[ct] = zero; aV[ct] = zero; aU2[ct] = zero;
#pragma unroll
            for (int kk = 0; kk < 2; kk++) {
                aU[ct]  = __builtin_amdgcn_mfma_f32_16x16x32_bf16(al[kk],   wfh[kk][ct],   aU[ct],  0, 0, 0);
                aU[ct]  = __builtin_amdgcn_mfma_f32_16x16x32_bf16(ah[kk],   wfl[kk][ct],   aU[ct],  0, 0, 0);
                aU[ct]  = __builtin_amdgcn_mfma_f32_16x16x32_bf16(ah[kk],   wfh[kk][ct],   aU[ct],  0, 0, 0);
                aV[ct]  = __builtin_amdgcn_mfma_f32_16x16x32_bf16(al[kk+2], wfh[kk+2][ct], aV[ct],  0, 0, 0);
                aV[ct]  = __builtin_amdgcn_mfma_f32_16x16x32_bf16(ah[kk+2], wfl[kk+2][ct], aV[ct],  0, 0, 0);
                aV[ct]  = __builtin_amdgcn_mfma_f32_16x16x32_bf16(ah[kk+2], wfh[kk+2][ct], aV[ct],  0, 0, 0);
                aU2[ct] = __builtin_amdgcn_mfma_f32_16x16x32_bf16(al[kk+2], wfh[kk][ct],   aU2[ct], 0, 0, 0);
                aU2[ct] = __builtin_amdgcn_mfma_f32_16x16x32_bf16(ah[kk+2], wfl[kk][ct],   aU2[ct], 0, 0, 0);
                aU2[ct] = __builtin_amdgcn_mfma_f32_16x16x32_bf16(ah[kk+2], wfh[kk][ct],   aU2[ct], 0, 0, 0);
            }
        }
        epi_tile<false, false>(wl, lane, aU,  zb, u,  tile, nullptr, nullptr);
        epi_tile<false, false>(wl, lane, aV,  zb, v,  tile, nullptr, nullptr);
        epi_tile<false, false>(wl, lane, aU2, zb, u2, tile, nullptr, nullptr);
    }
}

// ---------- analytic stage-1 stats ----------
__global__ void k_stats1a(const float* __restrict__ u, const float* __restrict__ v,
                          const float* __restrict__ u2, const int* __restrict__ od,
                          const int* __restrict__ id, double* __restrict__ stats_raw) {
    __shared__ double lsum[4][64], lsq[4][64];
    int tid = threadIdx.x, c = tid & 63, w = tid >> 6;
    double a1 = 0.0, a2 = 0.0;
    for (int n = blockIdx.x * 4 + w; n < NN; n += gridDim.x * 4) {
        double uu = u[(size_t)n * 64 + c], vv = v[(size_t)n * 64 + c];
        double uu2 = u2[(size_t)n * 64 + c];
        double wod = 1.0 + od[n], wid = 1.0 + id[n];
        a1 += wod * uu + wid * vv;
        a2 += wod * uu * uu + wid * vv * vv + 2.0 * vv * uu2;
    }
    lsum[w][c] = a1; lsq[w][c] = a2;
    __syncthreads();
    if (w == 0) {
        a1 = lsum[0][c] + lsum[1][c] + lsum[2][c] + lsum[3][c];
        a2 = lsq[0][c] + lsq[1][c] + lsq[2][c] + lsq[3][c];
        atomAddD(&stats_raw[c], a1);
        atomAddD(&stats_raw[64 + c], a2);
    }
}

__global__ void k_fin1(const double* __restrict__ raw, const float* __restrict__ b,
                       float* __restrict__ fin, double inv_cnt) {
    int c = threadIdx.x;
    double m1 = raw[c] * inv_cnt;
    double var = raw[64 + c] * inv_cnt - m1 * m1;
    if (var < 0.0) var = 0.0;
    fin[c] = (float)(m1 + (double)b[c]);
    fin[64 + c] = (float)(1.0 / sqrt(var + 1e-5));
}

__global__ void k_fin(const double* __restrict__ raw, float* __restrict__ fin, double inv_cnt) {
    int c = threadIdx.x;
    double mean = raw[c] * inv_cnt;
    double var = raw[64 + c] * inv_cnt - mean * mean;
    if (var < 0.0) var = 0.0;
    fin[c] = (float)mean;
    fin[64 + c] = (float)(1.0 / sqrt(var + 1e-5));
}

// ---------- stage-1 reduce + per-row h store in BF16 (16-way MLP gather preserved) ----------
__global__ void k_s1h(const float* __restrict__ u, const float* __restrict__ v,
                      const int* __restrict__ off, const unsigned int* __restrict__ sd_s,
                      const float* __restrict__ b_un, const float* __restrict__ fin,
                      const float* __restrict__ g1, const float* __restrict__ be1,
                      float* __restrict__ s_tab, unsigned short* __restrict__ hb) {
    int team = (blockIdx.x * 256 + threadIdx.x) >> 6;
    int c = threadIdx.x & 63;
    float sc = fin[64 + c] * g1[c];
    float tsh = (b_un[c] - fin[c]) * sc + be1[c];
    float vn = v[(size_t)team * 64 + c];
    float a[16];
#pragma unroll
    for (int j = 0; j < 16; j++) a[j] = 0.f;
    float hs = fmaxf((u[(size_t)team * 64 + c] + vn) * sc + tsh, 0.f);   // self row
    a[0] = hs;
    hb[(size_t)team * 64 + c] = f2bf(hs);
    int e = off[team], e1 = off[team + 1];
    for (; e + 15 < e1; e += 16)
#pragma unroll
        for (int j = 0; j < 16; j++) {
            float h = fmaxf((u[(size_t)(sd_s[e + j] & 0xFFFFu) * 64 + c] + vn) * sc + tsh, 0.f);
            a[j] += h;
            hb[(size_t)(NN + e + j) * 64 + c] = f2bf(h);
        }
    for (; e + 3 < e1; e += 4)
#pragma unroll
        for (int j = 0; j < 4; j++) {
            float h = fmaxf((u[(size_t)(sd_s[e + j] & 0xFFFFu) * 64 + c] + vn) * sc + tsh, 0.f);
            a[j] += h;
            hb[(size_t)(NN + e + j) * 64 + c] = f2bf(h);
        }
    for (; e < e1; e++) {
        float h = fmaxf((u[(size_t)(sd_s[e] & 0xFFFFu) * 64 + c] + vn) * sc + tsh, 0.f);
        a[0] += h;
        hb[(size_t)(NN + e) * 64 + c] = f2bf(h);
    }
#pragma unroll
    for (int j = 0; j < 8; j++) a[j] += a[j + 8];
#pragma unroll
    for (int j = 0; j < 4; j++) a[j] += a[j + 4];
    s_tab[(size_t)team * 64 + c] = (a[0] + a[1]) + (a[2] + a[3]);
}

// ---------- msg[n] = sum_{e:dst=n} s_tab[src_e] ----------
__global__ void k_msg_csr(const int* __restrict__ off, const unsigned int* __restrict__ sd_s,
                          const float* __restrict__ s_tab, float* __restrict__ msg) {
    int team = (blockIdx.x * 256 + threadIdx.x) >> 6;
    int c = threadIdx.x & 63;
    float a[16];
#pragma unroll
    for (int j = 0; j < 16; j++) a[j] = 0.f;
    int e = off[team], e1 = off[team + 1];
    for (; e + 15 < e1; e += 16)
#pragma unroll
        for (int j = 0; j < 16; j++) a[j] += s_tab[(size_t)(sd_s[e + j] & 0xFFFFu) * 64 + c];
    for (; e + 3 < e1; e += 4)
#pragma unroll
        for (int j = 0; j < 4; j++) a[j] += s_tab[(size_t)(sd_s[e + j] & 0xFFFFu) * 64 + c];
    for (; e < e1; e++) a[0] += s_tab[(size_t)(sd_s[e] & 0xFFFFu) * 64 + c];
#pragma unroll
    for (int j = 0; j < 8; j++) a[j] += a[j + 8];
#pragma unroll
    for (int j = 0; j < 4; j++) a[j] += a[j + 4];
    msg[(size_t)team * 64 + c] = (a[0] + a[1]) + (a[2] + a[3]);
}

// ---------- mb = msg @ W_gc[64:128]  (streaming; in/out may differ) ----------
__global__ void k_mb(const float* __restrict__ in, float* __restrict__ outp,
                     const float* __restrict__ W) {
    __shared__ float lds[4][16 * 68];
    const int lane = threadIdx.x & 63;
    const int wid = threadIdx.x >> 6;
    const int m = lane & 15, quad = lane >> 4;
    const int gwave = (blockIdx.x * blockDim.x + threadIdx.x) >> 6;
    const int nwaves = (gridDim.x * blockDim.x) >> 6;
    float* wl = lds[wid];

    bf16x8 wfh[2][4], wfl[2][4];
#pragma unroll
    for (int kk = 0; kk < 2; kk++)
#pragma unroll
        for (int ct = 0; ct < 4; ct++) {
            float wv[8];
#pragma unroll
            for (int j = 0; j < 8; j++)
                wv[j] = W[(kk * 32 + quad * 8 + j) * 64 + ct * 16 + m];
            split8r(wv, wfh[kk][ct], wfl[kk][ct]);
        }
    float zb[4] = {0.f, 0.f, 0.f, 0.f};

    for (int tile = gwave; tile < NT_N; tile += nwaves) {
        const int r = (tile << 4) + m;
        bf16x8 ah[2], al[2];
        split8(in + (size_t)r * 64 + quad * 8,      ah[0], al[0]);
        split8(in + (size_t)r * 64 + 32 + quad * 8, ah[1], al[1]);

        f32x4 zero = {0.f, 0.f, 0.f, 0.f};
        f32x4 acc[4];
#pragma unroll
        for (int ct = 0; ct < 4; ct++) {
            acc[ct] = zero;
#pragma unroll
            for (int kk = 0; kk < 2; kk++) {
                acc[ct] = __builtin_amdgcn_mfma_f32_16x16x32_bf16(al[kk], wfh[kk][ct], acc[ct], 0, 0, 0);
                acc[ct] = __builtin_amdgcn_mfma_f32_16x16x32_bf16(ah[kk], wfl[kk][ct], acc[ct], 0, 0, 0);
                acc[ct] = __builtin_amdgcn_mfma_f32_16x16x32_bf16(ah[kk], wfh[kk][ct], acc[ct], 0, 0, 0);
            }
        }
        epi_tile<false, false>(wl, lane, acc, zb, outp, tile, nullptr, nullptr);
    }
}

// ---------- stage-2 streaming matmul over bf16 h rows:
// h2b[r] = bf16( hb[r]@Wtop2 + mb[dst(r)] + b_gc ); stats via block partials (no atomics).
__global__ void k_h2(const unsigned short* __restrict__ hb, unsigned short* __restrict__ h2b,
                     const float* __restrict__ mb, const unsigned int* __restrict__ sd_s,
                     const float* __restrict__ W, const float* __restrict__ b_gc,
                     double* __restrict__ part) {
    __shared__ float lds[4][16 * 68];
    const int lane = threadIdx.x & 63;
    const int wid = threadIdx.x >> 6;
    const int m = lane & 15, quad = lane >> 4;
    const int gwave = (blockIdx.x * blockDim.x + threadIdx.x) >> 6;
    const int nwaves = (gridDim.x * blockDim.x) >> 6;
    float* wl = lds[wid];

    bf16x8 wfh[2][4], wfl[2][4];
#pragma unroll
    for (int kk = 0; kk < 2; kk++)
#pragma unroll
        for (int ct = 0; ct < 4; ct++) {
            float wv[8];
#pragma unroll
            for (int j = 0; j < 8; j++)
                wv[j] = W[(kk * 32 + quad * 8 + j) * 64 + ct * 16 + m];
            split8r(wv, wfh[kk][ct], wfl[kk][ct]);
        }

    float bv[4];
#pragma unroll
    for (int ct = 0; ct < 4; ct++) bv[ct] = b_gc[ct * 16 + m];

    double ssum[4] = {0,0,0,0}, ssq[4] = {0,0,0,0};

    for (int tile = gwave; tile < NT_R; tile += nwaves) {
        const int r = (tile << 4) + m;
        int dm = (tile < NT_N) ? r : (int)(sd_s[r - NN] >> 16);

        bf16x8 ah[2];
        ah[0] = *reinterpret_cast<const bf16x8*>(hb + (size_t)r * 64 + quad * 8);
        ah[1] = *reinterpret_cast<const bf16x8*>(hb + (size_t)r * 64 + 32 + quad * 8);

        f32x4 zero = {0.f, 0.f, 0.f, 0.f};
        f32x4 acc[4];
#pragma unroll
        for (int ct = 0; ct < 4; ct++) {
            acc[ct] = zero;
#pragma unroll
            for (int kk = 0; kk < 2; kk++) {
                acc[ct] = __builtin_amdgcn_mfma_f32_16x16x32_bf16(ah[kk], wfl[kk][ct], acc[ct], 0, 0, 0);
                acc[ct] = __builtin_amdgcn_mfma_f32_16x16x32_bf16(ah[kk], wfh[kk][ct], acc[ct], 0, 0, 0);
            }
        }

        // add mb[dst_of_row] + b_gc per element, then stats + LDS-coalesced bf16 store
#pragma unroll
        for (int i = 0; i < 4; i++) {
            int dmv = __shfl(dm, (lane & 48) + quad * 4 + i, 64);   // dm of row quad*4+i
#pragma unroll
            for (int ct = 0; ct < 4; ct++) {
                float val = acc[ct][i] + bv[ct] + mb[(size_t)dmv * 64 + ct * 16 + m];
                wl[(quad * 4 + i) * 68 + ct * 16 + m] = val;
                ssum[ct] += (double)val;
                ssq[ct]  += (double)val * (double)val;
            }
        }
        asm volatile("s_waitcnt lgkmcnt(0)" ::: "memory");
#pragma unroll
        for (int j = 0; j < 4; j++) {
            int row = j * 4 + quad;
            f32x4 vv = *reinterpret_cast<const f32x4*>(wl + row * 68 + m * 4);
            unsigned int p0 = (unsigned int)f2bf(vv[0]) | ((unsigned int)f2bf(vv[1]) << 16);
            unsigned int p1 = (unsigned int)f2bf(vv[2]) | ((unsigned int)f2bf(vv[3]) << 16);
            uint2 pk; pk.x = p0; pk.y = p1;
            *reinterpret_cast<uint2*>(h2b + ((size_t)(tile << 4) + row) * 64 + m * 4) = pk;
        }
    }

    stats_block_out(&lds[0][0], lane, wid, ssum, ssq, part);
}

// ---------- agg[n] = relu(bn2(h2b[n])) + sum_{q in src-CSR} relu(bn2(h2b[NN+perm_s[q]])) ----------
__global__ void k_agg_csr(const unsigned short* __restrict__ h2b, const int* __restrict__ off_s,
                          const int* __restrict__ perm_s, const float* __restrict__ fin2,
                          const float* __restrict__ g2, const float* __restrict__ be2,
                          float* __restrict__ agg) {
    int n = (blockIdx.x * 256 + threadIdx.x) >> 6;
    int c = threadIdx.x & 63;
    float sc = fin2[64 + c] * g2[c];
    float sh = be2[c] - fin2[c] * sc;
    float a[16];
#pragma unroll
    for (int j = 0; j < 16; j++) a[j] = 0.f;
    a[0] = fmaxf(bf2f(h2b[(size_t)n * 64 + c]) * sc + sh, 0.f);   // self row
    int q = off_s[n], q1 = off_s[n + 1];
    for (; q + 15 < q1; q += 16)
#pragma unroll
        for (int j = 0; j < 16; j++) {
            float hv = bf2f(h2b[(size_t)(NN + perm_s[q + j]) * 64 + c]);
            a[j] += fmaxf(hv * sc + sh, 0.f);
        }
    for (; q + 3 < q1; q += 4)
#pragma unroll
        for (int j = 0; j < 4; j++) {
            float hv = bf2f(h2b[(size_t)(NN + perm_s[q + j]) * 64 + c]);
            a[j] += fmaxf(hv * sc + sh, 0.f);
        }
    for (; q < q1; q++) {
        float hv = bf2f(h2b[(size_t)(NN + perm_s[q]) * 64 + c]);
        a[0] += fmaxf(hv * sc + sh, 0.f);
    }
#pragma unroll
    for (int j = 0; j < 8; j++) a[j] += a[j + 8];
#pragma unroll
    for (int j = 0; j < 4; j++) a[j] += a[j + 4];
    agg[(size_t)n * 64 + c] = (a[0] + a[1]) + (a[2] + a[3]);
}

// ---------- stage 3: t_pre = [relu(bn2(h2b[:N])), agg] @ W_tr + b_tr, stats3 ----------
__global__ void k_mm3(const unsigned short* __restrict__ h2b, const float* __restrict__ agg,
                      const float* __restrict__ W, const float* __restrict__ bias,
                      const float* __restrict__ fin2, const float* __restrict__ g2,
                      const float* __restrict__ be2,
                      float* __restrict__ outp, double* __restrict__ part) {
    __shared__ float lds[4][16 * 68];
    const int lane = threadIdx.x & 63;
    const int wid = threadIdx.x >> 6;
    const int m = lane & 15, quad = lane >> 4;
    const int gwave = (blockIdx.x * blockDim.x + threadIdx.x) >> 6;
    const int nwaves = (gridDim.x * blockDim.x) >> 6;
    float* wl = lds[wid];

    bf16x8 wfh[4][4], wfl[4][4];
#pragma unroll
    for (int kk = 0; kk < 4; kk++)
#pragma unroll
        for (int ct = 0; ct < 4; ct++) {
            float wv[8];
#pragma unroll
            for (int j = 0; j < 8; j++)
                wv[j] = W[(kk * 32 + quad * 8 + j) * 64 + ct * 16 + m];
            split8r(wv, wfh[kk][ct], wfl[kk][ct]);
        }

    float bv[4];
#pragma unroll
    for (int ct = 0; ct < 4; ct++) bv[ct] = bias[ct * 16 + m];

    float s2f[2][8], t2f[2][8];
#pragma unroll
    for (int kk = 0; kk < 2; kk++)
#pragma unroll
        for (int j = 0; j < 8; j++) {
            int c = kk * 32 + quad * 8 + j;
            float sc = fin2[64 + c] * g2[c];
            s2f[kk][j] = sc;
            t2f[kk][j] = be2[c] - fin2[c] * sc;
        }

    double ssum[4] = {0,0,0,0}, ssq[4] = {0,0,0,0};

    for (int tile = gwave; tile < NT_N; tile += nwaves) {
        const int r = (tile << 4) + m;
        bf16x8 ah[4], al[4];
#pragma unroll
        for (int kk = 0; kk < 2; kk++) {
            bf16x8 hv = *reinterpret_cast<const bf16x8*>(h2b + (size_t)r * 64 + kk * 32 + quad * 8);
            float tv[8];
#pragma unroll
            for (int j = 0; j < 8; j++) {
                float f = bf2f((unsigned short)hv[j]);
                tv[j] = fmaxf(f * s2f[kk][j] + t2f[kk][j], 0.f);
            }
            split8r(tv, ah[kk], al[kk]);
        }
        split8(agg + (size_t)r * 64 + quad * 8,      ah[2], al[2]);
        split8(agg + (size_t)r * 64 + 32 + quad * 8, ah[3], al[3]);

        f32x4 zero = {0.f, 0.f, 0.f, 0.f};
        f32x4 acc[4];
#pragma unroll
        for (int ct = 0; ct < 4; ct++) {
            acc[ct] = zero;
#pragma unroll
            for (int kk = 0; kk < 4; kk++)
                acc[ct] = __builtin_amdgcn_mfma_f32_16x16x32_bf16(al[kk], wfh[kk][ct], acc[ct], 0, 0, 0);
#pragma unroll
            for (int kk = 0; kk < 4; kk++)
                acc[ct] = __builtin_amdgcn_mfma_f32_16x16x32_bf16(ah[kk], wfl[kk][ct], acc[ct], 0, 0, 0);
#pragma unroll
            for (int kk = 0; kk < 4; kk++)
                acc[ct] = __builtin_amdgcn_mfma_f32_16x16x32_bf16(ah[kk], wfh[kk][ct], acc[ct], 0, 0, 0);
        }

        epi_tile<false, true>(wl, lane, acc, bv, outp, tile, ssum, ssq);
    }

    stats_block_out(&lds[0][0], lane, wid, ssum, ssq, part);
}

// ---------- stage 4 ----------
__global__ void k_mm4(const float* __restrict__ tpre, const float* __restrict__ W,
                      const float* __restrict__ bias, const float* __restrict__ fin3,
                      const float* __restrict__ g2, const float* __restrict__ be2,
                      float* __restrict__ outp, double* __restrict__ part) {
    __shared__ float lds[4][16 * 68];
    const int lane = threadIdx.x & 63;
    const int wid = threadIdx.x >> 6;
    const int m = lane & 15, quad = lane >> 4;
    const int gwave = (blockIdx.x * blockDim.x + threadIdx.x) >> 6;
    const int nwaves = (gridDim.x * blockDim.x) >> 6;
    float* wl = lds[wid];

    bf16x8 wfh[2][4], wfl[2][4];
#pragma unroll
    for (int kk = 0; kk < 2; kk++)
#pragma unroll
        for (int ct = 0; ct < 4; ct++) {
            float wv[8];
#pragma unroll
            for (int j = 0; j < 8; j++)
                wv[j] = W[(kk * 32 + quad * 8 + j) * 64 + ct * 16 + m];
            split8r(wv, wfh[kk][ct], wfl[kk][ct]);
        }

    float bv[4];
#pragma unroll
    for (int ct = 0; ct < 4; ct++) bv[ct] = bias[ct * 16 + m];

    float sc[2][8], sh[2][8];
#pragma unroll
    for (int kk = 0; kk < 2; kk++)
#pragma unroll
        for (int j = 0; j < 8; j++) {
            int c = kk * 32 + quad * 8 + j;
            float s = fin3[64 + c] * g2[c];
            sc[kk][j] = s;
            sh[kk][j] = be2[c] - fin3[c] * s;
        }

    double ssum[4] = {0,0,0,0}, ssq[4] = {0,0,0,0};

    for (int tile = gwave; tile < NT_N; tile += nwaves) {
        const int r = (tile << 4) + m;
        bf16x8 ah[2], al[2];
#pragma unroll
        for (int kk = 0; kk < 2; kk++) {
            f32x4 v0 = *reinterpret_cast<const f32x4*>(tpre + (size_t)r * 64 + kk * 32 + quad * 8);
            f32x4 v1 = *reinterpret_cast<const f32x4*>(tpre + (size_t)r * 64 + kk * 32 + quad * 8 + 4);
            float tv[8];
#pragma unroll
            for (int j = 0; j < 4; j++) {
                tv[j]     = fmaxf(v0[j] * sc[kk][j]     + sh[kk][j],     0.f);
                tv[4 + j] = fmaxf(v1[j] * sc[kk][4 + j] + sh[kk][4 + j], 0.f);
            }
            split8r(tv, ah[kk], al[kk]);
        }

        f32x4 zero = {0.f, 0.f, 0.f, 0.f};
        f32x4 acc[4];
#pragma unroll
        for (int ct = 0; ct < 4; ct++) {
            acc[ct] = zero;
#pragma unroll
            for (int kk = 0; kk < 2; kk++) {
                acc[ct] = __builtin_amdgcn_mfma_f32_16x16x32_bf16(al[kk], wfh[kk][ct], acc[ct], 0, 0, 0);
                acc[ct] = __builtin_amdgcn_mfma_f32_16x16x32_bf16(ah[kk], wfl[kk][ct], acc[ct], 0, 0, 0);
                acc[ct] = __builtin_amdgcn_mfma_f32_16x16x32_bf16(ah[kk], wfh[kk][ct], acc[ct], 0, 0, 0);
            }
        }

        epi_tile<true, true>(wl, lane, acc, bv, outp, tile, ssum, ssq);
    }

    stats_block_out(&lds[0][0], lane, wid, ssum, ssq, part);
}

// out = relu(bn(out_pre; stats4, g3, be3)) -> f32
__global__ void k_out(const float* __restrict__ op, const float* __restrict__ fin,
                      const float* __restrict__ g, const float* __restrict__ be,
                      float* __restrict__ out) {
    int i = blockIdx.x * 256 + threadIdx.x;   // covers NN*64 exactly
    int c = i & 63;
    out[i] = fmaxf((op[i] - fin[c]) * fin[64 + c] * g[c] + be[c], 0.f);
}

extern "C" void kernel_launch(void* const* d_in, const int* in_sizes, int n_in,
                              void* d_out, int out_size, void* d_ws, size_t ws_size,
                              hipStream_t stream) {
    const float* x    = (const float*)d_in[0];
    const int*   ei   = (const int*)d_in[1];
    const float* W_un = (const float*)d_in[2];
    const float* b_un = (const float*)d_in[3];
    const float* g1   = (const float*)d_in[4];
    const float* be1  = (const float*)d_in[5];
    const float* W_gc = (const float*)d_in[6];
    const float* b_gc = (const float*)d_in[7];
    const float* g2   = (const float*)d_in[8];
    const float* be2  = (const float*)d_in[9];
    const float* W_tr = (const float*)d_in[10];
    const float* b_tr = (const float*)d_in[11];
    const float* W_li = (const float*)d_in[12];
    const float* b_li = (const float*)d_in[13];
    const float* g3   = (const float*)d_in[14];
    const float* be3  = (const float*)d_in[15];

    float* ws = (float*)d_ws;
    const size_t FN = (size_t)NN * 64;           // 3.2M floats (12.8 MB)
    const size_t FR = (size_t)RR * 64;           // 54.4M floats (217.6 MB)
    // Region plan (zero growth; lifetimes verified):
    //  P0: u -> msg/mb (u dead after k_s1h) -> part_mm3 (mb dead after k_h2) -> outpre
    //  P1: v -> agg (v dead after k_s1h) -> part_mm4 (agg dead after k_mm3)
    //  P2: s_tab -> part_h2 (s_tab dead after k_msg_csr) -> tpre (partials consumed by k_red)
    //  H (FR floats): dsum(H), u2(H+FN) [dead after k_stats1a]
    //      -> hb (FR ushorts) + h2b (FR ushorts)
    float* P0 = ws;
    float* P1 = ws + FN;
    float* P2 = ws + 2 * FN;
    float* H  = ws + 3 * FN;
    float* u      = P0;
    float* v      = P1;
    float* s_tab  = P2;
    float* dsum   = H;
    float* u2     = H + FN;
    unsigned short* hb  = (unsigned short*)H;        // bf16 h rows
    unsigned short* h2b = (unsigned short*)H + FR;   // bf16 h2pre rows
    float* msg    = P0;           // becomes mb after k_mb (in place)
    float* agg    = P1;
    float* tpre   = P2;
    float* outpre = P0;
    double* part_h2 = (double*)P2;   // 2048*128*8B = 2MB   (before tpre)
    double* part_m3 = (double*)P0;   // 512*128*8B = 512KB  (mb dead, before outpre)
    double* part_m4 = (double*)P1;   // 512KB               (agg dead)
    double*       stats_raw = (double*)(H + FR);
    int*          od        = (int*)(stats_raw + 512);
    int*          id        = od + NN;
    int*          off       = id + NN;
    int*          cursor    = off + NN + 1;
    int*          off_s     = cursor + NN;
    int*          cursor_s  = off_s + NN + 1;
    unsigned int* sd_s      = (unsigned int*)(cursor_s + NN);   // packed src|dst<<16, dst-sorted
    int*          perm_s    = (int*)(sd_s + EE);
    float*        stats_fin = (float*)(perm_s + EE);

    // zero: stats_raw + od + id (contiguous)
    hipMemsetAsync(stats_raw, 0, 512 * sizeof(double) + 2 * NN * sizeof(int), stream);

    // build dst-sorted packed edge list + src-CSR permutation
    k_deg  <<<3125, 256,  0, stream>>>(ei, od, id);
    k_scan2<<<2,    1024, 0, stream>>>(id, off, cursor, od, off_s, cursor_s);
    k_fill <<<3125, 256,  0, stream>>>(ei, cursor, sd_s);
    k_fill2<<<3125, 256,  0, stream>>>(sd_s, cursor_s, perm_s);

    // stage 0 + per-node tables
    k_dsum_csr<<<12500, 256, 0, stream>>>(x, off, sd_s, dsum);
    k_uv3<<<512, 256, 0, stream>>>(x, dsum, W_un, u, v, u2);

    // stage-1: analytic stats, then CSR reduce + per-row bf16 h store
    k_stats1a<<<256, 256, 0, stream>>>(u, v, u2, od, id, stats_raw + 0);
    k_fin1<<<1, 64, 0, stream>>>(stats_raw + 0, b_un, stats_fin + 0, 1.0 / (double)RR);
    k_s1h<<<12500, 256, 0, stream>>>(u, v, off, sd_s, b_un, stats_fin + 0, g1, be1,
                                     s_tab, hb);
    k_msg_csr<<<12500, 256, 0, stream>>>(off, sd_s, s_tab, msg);
    k_mb<<<512, 256, 0, stream>>>(msg, msg, W_gc + 64 * 64);   // msg -> mb in place

    // stage-2: streaming matmul over bf16 h rows -> bf16 h2 rows, block-partial stats
    k_h2<<<NBLK_H2, 256, 0, stream>>>(hb, h2b, msg, sd_s, W_gc, b_gc, part_h2);
    k_red<<<32, 128, 0, stream>>>(part_h2, NBLK_H2, stats_raw + 128);
    k_fin<<<1, 64, 0, stream>>>(stats_raw + 128, stats_fin + 128, 1.0 / (double)RR);
    k_agg_csr<<<12500, 256, 0, stream>>>(h2b, off_s, perm_s, stats_fin + 128, g2, be2, agg);

    // stage 3
    k_mm3<<<NBLK_MM, 256, 0, stream>>>(h2b, agg, W_tr, b_tr, stats_fin + 128, g2, be2,
                                       tpre, part_m3);
    k_red<<<16, 128, 0, stream>>>(part_m3, NBLK_MM, stats_raw + 256);
    k_fin<<<1, 64, 0, stream>>>(stats_raw + 256, stats_fin + 256, 1.0 / (double)NN);

    // stage 4
    k_mm4<<<NBLK_MM, 256, 0, stream>>>(tpre, W_li, b_li, stats_fin + 256, g2, be2,
                                       outpre, part_m4);
    k_red<<<16, 128, 0, stream>>>(part_m4, NBLK_MM, stats_raw + 384);
    k_fin<<<1, 64, 0, stream>>>(stats_raw + 384, stats_fin + 384, 1.0 / (double)NN);

    k_out<<<12500, 256, 0, stream>>>(outpre, stats_fin + 384, g3, be3, (float*)d_out);
}

// Round 8
// 722.590 us; speedup vs baseline: 2.5740x; 1.1544x over previous
//
#include <hip/hip_runtime.h>
#include <cstdint>
#include <math.h>

// Problem sizes (fixed by the reference).
#define NN 50000
#define EE 800000
#define RR 850000      // NN + EE rows
#define NT_N 3125      // NN/16
#define NT_R 53125     // RR/16
#define NBLK_H2 2048
#define NBLK_MM 512
#define CHUNK 512
#define NCH 98         // ceil(NN/CHUNK)

typedef short  bf16x8 __attribute__((ext_vector_type(8)));
typedef float  f32x4  __attribute__((ext_vector_type(4)));

__device__ __forceinline__ float bf2f(unsigned short b) {
    unsigned int u = ((unsigned int)b) << 16;
    return __builtin_bit_cast(float, u);
}
__device__ __forceinline__ unsigned short f2bf(float f) {
    unsigned int u = __builtin_bit_cast(unsigned int, f);
    u = u + 0x7fffu + ((u >> 16) & 1u);
    return (unsigned short)(u >> 16);
}
__device__ __forceinline__ void atomAddD(double* p, double v) { unsafeAtomicAdd(p, v); }
__device__ __forceinline__ int atomAddI(int* p, int v) { return atomicAdd(p, v); }

// split 8 consecutive f32 into hi/lo bf16 fragments: hi+lo == v to ~2^-16 rel
__device__ __forceinline__ void split8(const float* p, bf16x8& hi, bf16x8& lo) {
    f32x4 v0 = *reinterpret_cast<const f32x4*>(p);
    f32x4 v1 = *reinterpret_cast<const f32x4*>(p + 4);
#pragma unroll
    for (int j = 0; j < 4; j++) {
        unsigned short h0 = f2bf(v0[j]);
        hi[j] = (short)h0; lo[j] = (short)f2bf(v0[j] - bf2f(h0));
        unsigned short h1 = f2bf(v1[j]);
        hi[4 + j] = (short)h1; lo[4 + j] = (short)f2bf(v1[j] - bf2f(h1));
    }
}
__device__ __forceinline__ void split8r(const float* v, bf16x8& hi, bf16x8& lo) {
#pragma unroll
    for (int j = 0; j < 8; j++) {
        unsigned short h = f2bf(v[j]);
        hi[j] = (short)h; lo[j] = (short)f2bf(v[j] - bf2f(h));
    }
}

// LDS-staged coalesced tile store: MFMA C-layout -> 4x 1KB contiguous dwordx4 stores.
template <bool RELU, bool STATS>
__device__ __forceinline__ void epi_tile(float* wl, int lane, const f32x4* acc,
                                         const float* bv, float* __restrict__ gout,
                                         int tile, double* ssum, double* ssq) {
    const int m = lane & 15, quad = lane >> 4;
#pragma unroll
    for (int ct = 0; ct < 4; ct++)
#pragma unroll
        for (int i = 0; i < 4; i++) {
            float val = acc[ct][i] + bv[ct];
            if (RELU) val = fmaxf(val, 0.f);
            wl[(quad * 4 + i) * 68 + ct * 16 + m] = val;
            if (STATS) { ssum[ct] += (double)val; ssq[ct] += (double)val * (double)val; }
        }
    asm volatile("s_waitcnt lgkmcnt(0)" ::: "memory");
#pragma unroll
    for (int j = 0; j < 4; j++) {
        int row = j * 4 + quad;
        f32x4 vv = *reinterpret_cast<const f32x4*>(wl + row * 68 + m * 4);
        *reinterpret_cast<f32x4*>(gout + ((size_t)(tile << 4) + row) * 64 + m * 4) = vv;
    }
}

// block-level stats reduce: wave shfl-reduce -> LDS -> one coalesced 1KB store per block.
__device__ __forceinline__ void stats_block_out(float* ldsbase, int lane, int wid,
                                                const double* ssum, const double* ssq,
                                                double* __restrict__ part) {
    const int m = lane & 15, quad = lane >> 4;
    double* dl = (double*)ldsbase;
    __syncthreads();
#pragma unroll
    for (int ct = 0; ct < 4; ct++) {
        double sv = ssum[ct], qv = ssq[ct];
        sv += __shfl_xor(sv, 16, 64); sv += __shfl_xor(sv, 32, 64);
        qv += __shfl_xor(qv, 16, 64); qv += __shfl_xor(qv, 32, 64);
        if (quad == 0) {
            dl[wid * 128 + ct * 16 + m]      = sv;
            dl[wid * 128 + 64 + ct * 16 + m] = qv;
        }
    }
    __syncthreads();
    int tid = wid * 64 + lane;
    if (tid < 128) {
        double tot = dl[tid] + dl[128 + tid] + dl[256 + tid] + dl[384 + tid];
        part[(size_t)blockIdx.x * 128 + tid] = tot;
    }
}

// reduce block partials into raw[0..127] (few spread atomics only)
__global__ void k_red(const double* __restrict__ p, int nblk, double* __restrict__ raw) {
    int t = threadIdx.x;   // 128
    double acc = 0.0;
    for (int b = blockIdx.x; b < nblk; b += gridDim.x)
        acc += p[(size_t)b * 128 + t];
    atomAddD(&raw[t], acc);
}

// ---------- degree counts ----------
__global__ void k_deg(const int* __restrict__ ei, int* __restrict__ od, int* __restrict__ id) {
    int e = blockIdx.x * 256 + threadIdx.x;   // covers EE exactly
    atomAddI(&od[ei[e]], 1);
    atomAddI(&id[ei[EE + e]], 1);
}

// ---------- coalesced 3-phase dual scan (replaces 2-block strided k_scan2) ----------
// A: per-chunk sums (coalesced). grid = 2*NCH, 256 thr.
__global__ void k_scanA(const int* __restrict__ id, const int* __restrict__ od,
                        int* __restrict__ csum) {
    int arr = blockIdx.x / NCH;
    int ch  = blockIdx.x % NCH;
    const int* cnt = arr ? od : id;
    int t = threadIdx.x;
    int i0 = ch * CHUNK + t;
    int s = 0;
    if (i0 < NN) s += cnt[i0];
    if (i0 + 256 < NN && (t + 256) < CHUNK) s += cnt[i0 + 256];
#pragma unroll
    for (int d = 1; d < 64; d <<= 1) s += __shfl_xor(s, d, 64);
    __shared__ int ws[4];
    if ((t & 63) == 0) ws[t >> 6] = s;
    __syncthreads();
    if (t == 0) csum[arr * NCH + ch] = ws[0] + ws[1] + ws[2] + ws[3];
}

// B: exclusive scan of chunk sums for both arrays (1 block, 256 thr = 2 x 128 slots)
__global__ void k_scanB(int* __restrict__ csum) {
    __shared__ int part[256];
    int t = threadIdx.x;
    int arr = t >> 7, slot = t & 127;
    int v = (slot < NCH) ? csum[arr * NCH + slot] : 0;
    part[t] = v;
    __syncthreads();
#pragma unroll
    for (int d = 1; d < 128; d <<= 1) {
        int val = (slot >= d) ? part[t - d] : 0;
        __syncthreads();
        part[t] += val;
        __syncthreads();
    }
    if (slot < NCH)
        csum[arr * NCH + slot] = (slot == 0) ? 0 : part[t - 1];
}

// C: per-element exclusive scan within chunk + chunk base (coalesced pair loads/stores)
__global__ void k_scanC(const int* __restrict__ id, const int* __restrict__ od,
                        const int* __restrict__ csum,
                        int* __restrict__ off, int* __restrict__ cursor,
                        int* __restrict__ off_s, int* __restrict__ cursor_s) {
    int arr = blockIdx.x / NCH;
    int ch  = blockIdx.x % NCH;
    const int* cnt = arr ? od : id;
    int* o  = arr ? off_s : off;
    int* cu = arr ? cursor_s : cursor;
    int t = threadIdx.x;                 // 256 threads x 2 contiguous elems
    int idx = ch * CHUNK + 2 * t;
    int e0 = 0, e1 = 0;
    if (idx < NN)     e0 = cnt[idx];
    if (idx + 1 < NN) e1 = cnt[idx + 1];
    int p = e0 + e1;
    int lane = t & 63;
    int incl = p;
#pragma unroll
    for (int d = 1; d < 64; d <<= 1) {
        int v = __shfl_up(incl, d, 64);
        if (lane >= d) incl += v;
    }
    __shared__ int wsum[4];
    if (lane == 63) wsum[t >> 6] = incl;
    __syncthreads();
    int w = t >> 6;
    int wbase = 0;
#pragma unroll
    for (int i = 0; i < 4; i++) if (i < w) wbase += wsum[i];
    int base = csum[arr * NCH + ch] + wbase + (incl - p);   // exclusive prefix of e0
    if (idx < NN)     { o[idx]     = base;      cu[idx]     = base; }
    if (idx + 1 < NN) { o[idx + 1] = base + e0; cu[idx + 1] = base + e0; }
    if (blockIdx.x == 0 && t == 0) { off[NN] = EE; off_s[NN] = EE; }
}

// ---------- fill dst-sorted packed edge array: sd = src | (dst<<16) ----------
__global__ void k_fill(const int* __restrict__ ei, int* __restrict__ cursor,
                       unsigned int* __restrict__ sd_s) {
    int e = blockIdx.x * 256 + threadIdx.x;   // covers EE exactly
    int s = ei[e], d = ei[EE + e];
    int p = atomAddI(&cursor[d], 1);
    sd_s[p] = (unsigned int)s | ((unsigned int)d << 16);
}

// ---------- fill src-CSR permutation: perm_s[q] = dst-order position p ----------
__global__ void k_fill2(const unsigned int* __restrict__ sd_s, int* __restrict__ cursor_s,
                        int* __restrict__ perm_s) {
    int p = blockIdx.x * 256 + threadIdx.x;   // covers EE exactly
    int s = (int)(sd_s[p] & 0xFFFFu);
    int q = atomAddI(&cursor_s[s], 1);
    perm_s[q] = p;
}

// ---------- dsum[n] = x[n] + sum_{e: dst=n} x[src_e]  (CSR, no atomics, 16-way MLP) ----------
__global__ void k_dsum_csr(const float* __restrict__ x, const int* __restrict__ off,
                           const unsigned int* __restrict__ sd_s, float* __restrict__ dsum) {
    int team = (blockIdx.x * 256 + threadIdx.x) >> 6;   // 12500 blocks x 4 = NN
    int c = threadIdx.x & 63;
    float a[16];
#pragma unroll
    for (int j = 0; j < 16; j++) a[j] = 0.f;
    a[0] = x[(size_t)team * 64 + c];
    int e = off[team], e1 = off[team + 1];
    for (; e + 15 < e1; e += 16)
#pragma unroll
        for (int j = 0; j < 16; j++) a[j] += x[(size_t)(sd_s[e + j] & 0xFFFFu) * 64 + c];
    for (; e + 3 < e1; e += 4)
#pragma unroll
        for (int j = 0; j < 4; j++) a[j] += x[(size_t)(sd_s[e + j] & 0xFFFFu) * 64 + c];
    for (; e < e1; e++) a[0] += x[(size_t)(sd_s[e] & 0xFFFFu) * 64 + c];
#pragma unroll
    for (int j = 0; j < 8; j++) a[j] += a[j + 8];
#pragma unroll
    for (int j = 0; j < 4; j++) a[j] += a[j + 4];
    dsum[(size_t)team * 64 + c] = (a[0] + a[1]) + (a[2] + a[3]);
}

// ---------- u = x@W_top, v = dsum@W_bot, u2 = dsum@W_top ----------
__global__ void k_uv3(const float* __restrict__ x, const float* __restrict__ dsum,
                      const float* __restrict__ W, float* __restrict__ u,
                      float* __restrict__ v, float* __restrict__ u2) {
    __shared__ float lds[4][16 * 68];
    const int lane = threadIdx.x & 63;
    const int wid = threadIdx.x >> 6;
    const int m = lane & 15, quad = lane >> 4;
    const int gwave = (blockIdx.x * blockDim.x + threadIdx.x) >> 6;
    const int nwaves = (gridDim.x * blockDim.x) >> 6;
    float* wl = lds[wid];

    bf16x8 wfh[4][4], wfl[4][4];
#pragma unroll
    for (int kk = 0; kk < 4; kk++)
#pragma unroll
        for (int ct = 0; ct < 4; ct++) {
            float wv[8];
#pragma unroll
            for (int j = 0; j < 8; j++)
                wv[j] = W[(kk * 32 + quad * 8 + j) * 64 + ct * 16 + m];
            split8r(wv, wfh[kk][ct], wfl[kk][ct]);
        }
    float zb[4] = {0.f, 0.f, 0.f, 0.f};

    for (int tile = gwave; tile < NT_N; tile += nwaves) {
        const int r = (tile << 4) + m;
        bf16x8 ah[4], al[4];
        split8(x    + (size_t)r * 64 + quad * 8,      ah[0], al[0]);
        split8(x    + (size_t)r * 64 + 32 + quad * 8, ah[1], al[1]);
        split8(dsum + (size_t)r * 64 + quad * 8,      ah[2], al[2]);
        split8(dsum + (size_t)r * 64 + 32 + quad * 8, ah[3], al[3]);

        f32x4 zero = {0.f, 0.f, 0.f, 0.f};
        f32x4 aU[4], aV[4], aU2[4];
#pragma unroll
        for (int ct = 0; ct < 4; ct++) {
            aU[ct] = zero; aV[ct] = zero; aU2[ct] = zero;
#pragma unroll
            for (int kk = 0; kk < 2; kk++) {
                aU[ct]  = __builtin_amdgcn_mfma_f32_16x16x32_bf16(al[kk],   wfh[kk][ct],   aU[ct],  0, 0, 0);
                aU[ct]  = __builtin_amdgcn_mfma_f32_16x16x32_bf16(ah[kk],   wfl[kk][ct],   aU[ct],  0, 0, 0);
                aU[ct]  = __builtin_amdgcn_mfma_f32_16x16x32_bf16(ah[kk],   wfh[kk][ct],   aU[ct],  0, 0, 0);
                aV[ct]  = __builtin_amdgcn_mfma_f32_16x16x32_bf16(al[kk+2], wfh[kk+2][ct], aV[ct],  0, 0, 0);
                aV[ct]  = __builtin_amdgcn_mfma_f32_16x16x32_bf16(ah[kk+2], wfl[kk+2][ct], aV[ct],  0, 0, 0);
                aV[ct]  = __builtin_amdgcn_mfma_f32_16x16x32_bf16(ah[kk+2], wfh[kk+2][ct], aV[ct],  0, 0, 0);
                aU2[ct] = __builtin_amdgcn_mfma_f32_16x16x32_bf16(al[kk+2], wfh[kk][ct],   aU2[ct], 0, 0, 0);
                aU2[ct] = __builtin_amdgcn_mfma_f32_16x16x32_bf16(ah[kk+2], wfl[kk][ct],   aU2[ct], 0, 0, 0);
                aU2[ct] = __builtin_amdgcn_mfma_f32_16x16x32_bf16(ah[kk+2], wfh[kk][ct],   aU2[ct], 0, 0, 0);
            }
        }
        epi_tile<false, false>(wl, lane, aU,  zb, u,  tile, nullptr, nullptr);
        epi_tile<false, false>(wl, lane, aV,  zb, v,  tile, nullptr, nullptr);
        epi_tile<false, false>(wl, lane, aU2, zb, u2, tile, nullptr, nullptr);
    }
}

// ---------- analytic stage-1 stats ----------
__global__ void k_stats1a(const float* __restrict__ u, const float* __restrict__ v,
                          const float* __restrict__ u2, const int* __restrict__ od,
                          const int* __restrict__ id, double* __restrict__ stats_raw) {
    __shared__ double lsum[4][64], lsq[4][64];
    int tid = threadIdx.x, c = tid & 63, w = tid >> 6;
    double a1 = 0.0, a2 = 0.0;
    for (int n = blockIdx.x * 4 + w; n < NN; n += gridDim.x * 4) {
        double uu = u[(size_t)n * 64 + c], vv = v[(size_t)n * 64 + c];
        double uu2 = u2[(size_t)n * 64 + c];
        double wod = 1.0 + od[n], wid = 1.0 + id[n];
        a1 += wod * uu + wid * vv;
        a2 += wod * uu * uu + wid * vv * vv + 2.0 * vv * uu2;
    }
    lsum[w][c] = a1; lsq[w][c] = a2;
    __syncthreads();
    if (w == 0) {
        a1 = lsum[0][c] + lsum[1][c] + lsum[2][c] + lsum[3][c];
        a2 = lsq[0][c] + lsq[1][c] + lsq[2][c] + lsq[3][c];
        atomAddD(&stats_raw[c], a1);
        atomAddD(&stats_raw[64 + c], a2);
    }
}

__global__ void k_fin1(const double* __restrict__ raw, const float* __restrict__ b,
                       float* __restrict__ fin, double inv_cnt) {
    int c = threadIdx.x;
    double m1 = raw[c] * inv_cnt;
    double var = raw[64 + c] * inv_cnt - m1 * m1;
    if (var < 0.0) var = 0.0;
    fin[c] = (float)(m1 + (double)b[c]);
    fin[64 + c] = (float)(1.0 / sqrt(var + 1e-5));
}

__global__ void k_fin(const double* __restrict__ raw, float* __restrict__ fin, double inv_cnt) {
    int c = threadIdx.x;
    double mean = raw[c] * inv_cnt;
    double var = raw[64 + c] * inv_cnt - mean * mean;
    if (var < 0.0) var = 0.0;
    fin[c] = (float)mean;
    fin[64 + c] = (float)(1.0 / sqrt(var + 1e-5));
}

// ---------- stage-1 reduce + per-row h store in BF16 (16-way MLP gather preserved) ----------
__global__ void k_s1h(const float* __restrict__ u, const float* __restrict__ v,
                      const int* __restrict__ off, const unsigned int* __restrict__ sd_s,
                      const float* __restrict__ b_un, const float* __restrict__ fin,
                      const float* __restrict__ g1, const float* __restrict__ be1,
                      float* __restrict__ s_tab, unsigned short* __restrict__ hb) {
    int team = (blockIdx.x * 256 + threadIdx.x) >> 6;
    int c = threadIdx.x & 63;
    float sc = fin[64 + c] * g1[c];
    float tsh = (b_un[c] - fin[c]) * sc + be1[c];
    float vn = v[(size_t)team * 64 + c];
    float a[16];
#pragma unroll
    for (int j = 0; j < 16; j++) a[j] = 0.f;
    float hs = fmaxf((u[(size_t)team * 64 + c] + vn) * sc + tsh, 0.f);   // self row
    a[0] = hs;
    hb[(size_t)team * 64 + c] = f2bf(hs);
    int e = off[team], e1 = off[team + 1];
    for (; e + 15 < e1; e += 16)
#pragma unroll
        for (int j = 0; j < 16; j++) {
            float h = fmaxf((u[(size_t)(sd_s[e + j] & 0xFFFFu) * 64 + c] + vn) * sc + tsh, 0.f);
            a[j] += h;
            hb[(size_t)(NN + e + j) * 64 + c] = f2bf(h);
        }
    for (; e + 3 < e1; e += 4)
#pragma unroll
        for (int j = 0; j < 4; j++) {
            float h = fmaxf((u[(size_t)(sd_s[e + j] & 0xFFFFu) * 64 + c] + vn) * sc + tsh, 0.f);
            a[j] += h;
            hb[(size_t)(NN + e + j) * 64 + c] = f2bf(h);
        }
    for (; e < e1; e++) {
        float h = fmaxf((u[(size_t)(sd_s[e] & 0xFFFFu) * 64 + c] + vn) * sc + tsh, 0.f);
        a[0] += h;
        hb[(size_t)(NN + e) * 64 + c] = f2bf(h);
    }
#pragma unroll
    for (int j = 0; j < 8; j++) a[j] += a[j + 8];
#pragma unroll
    for (int j = 0; j < 4; j++) a[j] += a[j + 4];
    s_tab[(size_t)team * 64 + c] = (a[0] + a[1]) + (a[2] + a[3]);
}

// ---------- msg[n] = sum_{e:dst=n} s_tab[src_e] ----------
__global__ void k_msg_csr(const int* __restrict__ off, const unsigned int* __restrict__ sd_s,
                          const float* __restrict__ s_tab, float* __restrict__ msg) {
    int team = (blockIdx.x * 256 + threadIdx.x) >> 6;
    int c = threadIdx.x & 63;
    float a[16];
#pragma unroll
    for (int j = 0; j < 16; j++) a[j] = 0.f;
    int e = off[team], e1 = off[team + 1];
    for (; e + 15 < e1; e += 16)
#pragma unroll
        for (int j = 0; j < 16; j++) a[j] += s_tab[(size_t)(sd_s[e + j] & 0xFFFFu) * 64 + c];
    for (; e + 3 < e1; e += 4)
#pragma unroll
        for (int j = 0; j < 4; j++) a[j] += s_tab[(size_t)(sd_s[e + j] & 0xFFFFu) * 64 + c];
    for (; e < e1; e++) a[0] += s_tab[(size_t)(sd_s[e] & 0xFFFFu) * 64 + c];
#pragma unroll
    for (int j = 0; j < 8; j++) a[j] += a[j + 8];
#pragma unroll
    for (int j = 0; j < 4; j++) a[j] += a[j + 4];
    msg[(size_t)team * 64 + c] = (a[0] + a[1]) + (a[2] + a[3]);
}

// ---------- mb = msg @ W_gc[64:128]  (streaming; in/out may differ) ----------
__global__ void k_mb(const float* __restrict__ in, float* __restrict__ outp,
                     const float* __restrict__ W) {
    __shared__ float lds[4][16 * 68];
    const int lane = threadIdx.x & 63;
    const int wid = threadIdx.x >> 6;
    const int m = lane & 15, quad = lane >> 4;
    const int gwave = (blockIdx.x * blockDim.x + threadIdx.x) >> 6;
    const int nwaves = (gridDim.x * blockDim.x) >> 6;
    float* wl = lds[wid];

    bf16x8 wfh[2][4], wfl[2][4];
#pragma unroll
    for (int kk = 0; kk < 2; kk++)
#pragma unroll
        for (int ct = 0; ct < 4; ct++) {
            float wv[8];
#pragma unroll
            for (int j = 0; j < 8; j++)
                wv[j] = W[(kk * 32 + quad * 8 + j) * 64 + ct * 16 + m];
            split8r(wv, wfh[kk][ct], wfl[kk][ct]);
        }
    float zb[4] = {0.f, 0.f, 0.f, 0.f};

    for (int tile = gwave; tile < NT_N; tile += nwaves) {
        const int r = (tile << 4) + m;
        bf16x8 ah[2], al[2];
        split8(in + (size_t)r * 64 + quad * 8,      ah[0], al[0]);
        split8(in + (size_t)r * 64 + 32 + quad * 8, ah[1], al[1]);

        f32x4 zero = {0.f, 0.f, 0.f, 0.f};
        f32x4 acc[4];
#pragma unroll
        for (int ct = 0; ct < 4; ct++) {
            acc[ct] = zero;
#pragma unroll
            for (int kk = 0; kk < 2; kk++) {
                acc[ct] = __builtin_amdgcn_mfma_f32_16x16x32_bf16(al[kk], wfh[kk][ct], acc[ct], 0, 0, 0);
                acc[ct] = __builtin_amdgcn_mfma_f32_16x16x32_bf16(ah[kk], wfl[kk][ct], acc[ct], 0, 0, 0);
                acc[ct] = __builtin_amdgcn_mfma_f32_16x16x32_bf16(ah[kk], wfh[kk][ct], acc[ct], 0, 0, 0);
            }
        }
        epi_tile<false, false>(wl, lane, acc, zb, outp, tile, nullptr, nullptr);
    }
}

// ---------- stage-2 streaming matmul over bf16 h rows:
// h2b[r] = bf16( hb[r]@Wtop2 + mb[dst(r)] + b_gc ); stats via block partials (no atomics).
__global__ void k_h2(const unsigned short* __restrict__ hb, unsigned short* __restrict__ h2b,
                     const float* __restrict__ mb, const unsigned int* __restrict__ sd_s,
                     const float* __restrict__ W, const float* __restrict__ b_gc,
                     double* __restrict__ part) {
    __shared__ float lds[4][16 * 68];
    const int lane = threadIdx.x & 63;
    const int wid = threadIdx.x >> 6;
    const int m = lane & 15, quad = lane >> 4;
    const int gwave = (blockIdx.x * blockDim.x + threadIdx.x) >> 6;
    const int nwaves = (gridDim.x * blockDim.x) >> 6;
    float* wl = lds[wid];

    bf16x8 wfh[2][4], wfl[2][4];
#pragma unroll
    for (int kk = 0; kk < 2; kk++)
#pragma unroll
        for (int ct = 0; ct < 4; ct++) {
            float wv[8];
#pragma unroll
            for (int j = 0; j < 8; j++)
                wv[j] = W[(kk * 32 + quad * 8 + j) * 64 + ct * 16 + m];
            split8r(wv, wfh[kk][ct], wfl[kk][ct]);
        }

    float bv[4];
#pragma unroll
    for (int ct = 0; ct < 4; ct++) bv[ct] = b_gc[ct * 16 + m];

    double ssum[4] = {0,0,0,0}, ssq[4] = {0,0,0,0};

    for (int tile = gwave; tile < NT_R; tile += nwaves) {
        const int r = (tile << 4) + m;
        int dm = (tile < NT_N) ? r : (int)(sd_s[r - NN] >> 16);

        bf16x8 ah[2];
        ah[0] = *reinterpret_cast<const bf16x8*>(hb + (size_t)r * 64 + quad * 8);
        ah[1] = *reinterpret_cast<const bf16x8*>(hb + (size_t)r * 64 + 32 + quad * 8);

        f32x4 zero = {0.f, 0.f, 0.f, 0.f};
        f32x4 acc[4];
#pragma unroll
        for (int ct = 0; ct < 4; ct++) {
            acc[ct] = zero;
#pragma unroll
            for (int kk = 0; kk < 2; kk++) {
                acc[ct] = __builtin_amdgcn_mfma_f32_16x16x32_bf16(ah[kk], wfl[kk][ct], acc[ct], 0, 0, 0);
                acc[ct] = __builtin_amdgcn_mfma_f32_16x16x32_bf16(ah[kk], wfh[kk][ct], acc[ct], 0, 0, 0);
            }
        }

        // add mb[dst_of_row] + b_gc per element, then stats + LDS-coalesced bf16 store
#pragma unroll
        for (int i = 0; i < 4; i++) {
            int dmv = __shfl(dm, (lane & 48) + quad * 4 + i, 64);   // dm of row quad*4+i
#pragma unroll
            for (int ct = 0; ct < 4; ct++) {
                float val = acc[ct][i] + bv[ct] + mb[(size_t)dmv * 64 + ct * 16 + m];
                wl[(quad * 4 + i) * 68 + ct * 16 + m] = val;
                ssum[ct] += (double)val;
                ssq[ct]  += (double)val * (double)val;
            }
        }
        asm volatile("s_waitcnt lgkmcnt(0)" ::: "memory");
#pragma unroll
        for (int j = 0; j < 4; j++) {
            int row = j * 4 + quad;
            f32x4 vv = *reinterpret_cast<const f32x4*>(wl + row * 68 + m * 4);
            unsigned int p0 = (unsigned int)f2bf(vv[0]) | ((unsigned int)f2bf(vv[1]) << 16);
            unsigned int p1 = (unsigned int)f2bf(vv[2]) | ((unsigned int)f2bf(vv[3]) << 16);
            uint2 pk; pk.x = p0; pk.y = p1;
            *reinterpret_cast<uint2*>(h2b + ((size_t)(tile << 4) + row) * 64 + m * 4) = pk;
        }
    }

    stats_block_out(&lds[0][0], lane, wid, ssum, ssq, part);
}

// ---------- agg[n] = relu(bn2(h2b[n])) + sum_{q in src-CSR} relu(bn2(h2b[NN+perm_s[q]])) ----------
__global__ void k_agg_csr(const unsigned short* __restrict__ h2b, const int* __restrict__ off_s,
                          const int* __restrict__ perm_s, const float* __restrict__ fin2,
                          const float* __restrict__ g2, const float* __restrict__ be2,
                          float* __restrict__ agg) {
    int n = (blockIdx.x * 256 + threadIdx.x) >> 6;
    int c = threadIdx.x & 63;
    float sc = fin2[64 + c] * g2[c];
    float sh = be2[c] - fin2[c] * sc;
    float a[16];
#pragma unroll
    for (int j = 0; j < 16; j++) a[j] = 0.f;
    a[0] = fmaxf(bf2f(h2b[(size_t)n * 64 + c]) * sc + sh, 0.f);   // self row
    int q = off_s[n], q1 = off_s[n + 1];
    for (; q + 15 < q1; q += 16)
#pragma unroll
        for (int j = 0; j < 16; j++) {
            float hv = bf2f(h2b[(size_t)(NN + perm_s[q + j]) * 64 + c]);
            a[j] += fmaxf(hv * sc + sh, 0.f);
        }
    for (; q + 3 < q1; q += 4)
#pragma unroll
        for (int j = 0; j < 4; j++) {
            float hv = bf2f(h2b[(size_t)(NN + perm_s[q + j]) * 64 + c]);
            a[j] += fmaxf(hv * sc + sh, 0.f);
        }
    for (; q < q1; q++) {
        float hv = bf2f(h2b[(size_t)(NN + perm_s[q]) * 64 + c]);
        a[0] += fmaxf(hv * sc + sh, 0.f);
    }
#pragma unroll
    for (int j = 0; j < 8; j++) a[j] += a[j + 8];
#pragma unroll
    for (int j = 0; j < 4; j++) a[j] += a[j + 4];
    agg[(size_t)n * 64 + c] = (a[0] + a[1]) + (a[2] + a[3]);
}

// ---------- stage 3: t_pre = [relu(bn2(h2b[:N])), agg] @ W_tr + b_tr, stats3 ----------
__global__ void k_mm3(const unsigned short* __restrict__ h2b, const float* __restrict__ agg,
                      const float* __restrict__ W, const float* __restrict__ bias,
                      const float* __restrict__ fin2, const float* __restrict__ g2,
                      const float* __restrict__ be2,
                      float* __restrict__ outp, double* __restrict__ part) {
    __shared__ float lds[4][16 * 68];
    const int lane = threadIdx.x & 63;
    const int wid = threadIdx.x >> 6;
    const int m = lane & 15, quad = lane >> 4;
    const int gwave = (blockIdx.x * blockDim.x + threadIdx.x) >> 6;
    const int nwaves = (gridDim.x * blockDim.x) >> 6;
    float* wl = lds[wid];

    bf16x8 wfh[4][4], wfl[4][4];
#pragma unroll
    for (int kk = 0; kk < 4; kk++)
#pragma unroll
        for (int ct = 0; ct < 4; ct++) {
            float wv[8];
#pragma unroll
            for (int j = 0; j < 8; j++)
                wv[j] = W[(kk * 32 + quad * 8 + j) * 64 + ct * 16 + m];
            split8r(wv, wfh[kk][ct], wfl[kk][ct]);
        }

    float bv[4];
#pragma unroll
    for (int ct = 0; ct < 4; ct++) bv[ct] = bias[ct * 16 + m];

    float s2f[2][8], t2f[2][8];
#pragma unroll
    for (int kk = 0; kk < 2; kk++)
#pragma unroll
        for (int j = 0; j < 8; j++) {
            int c = kk * 32 + quad * 8 + j;
            float sc = fin2[64 + c] * g2[c];
            s2f[kk][j] = sc;
            t2f[kk][j] = be2[c] - fin2[c] * sc;
        }

    double ssum[4] = {0,0,0,0}, ssq[4] = {0,0,0,0};

    for (int tile = gwave; tile < NT_N; tile += nwaves) {
        const int r = (tile << 4) + m;
        bf16x8 ah[4], al[4];
#pragma unroll
        for (int kk = 0; kk < 2; kk++) {
            bf16x8 hv = *reinterpret_cast<const bf16x8*>(h2b + (size_t)r * 64 + kk * 32 + quad * 8);
            float tv[8];
#pragma unroll
            for (int j = 0; j < 8; j++) {
                float f = bf2f((unsigned short)hv[j]);
                tv[j] = fmaxf(f * s2f[kk][j] + t2f[kk][j], 0.f);
            }
            split8r(tv, ah[kk], al[kk]);
        }
        split8(agg + (size_t)r * 64 + quad * 8,      ah[2], al[2]);
        split8(agg + (size_t)r * 64 + 32 + quad * 8, ah[3], al[3]);

        f32x4 zero = {0.f, 0.f, 0.f, 0.f};
        f32x4 acc[4];
#pragma unroll
        for (int ct = 0; ct < 4; ct++) {
            acc[ct] = zero;
#pragma unroll
            for (int kk = 0; kk < 4; kk++)
                acc[ct] = __builtin_amdgcn_mfma_f32_16x16x32_bf16(al[kk], wfh[kk][ct], acc[ct], 0, 0, 0);
#pragma unroll
            for (int kk = 0; kk < 4; kk++)
                acc[ct] = __builtin_amdgcn_mfma_f32_16x16x32_bf16(ah[kk], wfl[kk][ct], acc[ct], 0, 0, 0);
#pragma unroll
            for (int kk = 0; kk < 4; kk++)
                acc[ct] = __builtin_amdgcn_mfma_f32_16x16x32_bf16(ah[kk], wfh[kk][ct], acc[ct], 0, 0, 0);
        }

        epi_tile<false, true>(wl, lane, acc, bv, outp, tile, ssum, ssq);
    }

    stats_block_out(&lds[0][0], lane, wid, ssum, ssq, part);
}

// ---------- stage 4 ----------
__global__ void k_mm4(const float* __restrict__ tpre, const float* __restrict__ W,
                      const float* __restrict__ bias, const float* __restrict__ fin3,
                      const float* __restrict__ g2, const float* __restrict__ be2,
                      float* __restrict__ outp, double* __restrict__ part) {
    __shared__ float lds[4][16 * 68];
    const int lane = threadIdx.x & 63;
    const int wid = threadIdx.x >> 6;
    const int m = lane & 15, quad = lane >> 4;
    const int gwave = (blockIdx.x * blockDim.x + threadIdx.x) >> 6;
    const int nwaves = (gridDim.x * blockDim.x) >> 6;
    float* wl = lds[wid];

    bf16x8 wfh[2][4], wfl[2][4];
#pragma unroll
    for (int kk = 0; kk < 2; kk++)
#pragma unroll
        for (int ct = 0; ct < 4; ct++) {
            float wv[8];
#pragma unroll
            for (int j = 0; j < 8; j++)
                wv[j] = W[(kk * 32 + quad * 8 + j) * 64 + ct * 16 + m];
            split8r(wv, wfh[kk][ct], wfl[kk][ct]);
        }

    float bv[4];
#pragma unroll
    for (int ct = 0; ct < 4; ct++) bv[ct] = bias[ct * 16 + m];

    float sc[2][8], sh[2][8];
#pragma unroll
    for (int kk = 0; kk < 2; kk++)
#pragma unroll
        for (int j = 0; j < 8; j++) {
            int c = kk * 32 + quad * 8 + j;
            float s = fin3[64 + c] * g2[c];
            sc[kk][j] = s;
            sh[kk][j] = be2[c] - fin3[c] * s;
        }

    double ssum[4] = {0,0,0,0}, ssq[4] = {0,0,0,0};

    for (int tile = gwave; tile < NT_N; tile += nwaves) {
        const int r = (tile << 4) + m;
        bf16x8 ah[2], al[2];
#pragma unroll
        for (int kk = 0; kk < 2; kk++) {
            f32x4 v0 = *reinterpret_cast<const f32x4*>(tpre + (size_t)r * 64 + kk * 32 + quad * 8);
            f32x4 v1 = *reinterpret_cast<const f32x4*>(tpre + (size_t)r * 64 + kk * 32 + quad * 8 + 4);
            float tv[8];
#pragma unroll
            for (int j = 0; j < 4; j++) {
                tv[j]     = fmaxf(v0[j] * sc[kk][j]     + sh[kk][j],     0.f);
                tv[4 + j] = fmaxf(v1[j] * sc[kk][4 + j] + sh[kk][4 + j], 0.f);
            }
            split8r(tv, ah[kk], al[kk]);
        }

        f32x4 zero = {0.f, 0.f, 0.f, 0.f};
        f32x4 acc[4];
#pragma unroll
        for (int ct = 0; ct < 4; ct++) {
            acc[ct] = zero;
#pragma unroll
            for (int kk = 0; kk < 2; kk++) {
                acc[ct] = __builtin_amdgcn_mfma_f32_16x16x32_bf16(al[kk], wfh[kk][ct], acc[ct], 0, 0, 0);
                acc[ct] = __builtin_amdgcn_mfma_f32_16x16x32_bf16(ah[kk], wfl[kk][ct], acc[ct], 0, 0, 0);
                acc[ct] = __builtin_amdgcn_mfma_f32_16x16x32_bf16(ah[kk], wfh[kk][ct], acc[ct], 0, 0, 0);
            }
        }

        epi_tile<true, true>(wl, lane, acc, bv, outp, tile, ssum, ssq);
    }

    stats_block_out(&lds[0][0], lane, wid, ssum, ssq, part);
}

// out = relu(bn(out_pre; stats4, g3, be3)) -> f32
__global__ void k_out(const float* __restrict__ op, const float* __restrict__ fin,
                      const float* __restrict__ g, const float* __restrict__ be,
                      float* __restrict__ out) {
    int i = blockIdx.x * 256 + threadIdx.x;   // covers NN*64 exactly
    int c = i & 63;
    out[i] = fmaxf((op[i] - fin[c]) * fin[64 + c] * g[c] + be[c], 0.f);
}

extern "C" void kernel_launch(void* const* d_in, const int* in_sizes, int n_in,
                              void* d_out, int out_size, void* d_ws, size_t ws_size,
                              hipStream_t stream) {
    const float* x    = (const float*)d_in[0];
    const int*   ei   = (const int*)d_in[1];
    const float* W_un = (const float*)d_in[2];
    const float* b_un = (const float*)d_in[3];
    const float* g1   = (const float*)d_in[4];
    const float* be1  = (const float*)d_in[5];
    const float* W_gc = (const float*)d_in[6];
    const float* b_gc = (const float*)d_in[7];
    const float* g2   = (const float*)d_in[8];
    const float* be2  = (const float*)d_in[9];
    const float* W_tr = (const float*)d_in[10];
    const float* b_tr = (const float*)d_in[11];
    const float* W_li = (const float*)d_in[12];
    const float* b_li = (const float*)d_in[13];
    const float* g3   = (const float*)d_in[14];
    const float* be3  = (const float*)d_in[15];

    float* ws = (float*)d_ws;
    const size_t FN = (size_t)NN * 64;           // 3.2M floats (12.8 MB)
    const size_t FR = (size_t)RR * 64;           // 54.4M floats (217.6 MB)
    // Region plan (zero growth; lifetimes verified):
    //  P0: u -> msg/mb -> part_mm3 -> outpre
    //  P1: v -> agg -> part_mm4
    //  P2: csum (scan scratch, dead before k_s1h) -> s_tab -> part_h2 -> tpre
    //  H (FR floats): dsum(H), u2(H+FN) [dead after k_stats1a]
    //      -> hb (FR ushorts) + h2b (FR ushorts)
    float* P0 = ws;
    float* P1 = ws + FN;
    float* P2 = ws + 2 * FN;
    float* H  = ws + 3 * FN;
    float* u      = P0;
    float* v      = P1;
    float* s_tab  = P2;
    int*   csum   = (int*)P2;     // 196 ints, scan scratch (dead before k_s1h writes s_tab)
    float* dsum   = H;
    float* u2     = H + FN;
    unsigned short* hb  = (unsigned short*)H;        // bf16 h rows
    unsigned short* h2b = (unsigned short*)H + FR;   // bf16 h2pre rows
    float* msg    = P0;           // becomes mb after k_mb (in place)
    float* agg    = P1;
    float* tpre   = P2;
    float* outpre = P0;
    double* part_h2 = (double*)P2;   // 2048*128*8B = 2MB   (before tpre)
    double* part_m3 = (double*)P0;   // 512*128*8B = 512KB  (mb dead, before outpre)
    double* part_m4 = (double*)P1;   // 512KB               (agg dead)
    double*       stats_raw = (double*)(H + FR);
    int*          od        = (int*)(stats_raw + 512);
    int*          id        = od + NN;
    int*          off       = id + NN;
    int*          cursor    = off + NN + 1;
    int*          off_s     = cursor + NN;
    int*          cursor_s  = off_s + NN + 1;
    unsigned int* sd_s      = (unsigned int*)(cursor_s + NN);   // packed src|dst<<16, dst-sorted
    int*          perm_s    = (int*)(sd_s + EE);
    float*        stats_fin = (float*)(perm_s + EE);

    // zero: stats_raw + od + id (contiguous)
    hipMemsetAsync(stats_raw, 0, 512 * sizeof(double) + 2 * NN * sizeof(int), stream);

    // build dst-sorted packed edge list + src-CSR permutation (coalesced 3-phase scan)
    k_deg  <<<3125, 256, 0, stream>>>(ei, od, id);
    k_scanA<<<2 * NCH, 256, 0, stream>>>(id, od, csum);
    k_scanB<<<1, 256, 0, stream>>>(csum);
    k_scanC<<<2 * NCH, 256, 0, stream>>>(id, od, csum, off, cursor, off_s, cursor_s);
    k_fill <<<3125, 256, 0, stream>>>(ei, cursor, sd_s);
    k_fill2<<<3125, 256, 0, stream>>>(sd_s, cursor_s, perm_s);

    // stage 0 + per-node tables
    k_dsum_csr<<<12500, 256, 0, stream>>>(x, off, sd_s, dsum);
    k_uv3<<<512, 256, 0, stream>>>(x, dsum, W_un, u, v, u2);

    // stage-1: analytic stats, then CSR reduce + per-row bf16 h store
    k_stats1a<<<256, 256, 0, stream>>>(u, v, u2, od, id, stats_raw + 0);
    k_fin1<<<1, 64, 0, stream>>>(stats_raw + 0, b_un, stats_fin + 0, 1.0 / (double)RR);
    k_s1h<<<12500, 256, 0, stream>>>(u, v, off, sd_s, b_un, stats_fin + 0, g1, be1,
                                     s_tab, hb);
    k_msg_csr<<<12500, 256, 0, stream>>>(off, sd_s, s_tab, msg);
    k_mb<<<512, 256, 0, stream>>>(msg, msg, W_gc + 64 * 64);   // msg -> mb in place

    // stage-2: streaming matmul over bf16 h rows -> bf16 h2 rows, block-partial stats
    k_h2<<<NBLK_H2, 256, 0, stream>>>(hb, h2b, msg, sd_s, W_gc, b_gc, part_h2);
    k_red<<<32, 128, 0, stream>>>(part_h2, NBLK_H2, stats_raw + 128);
    k_fin<<<1, 64, 0, stream>>>(stats_raw + 128, stats_fin + 128, 1.0 / (double)RR);
    k_agg_csr<<<12500, 256, 0, stream>>>(h2b, off_s, perm_s, stats_fin + 128, g2, be2, agg);

    // stage 3
    k_mm3<<<NBLK_MM, 256, 0, stream>>>(h2b, agg, W_tr, b_tr, stats_fin + 128, g2, be2,
                                       tpre, part_m3);
    k_red<<<16, 128, 0, stream>>>(part_m3, NBLK_MM, stats_raw + 256);
    k_fin<<<1, 64, 0, stream>>>(stats_raw + 256, stats_fin + 256, 1.0 / (double)NN);

    // stage 4
    k_mm4<<<NBLK_MM, 256, 0, stream>>>(tpre, W_li, b_li, stats_fin + 256, g2, be2,
                                       outpre, part_m4);
    k_red<<<16, 128, 0, stream>>>(part_m4, NBLK_MM, stats_raw + 384);
    k_fin<<<1, 64, 0, stream>>>(stats_raw + 384, stats_fin + 384, 1.0 / (double)NN);

    k_out<<<12500, 256, 0, stream>>>(outpre, stats_fin + 384, g3, be3, (float*)d_out);
}

// Round 9
// 716.692 us; speedup vs baseline: 2.5952x; 1.0082x over previous
//
#include <hip/hip_runtime.h>
#include <cstdint>
#include <math.h>

// Problem sizes (fixed by the reference).
#define NN 50000
#define EE 800000
#define RR 850000      // NN + EE rows
#define NT_N 3125      // NN/16
#define NT_R 53125     // RR/16
#define NBLK_H2 2048
#define NBLK_MM 512
#define CHUNK 512
#define NCH 98         // ceil(NN/CHUNK)

typedef short  bf16x8 __attribute__((ext_vector_type(8)));
typedef float  f32x4  __attribute__((ext_vector_type(4)));

__device__ __forceinline__ float bf2f(unsigned short b) {
    unsigned int u = ((unsigned int)b) << 16;
    return __builtin_bit_cast(float, u);
}
__device__ __forceinline__ unsigned short f2bf(float f) {
    unsigned int u = __builtin_bit_cast(unsigned int, f);
    u = u + 0x7fffu + ((u >> 16) & 1u);
    return (unsigned short)(u >> 16);
}
__device__ __forceinline__ void atomAddD(double* p, double v) { unsafeAtomicAdd(p, v); }
__device__ __forceinline__ int atomAddI(int* p, int v) { return atomicAdd(p, v); }

// split 8 consecutive f32 into hi/lo bf16 fragments: hi+lo == v to ~2^-16 rel
__device__ __forceinline__ void split8(const float* p, bf16x8& hi, bf16x8& lo) {
    f32x4 v0 = *reinterpret_cast<const f32x4*>(p);
    f32x4 v1 = *reinterpret_cast<const f32x4*>(p + 4);
#pragma unroll
    for (int j = 0; j < 4; j++) {
        unsigned short h0 = f2bf(v0[j]);
        hi[j] = (short)h0; lo[j] = (short)f2bf(v0[j] - bf2f(h0));
        unsigned short h1 = f2bf(v1[j]);
        hi[4 + j] = (short)h1; lo[4 + j] = (short)f2bf(v1[j] - bf2f(h1));
    }
}
__device__ __forceinline__ void split8r(const float* v, bf16x8& hi, bf16x8& lo) {
#pragma unroll
    for (int j = 0; j < 8; j++) {
        unsigned short h = f2bf(v[j]);
        hi[j] = (short)h; lo[j] = (short)f2bf(v[j] - bf2f(h));
    }
}

// LDS-staged coalesced tile store: MFMA C-layout -> 4x 1KB contiguous dwordx4 stores.
template <bool RELU, bool STATS>
__device__ __forceinline__ void epi_tile(float* wl, int lane, const f32x4* acc,
                                         const float* bv, float* __restrict__ gout,
                                         int tile, double* ssum, double* ssq) {
    const int m = lane & 15, quad = lane >> 4;
#pragma unroll
    for (int ct = 0; ct < 4; ct++)
#pragma unroll
        for (int i = 0; i < 4; i++) {
            float val = acc[ct][i] + bv[ct];
            if (RELU) val = fmaxf(val, 0.f);
            wl[(quad * 4 + i) * 68 + ct * 16 + m] = val;
            if (STATS) { ssum[ct] += (double)val; ssq[ct] += (double)val * (double)val; }
        }
    asm volatile("s_waitcnt lgkmcnt(0)" ::: "memory");
#pragma unroll
    for (int j = 0; j < 4; j++) {
        int row = j * 4 + quad;
        f32x4 vv = *reinterpret_cast<const f32x4*>(wl + row * 68 + m * 4);
        *reinterpret_cast<f32x4*>(gout + ((size_t)(tile << 4) + row) * 64 + m * 4) = vv;
    }
}

// bf16 variant: stage f32 in LDS, pack to bf16, coalesced uint2 stores.
__device__ __forceinline__ void epi_tile_b16(float* wl, int lane, const f32x4* acc,
                                             unsigned short* __restrict__ gout, int tile) {
    const int m = lane & 15, quad = lane >> 4;
#pragma unroll
    for (int ct = 0; ct < 4; ct++)
#pragma unroll
        for (int i = 0; i < 4; i++)
            wl[(quad * 4 + i) * 68 + ct * 16 + m] = acc[ct][i];
    asm volatile("s_waitcnt lgkmcnt(0)" ::: "memory");
#pragma unroll
    for (int j = 0; j < 4; j++) {
        int row = j * 4 + quad;
        f32x4 vv = *reinterpret_cast<const f32x4*>(wl + row * 68 + m * 4);
        unsigned int p0 = (unsigned int)f2bf(vv[0]) | ((unsigned int)f2bf(vv[1]) << 16);
        unsigned int p1 = (unsigned int)f2bf(vv[2]) | ((unsigned int)f2bf(vv[3]) << 16);
        uint2 pk; pk.x = p0; pk.y = p1;
        *reinterpret_cast<uint2*>(gout + ((size_t)(tile << 4) + row) * 64 + m * 4) = pk;
    }
}

// block-level stats reduce: wave shfl-reduce -> LDS -> one coalesced 1KB store per block.
__device__ __forceinline__ void stats_block_out(float* ldsbase, int lane, int wid,
                                                const double* ssum, const double* ssq,
                                                double* __restrict__ part) {
    const int m = lane & 15, quad = lane >> 4;
    double* dl = (double*)ldsbase;
    __syncthreads();
#pragma unroll
    for (int ct = 0; ct < 4; ct++) {
        double sv = ssum[ct], qv = ssq[ct];
        sv += __shfl_xor(sv, 16, 64); sv += __shfl_xor(sv, 32, 64);
        qv += __shfl_xor(qv, 16, 64); qv += __shfl_xor(qv, 32, 64);
        if (quad == 0) {
            dl[wid * 128 + ct * 16 + m]      = sv;
            dl[wid * 128 + 64 + ct * 16 + m] = qv;
        }
    }
    __syncthreads();
    int tid = wid * 64 + lane;
    if (tid < 128) {
        double tot = dl[tid] + dl[128 + tid] + dl[256 + tid] + dl[384 + tid];
        part[(size_t)blockIdx.x * 128 + tid] = tot;
    }
}

// reduce block partials into raw[0..127] (few spread atomics only)
__global__ void k_red(const double* __restrict__ p, int nblk, double* __restrict__ raw) {
    int t = threadIdx.x;   // 128
    double acc = 0.0;
    for (int b = blockIdx.x; b < nblk; b += gridDim.x)
        acc += p[(size_t)b * 128 + t];
    atomAddD(&raw[t], acc);
}

// ---------- degree counts ----------
__global__ void k_deg(const int* __restrict__ ei, int* __restrict__ od, int* __restrict__ id) {
    int e = blockIdx.x * 256 + threadIdx.x;   // covers EE exactly
    atomAddI(&od[ei[e]], 1);
    atomAddI(&id[ei[EE + e]], 1);
}

// ---------- x -> bf16 copy (gather table for k_dsum) ----------
__global__ void k_xc(const float* __restrict__ x, unsigned short* __restrict__ xb) {
    int i = blockIdx.x * 256 + threadIdx.x;   // covers NN*64 exactly
    xb[i] = f2bf(x[i]);
}

// ---------- coalesced 3-phase dual scan ----------
__global__ void k_scanA(const int* __restrict__ id, const int* __restrict__ od,
                        int* __restrict__ csum) {
    int arr = blockIdx.x / NCH;
    int ch  = blockIdx.x % NCH;
    const int* cnt = arr ? od : id;
    int t = threadIdx.x;
    int i0 = ch * CHUNK + t;
    int s = 0;
    if (i0 < NN) s += cnt[i0];
    if (i0 + 256 < NN && (t + 256) < CHUNK) s += cnt[i0 + 256];
#pragma unroll
    for (int d = 1; d < 64; d <<= 1) s += __shfl_xor(s, d, 64);
    __shared__ int ws[4];
    if ((t & 63) == 0) ws[t >> 6] = s;
    __syncthreads();
    if (t == 0) csum[arr * NCH + ch] = ws[0] + ws[1] + ws[2] + ws[3];
}

__global__ void k_scanB(int* __restrict__ csum) {
    __shared__ int part[256];
    int t = threadIdx.x;
    int arr = t >> 7, slot = t & 127;
    int v = (slot < NCH) ? csum[arr * NCH + slot] : 0;
    part[t] = v;
    __syncthreads();
#pragma unroll
    for (int d = 1; d < 128; d <<= 1) {
        int val = (slot >= d) ? part[t - d] : 0;
        __syncthreads();
        part[t] += val;
        __syncthreads();
    }
    if (slot < NCH)
        csum[arr * NCH + slot] = (slot == 0) ? 0 : part[t - 1];
}

__global__ void k_scanC(const int* __restrict__ id, const int* __restrict__ od,
                        const int* __restrict__ csum,
                        int* __restrict__ off, int* __restrict__ cursor,
                        int* __restrict__ off_s, int* __restrict__ cursor_s) {
    int arr = blockIdx.x / NCH;
    int ch  = blockIdx.x % NCH;
    const int* cnt = arr ? od : id;
    int* o  = arr ? off_s : off;
    int* cu = arr ? cursor_s : cursor;
    int t = threadIdx.x;                 // 256 threads x 2 contiguous elems
    int idx = ch * CHUNK + 2 * t;
    int e0 = 0, e1 = 0;
    if (idx < NN)     e0 = cnt[idx];
    if (idx + 1 < NN) e1 = cnt[idx + 1];
    int p = e0 + e1;
    int lane = t & 63;
    int incl = p;
#pragma unroll
    for (int d = 1; d < 64; d <<= 1) {
        int v = __shfl_up(incl, d, 64);
        if (lane >= d) incl += v;
    }
    __shared__ int wsum[4];
    if (lane == 63) wsum[t >> 6] = incl;
    __syncthreads();
    int w = t >> 6;
    int wbase = 0;
#pragma unroll
    for (int i = 0; i < 4; i++) if (i < w) wbase += wsum[i];
    int base = csum[arr * NCH + ch] + wbase + (incl - p);   // exclusive prefix of e0
    if (idx < NN)     { o[idx]     = base;      cu[idx]     = base; }
    if (idx + 1 < NN) { o[idx + 1] = base + e0; cu[idx + 1] = base + e0; }
    if (blockIdx.x == 0 && t == 0) { off[NN] = EE; off_s[NN] = EE; }
}

// ---------- fill dst-sorted packed edge array: sd = src | (dst<<16) ----------
__global__ void k_fill(const int* __restrict__ ei, int* __restrict__ cursor,
                       unsigned int* __restrict__ sd_s) {
    int e = blockIdx.x * 256 + threadIdx.x;   // covers EE exactly
    int s = ei[e], d = ei[EE + e];
    int p = atomAddI(&cursor[d], 1);
    sd_s[p] = (unsigned int)s | ((unsigned int)d << 16);
}

// ---------- fill src-CSR permutation: perm_s[q] = dst-order position p ----------
__global__ void k_fill2(const unsigned int* __restrict__ sd_s, int* __restrict__ cursor_s,
                        int* __restrict__ perm_s) {
    int p = blockIdx.x * 256 + threadIdx.x;   // covers EE exactly
    int s = (int)(sd_s[p] & 0xFFFFu);
    int q = atomAddI(&cursor_s[s], 1);
    perm_s[q] = p;
}

// ---------- dsum[n] = x[n] + sum_{e: dst=n} xb[src_e]  (bf16 gather table) ----------
__global__ void k_dsum_csr(const float* __restrict__ x, const unsigned short* __restrict__ xb,
                           const int* __restrict__ off,
                           const unsigned int* __restrict__ sd_s, float* __restrict__ dsum) {
    int team = (blockIdx.x * 256 + threadIdx.x) >> 6;   // 12500 blocks x 4 = NN
    int c = threadIdx.x & 63;
    float a[16];
#pragma unroll
    for (int j = 0; j < 16; j++) a[j] = 0.f;
    a[0] = x[(size_t)team * 64 + c];
    int e = off[team], e1 = off[team + 1];
    for (; e + 15 < e1; e += 16)
#pragma unroll
        for (int j = 0; j < 16; j++) a[j] += bf2f(xb[(size_t)(sd_s[e + j] & 0xFFFFu) * 64 + c]);
    for (; e + 3 < e1; e += 4)
#pragma unroll
        for (int j = 0; j < 4; j++) a[j] += bf2f(xb[(size_t)(sd_s[e + j] & 0xFFFFu) * 64 + c]);
    for (; e < e1; e++) a[0] += bf2f(xb[(size_t)(sd_s[e] & 0xFFFFu) * 64 + c]);
#pragma unroll
    for (int j = 0; j < 8; j++) a[j] += a[j + 8];
#pragma unroll
    for (int j = 0; j < 4; j++) a[j] += a[j + 4];
    dsum[(size_t)team * 64 + c] = (a[0] + a[1]) + (a[2] + a[3]);
}

// ---------- u(bf16) = x@W_top, v = dsum@W_bot, u2 = dsum@W_top ----------
__global__ void k_uv3(const float* __restrict__ x, const float* __restrict__ dsum,
                      const float* __restrict__ W, unsigned short* __restrict__ ub,
                      float* __restrict__ v, float* __restrict__ u2) {
    __shared__ float lds[4][16 * 68];
    const int lane = threadIdx.x & 63;
    const int wid = threadIdx.x >> 6;
    const int m = lane & 15, quad = lane >> 4;
    const int gwave = (blockIdx.x * blockDim.x + threadIdx.x) >> 6;
    const int nwaves = (gridDim.x * blockDim.x) >> 6;
    float* wl = lds[wid];

    bf16x8 wfh[4][4], wfl[4][4];
#pragma unroll
    for (int kk = 0; kk < 4; kk++)
#pragma unroll
        for (int ct = 0; ct < 4; ct++) {
            float wv[8];
#pragma unroll
            for (int j = 0; j < 8; j++)
                wv[j] = W[(kk * 32 + quad * 8 + j) * 64 + ct * 16 + m];
            split8r(wv, wfh[kk][ct], wfl[kk][ct]);
        }
    float zb[4] = {0.f, 0.f, 0.f, 0.f};

    for (int tile = gwave; tile < NT_N; tile += nwaves) {
        const int r = (tile << 4) + m;
        bf16x8 ah[4], al[4];
        split8(x    + (size_t)r * 64 + quad * 8,      ah[0], al[0]);
        split8(x    + (size_t)r * 64 + 32 + quad * 8, ah[1], al[1]);
        split8(dsum + (size_t)r * 64 + quad * 8,      ah[2], al[2]);
        split8(dsum + (size_t)r * 64 + 32 + quad * 8, ah[3], al[3]);

        f32x4 zero = {0.f, 0.f, 0.f, 0.f};
        f32x4 aU[4], aV[4], aU2[4];
#pragma unroll
        for (int ct = 0; ct < 4; ct++) {
            aU[ct] = zero; aV[ct] = zero; aU2[ct] = zero;
#pragma unroll
            for (int kk = 0; kk < 2; kk++) {
                aU[ct]  = __builtin_amdgcn_mfma_f32_16x16x32_bf16(al[kk],   wfh[kk][ct],   aU[ct],  0, 0, 0);
                aU[ct]  = __builtin_amdgcn_mfma_f32_16x16x32_bf16(ah[kk],   wfl[kk][ct],   aU[ct],  0, 0, 0);
                aU[ct]  = __builtin_amdgcn_mfma_f32_16x16x32_bf16(ah[kk],   wfh[kk][ct],   aU[ct],  0, 0, 0);
                aV[ct]  = __builtin_amdgcn_mfma_f32_16x16x32_bf16(al[kk+2], wfh[kk+2][ct], aV[ct],  0, 0, 0);
                aV[ct]  = __builtin_amdgcn_mfma_f32_16x16x32_bf16(ah[kk+2], wfl[kk+2][ct], aV[ct],  0, 0, 0);
                aV[ct]  = __builtin_amdgcn_mfma_f32_16x16x32_bf16(ah[kk+2], wfh[kk+2][ct], aV[ct],  0, 0, 0);
                aU2[ct] = __builtin_amdgcn_mfma_f32_16x16x32_bf16(al[kk+2], wfh[kk][ct],   aU2[ct], 0, 0, 0);
                aU2[ct] = __builtin_amdgcn_mfma_f32_16x16x32_bf16(ah[kk+2], wfl[kk][ct],   aU2[ct], 0, 0, 0);
                aU2[ct] = __builtin_amdgcn_mfma_f32_16x16x32_bf16(ah[kk+2], wfh[kk][ct],   aU2[ct], 0, 0, 0);
            }
        }
        epi_tile_b16(wl, lane, aU, ub, tile);
        epi_tile<false, false>(wl, lane, aV,  zb, v,  tile, nullptr, nullptr);
        epi_tile<false, false>(wl, lane, aU2, zb, u2, tile, nullptr, nullptr);
    }
}

// ---------- analytic stage-1 stats (u read as bf16 for consistency with k_s1h) ----------
__global__ void k_stats1a(const unsigned short* __restrict__ ub, const float* __restrict__ v,
                          const float* __restrict__ u2, const int* __restrict__ od,
                          const int* __restrict__ id, double* __restrict__ stats_raw) {
    __shared__ double lsum[4][64], lsq[4][64];
    int tid = threadIdx.x, c = tid & 63, w = tid >> 6;
    double a1 = 0.0, a2 = 0.0;
    for (int n = blockIdx.x * 4 + w; n < NN; n += gridDim.x * 4) {
        double uu = (double)bf2f(ub[(size_t)n * 64 + c]);
        double vv = v[(size_t)n * 64 + c];
        double uu2 = u2[(size_t)n * 64 + c];
        double wod = 1.0 + od[n], wid = 1.0 + id[n];
        a1 += wod * uu + wid * vv;
        a2 += wod * uu * uu + wid * vv * vv + 2.0 * vv * uu2;
    }
    lsum[w][c] = a1; lsq[w][c] = a2;
    __syncthreads();
    if (w == 0) {
        a1 = lsum[0][c] + lsum[1][c] + lsum[2][c] + lsum[3][c];
        a2 = lsq[0][c] + lsq[1][c] + lsq[2][c] + lsq[3][c];
        atomAddD(&stats_raw[c], a1);
        atomAddD(&stats_raw[64 + c], a2);
    }
}

__global__ void k_fin1(const double* __restrict__ raw, const float* __restrict__ b,
                       float* __restrict__ fin, double inv_cnt) {
    int c = threadIdx.x;
    double m1 = raw[c] * inv_cnt;
    double var = raw[64 + c] * inv_cnt - m1 * m1;
    if (var < 0.0) var = 0.0;
    fin[c] = (float)(m1 + (double)b[c]);
    fin[64 + c] = (float)(1.0 / sqrt(var + 1e-5));
}

__global__ void k_fin(const double* __restrict__ raw, float* __restrict__ fin, double inv_cnt) {
    int c = threadIdx.x;
    double mean = raw[c] * inv_cnt;
    double var = raw[64 + c] * inv_cnt - mean * mean;
    if (var < 0.0) var = 0.0;
    fin[c] = (float)mean;
    fin[64 + c] = (float)(1.0 / sqrt(var + 1e-5));
}

// ---------- stage-1 reduce + per-row h store in BF16 (bf16 u gather) ----------
__global__ void k_s1h(const unsigned short* __restrict__ ub, const float* __restrict__ v,
                      const int* __restrict__ off, const unsigned int* __restrict__ sd_s,
                      const float* __restrict__ b_un, const float* __restrict__ fin,
                      const float* __restrict__ g1, const float* __restrict__ be1,
                      unsigned short* __restrict__ stb, unsigned short* __restrict__ hb) {
    int team = (blockIdx.x * 256 + threadIdx.x) >> 6;
    int c = threadIdx.x & 63;
    float sc = fin[64 + c] * g1[c];
    float tsh = (b_un[c] - fin[c]) * sc + be1[c];
    float vn = v[(size_t)team * 64 + c];
    float a[16];
#pragma unroll
    for (int j = 0; j < 16; j++) a[j] = 0.f;
    float hs = fmaxf((bf2f(ub[(size_t)team * 64 + c]) + vn) * sc + tsh, 0.f);   // self row
    a[0] = hs;
    hb[(size_t)team * 64 + c] = f2bf(hs);
    int e = off[team], e1 = off[team + 1];
    for (; e + 15 < e1; e += 16)
#pragma unroll
        for (int j = 0; j < 16; j++) {
            float h = fmaxf((bf2f(ub[(size_t)(sd_s[e + j] & 0xFFFFu) * 64 + c]) + vn) * sc + tsh, 0.f);
            a[j] += h;
            hb[(size_t)(NN + e + j) * 64 + c] = f2bf(h);
        }
    for (; e + 3 < e1; e += 4)
#pragma unroll
        for (int j = 0; j < 4; j++) {
            float h = fmaxf((bf2f(ub[(size_t)(sd_s[e + j] & 0xFFFFu) * 64 + c]) + vn) * sc + tsh, 0.f);
            a[j] += h;
            hb[(size_t)(NN + e + j) * 64 + c] = f2bf(h);
        }
    for (; e < e1; e++) {
        float h = fmaxf((bf2f(ub[(size_t)(sd_s[e] & 0xFFFFu) * 64 + c]) + vn) * sc + tsh, 0.f);
        a[0] += h;
        hb[(size_t)(NN + e) * 64 + c] = f2bf(h);
    }
#pragma unroll
    for (int j = 0; j < 8; j++) a[j] += a[j + 8];
#pragma unroll
    for (int j = 0; j < 4; j++) a[j] += a[j + 4];
    stb[(size_t)team * 64 + c] = f2bf((a[0] + a[1]) + (a[2] + a[3]));
}

// ---------- msg[n] = sum_{e:dst=n} stb[src_e]  (bf16 gather table) ----------
__global__ void k_msg_csr(const int* __restrict__ off, const unsigned int* __restrict__ sd_s,
                          const unsigned short* __restrict__ stb, float* __restrict__ msg) {
    int team = (blockIdx.x * 256 + threadIdx.x) >> 6;
    int c = threadIdx.x & 63;
    float a[16];
#pragma unroll
    for (int j = 0; j < 16; j++) a[j] = 0.f;
    int e = off[team], e1 = off[team + 1];
    for (; e + 15 < e1; e += 16)
#pragma unroll
        for (int j = 0; j < 16; j++) a[j] += bf2f(stb[(size_t)(sd_s[e + j] & 0xFFFFu) * 64 + c]);
    for (; e + 3 < e1; e += 4)
#pragma unroll
        for (int j = 0; j < 4; j++) a[j] += bf2f(stb[(size_t)(sd_s[e + j] & 0xFFFFu) * 64 + c]);
    for (; e < e1; e++) a[0] += bf2f(stb[(size_t)(sd_s[e] & 0xFFFFu) * 64 + c]);
#pragma unroll
    for (int j = 0; j < 8; j++) a[j] += a[j + 8];
#pragma unroll
    for (int j = 0; j < 4; j++) a[j] += a[j + 4];
    msg[(size_t)team * 64 + c] = (a[0] + a[1]) + (a[2] + a[3]);
}

// ---------- mb = msg @ W_gc[64:128]  (streaming; in/out may differ) ----------
__global__ void k_mb(const float* __restrict__ in, float* __restrict__ outp,
                     const float* __restrict__ W) {
    __shared__ float lds[4][16 * 68];
    const int lane = threadIdx.x & 63;
    const int wid = threadIdx.x >> 6;
    const int m = lane & 15, quad = lane >> 4;
    const int gwave = (blockIdx.x * blockDim.x + threadIdx.x) >> 6;
    const int nwaves = (gridDim.x * blockDim.x) >> 6;
    float* wl = lds[wid];

    bf16x8 wfh[2][4], wfl[2][4];
#pragma unroll
    for (int kk = 0; kk < 2; kk++)
#pragma unroll
        for (int ct = 0; ct < 4; ct++) {
            float wv[8];
#pragma unroll
            for (int j = 0; j < 8; j++)
                wv[j] = W[(kk * 32 + quad * 8 + j) * 64 + ct * 16 + m];
            split8r(wv, wfh[kk][ct], wfl[kk][ct]);
        }
    float zb[4] = {0.f, 0.f, 0.f, 0.f};

    for (int tile = gwave; tile < NT_N; tile += nwaves) {
        const int r = (tile << 4) + m;
        bf16x8 ah[2], al[2];
        split8(in + (size_t)r * 64 + quad * 8,      ah[0], al[0]);
        split8(in + (size_t)r * 64 + 32 + quad * 8, ah[1], al[1]);

        f32x4 zero = {0.f, 0.f, 0.f, 0.f};
        f32x4 acc[4];
#pragma unroll
        for (int ct = 0; ct < 4; ct++) {
            acc[ct] = zero;
#pragma unroll
            for (int kk = 0; kk < 2; kk++) {
                acc[ct] = __builtin_amdgcn_mfma_f32_16x16x32_bf16(al[kk], wfh[kk][ct], acc[ct], 0, 0, 0);
                acc[ct] = __builtin_amdgcn_mfma_f32_16x16x32_bf16(ah[kk], wfl[kk][ct], acc[ct], 0, 0, 0);
                acc[ct] = __builtin_amdgcn_mfma_f32_16x16x32_bf16(ah[kk], wfh[kk][ct], acc[ct], 0, 0, 0);
            }
        }
        epi_tile<false, false>(wl, lane, acc, zb, outp, tile, nullptr, nullptr);
    }
}

// ---------- stage-2 streaming matmul over bf16 h rows:
// h2b[r] = bf16( hb[r]@Wtop2 + mb[dst(r)] + b_gc ); stats via block partials (no atomics).
__global__ void k_h2(const unsigned short* __restrict__ hb, unsigned short* __restrict__ h2b,
                     const float* __restrict__ mb, const unsigned int* __restrict__ sd_s,
                     const float* __restrict__ W, const float* __restrict__ b_gc,
                     double* __restrict__ part) {
    __shared__ float lds[4][16 * 68];
    const int lane = threadIdx.x & 63;
    const int wid = threadIdx.x >> 6;
    const int m = lane & 15, quad = lane >> 4;
    const int gwave = (blockIdx.x * blockDim.x + threadIdx.x) >> 6;
    const int nwaves = (gridDim.x * blockDim.x) >> 6;
    float* wl = lds[wid];

    bf16x8 wfh[2][4], wfl[2][4];
#pragma unroll
    for (int kk = 0; kk < 2; kk++)
#pragma unroll
        for (int ct = 0; ct < 4; ct++) {
            float wv[8];
#pragma unroll
            for (int j = 0; j < 8; j++)
                wv[j] = W[(kk * 32 + quad * 8 + j) * 64 + ct * 16 + m];
            split8r(wv, wfh[kk][ct], wfl[kk][ct]);
        }

    float bv[4];
#pragma unroll
    for (int ct = 0; ct < 4; ct++) bv[ct] = b_gc[ct * 16 + m];

    double ssum[4] = {0,0,0,0}, ssq[4] = {0,0,0,0};

    for (int tile = gwave; tile < NT_R; tile += nwaves) {
        const int r = (tile << 4) + m;
        int dm = (tile < NT_N) ? r : (int)(sd_s[r - NN] >> 16);

        bf16x8 ah[2];
        ah[0] = *reinterpret_cast<const bf16x8*>(hb + (size_t)r * 64 + quad * 8);
        ah[1] = *reinterpret_cast<const bf16x8*>(hb + (size_t)r * 64 + 32 + quad * 8);

        f32x4 zero = {0.f, 0.f, 0.f, 0.f};
        f32x4 acc[4];
#pragma unroll
        for (int ct = 0; ct < 4; ct++) {
            acc[ct] = zero;
#pragma unroll
            for (int kk = 0; kk < 2; kk++) {
                acc[ct] = __builtin_amdgcn_mfma_f32_16x16x32_bf16(ah[kk], wfl[kk][ct], acc[ct], 0, 0, 0);
                acc[ct] = __builtin_amdgcn_mfma_f32_16x16x32_bf16(ah[kk], wfh[kk][ct], acc[ct], 0, 0, 0);
            }
        }

        // add mb[dst_of_row] + b_gc per element, then stats + LDS-coalesced bf16 store
#pragma unroll
        for (int i = 0; i < 4; i++) {
            int dmv = __shfl(dm, (lane & 48) + quad * 4 + i, 64);   // dm of row quad*4+i
#pragma unroll
            for (int ct = 0; ct < 4; ct++) {
                float val = acc[ct][i] + bv[ct] + mb[(size_t)dmv * 64 + ct * 16 + m];
                wl[(quad * 4 + i) * 68 + ct * 16 + m] = val;
                ssum[ct] += (double)val;
                ssq[ct]  += (double)val * (double)val;
            }
        }
        asm volatile("s_waitcnt lgkmcnt(0)" ::: "memory");
#pragma unroll
        for (int j = 0; j < 4; j++) {
            int row = j * 4 + quad;
            f32x4 vv = *reinterpret_cast<const f32x4*>(wl + row * 68 + m * 4);
            unsigned int p0 = (unsigned int)f2bf(vv[0]) | ((unsigned int)f2bf(vv[1]) << 16);
            unsigned int p1 = (unsigned int)f2bf(vv[2]) | ((unsigned int)f2bf(vv[3]) << 16);
            uint2 pk; pk.x = p0; pk.y = p1;
            *reinterpret_cast<uint2*>(h2b + ((size_t)(tile << 4) + row) * 64 + m * 4) = pk;
        }
    }

    stats_block_out(&lds[0][0], lane, wid, ssum, ssq, part);
}

// ---------- agg[n] = relu(bn2(h2b[n])) + sum_{q in src-CSR} relu(bn2(h2b[NN+perm_s[q]])) ----------
__global__ void k_agg_csr(const unsigned short* __restrict__ h2b, const int* __restrict__ off_s,
                          const int* __restrict__ perm_s, const float* __restrict__ fin2,
                          const float* __restrict__ g2, const float* __restrict__ be2,
                          float* __restrict__ agg) {
    int n = (blockIdx.x * 256 + threadIdx.x) >> 6;
    int c = threadIdx.x & 63;
    float sc = fin2[64 + c] * g2[c];
    float sh = be2[c] - fin2[c] * sc;
    float a[16];
#pragma unroll
    for (int j = 0; j < 16; j++) a[j] = 0.f;
    a[0] = fmaxf(bf2f(h2b[(size_t)n * 64 + c]) * sc + sh, 0.f);   // self row
    int q = off_s[n], q1 = off_s[n + 1];
    for (; q + 15 < q1; q += 16)
#pragma unroll
        for (int j = 0; j < 16; j++) {
            float hv = bf2f(h2b[(size_t)(NN + perm_s[q + j]) * 64 + c]);
            a[j] += fmaxf(hv * sc + sh, 0.f);
        }
    for (; q + 3 < q1; q += 4)
#pragma unroll
        for (int j = 0; j < 4; j++) {
            float hv = bf2f(h2b[(size_t)(NN + perm_s[q + j]) * 64 + c]);
            a[j] += fmaxf(hv * sc + sh, 0.f);
        }
    for (; q < q1; q++) {
        float hv = bf2f(h2b[(size_t)(NN + perm_s[q]) * 64 + c]);
        a[0] += fmaxf(hv * sc + sh, 0.f);
    }
#pragma unroll
    for (int j = 0; j < 8; j++) a[j] += a[j + 8];
#pragma unroll
    for (int j = 0; j < 4; j++) a[j] += a[j + 4];
    agg[(size_t)n * 64 + c] = (a[0] + a[1]) + (a[2] + a[3]);
}

// ---------- stage 3: t_pre = [relu(bn2(h2b[:N])), agg] @ W_tr + b_tr, stats3 ----------
__global__ void k_mm3(const unsigned short* __restrict__ h2b, const float* __restrict__ agg,
                      const float* __restrict__ W, const float* __restrict__ bias,
                      const float* __restrict__ fin2, const float* __restrict__ g2,
                      const float* __restrict__ be2,
                      float* __restrict__ outp, double* __restrict__ part) {
    __shared__ float lds[4][16 * 68];
    const int lane = threadIdx.x & 63;
    const int wid = threadIdx.x >> 6;
    const int m = lane & 15, quad = lane >> 4;
    const int gwave = (blockIdx.x * blockDim.x + threadIdx.x) >> 6;
    const int nwaves = (gridDim.x * blockDim.x) >> 6;
    float* wl = lds[wid];

    bf16x8 wfh[4][4], wfl[4][4];
#pragma unroll
    for (int kk = 0; kk < 4; kk++)
#pragma unroll
        for (int ct = 0; ct < 4; ct++) {
            float wv[8];
#pragma unroll
            for (int j = 0; j < 8; j++)
                wv[j] = W[(kk * 32 + quad * 8 + j) * 64 + ct * 16 + m];
            split8r(wv, wfh[kk][ct], wfl[kk][ct]);
        }

    float bv[4];
#pragma unroll
    for (int ct = 0; ct < 4; ct++) bv[ct] = bias[ct * 16 + m];

    float s2f[2][8], t2f[2][8];
#pragma unroll
    for (int kk = 0; kk < 2; kk++)
#pragma unroll
        for (int j = 0; j < 8; j++) {
            int c = kk * 32 + quad * 8 + j;
            float sc = fin2[64 + c] * g2[c];
            s2f[kk][j] = sc;
            t2f[kk][j] = be2[c] - fin2[c] * sc;
        }

    double ssum[4] = {0,0,0,0}, ssq[4] = {0,0,0,0};

    for (int tile = gwave; tile < NT_N; tile += nwaves) {
        const int r = (tile << 4) + m;
        bf16x8 ah[4], al[4];
#pragma unroll
        for (int kk = 0; kk < 2; kk++) {
            bf16x8 hv = *reinterpret_cast<const bf16x8*>(h2b + (size_t)r * 64 + kk * 32 + quad * 8);
            float tv[8];
#pragma unroll
            for (int j = 0; j < 8; j++) {
                float f = bf2f((unsigned short)hv[j]);
                tv[j] = fmaxf(f * s2f[kk][j] + t2f[kk][j], 0.f);
            }
            split8r(tv, ah[kk], al[kk]);
        }
        split8(agg + (size_t)r * 64 + quad * 8,      ah[2], al[2]);
        split8(agg + (size_t)r * 64 + 32 + quad * 8, ah[3], al[3]);

        f32x4 zero = {0.f, 0.f, 0.f, 0.f};
        f32x4 acc[4];
#pragma unroll
        for (int ct = 0; ct < 4; ct++) {
            acc[ct] = zero;
#pragma unroll
            for (int kk = 0; kk < 4; kk++)
                acc[ct] = __builtin_amdgcn_mfma_f32_16x16x32_bf16(al[kk], wfh[kk][ct], acc[ct], 0, 0, 0);
#pragma unroll
            for (int kk = 0; kk < 4; kk++)
                acc[ct] = __builtin_amdgcn_mfma_f32_16x16x32_bf16(ah[kk], wfl[kk][ct], acc[ct], 0, 0, 0);
#pragma unroll
            for (int kk = 0; kk < 4; kk++)
                acc[ct] = __builtin_amdgcn_mfma_f32_16x16x32_bf16(ah[kk], wfh[kk][ct], acc[ct], 0, 0, 0);
        }

        epi_tile<false, true>(wl, lane, acc, bv, outp, tile, ssum, ssq);
    }

    stats_block_out(&lds[0][0], lane, wid, ssum, ssq, part);
}

// ---------- stage 4 ----------
__global__ void k_mm4(const float* __restrict__ tpre, const float* __restrict__ W,
                      const float* __restrict__ bias, const float* __restrict__ fin3,
                      const float* __restrict__ g2, const float* __restrict__ be2,
                      float* __restrict__ outp, double* __restrict__ part) {
    __shared__ float lds[4][16 * 68];
    const int lane = threadIdx.x & 63;
    const int wid = threadIdx.x >> 6;
    const int m = lane & 15, quad = lane >> 4;
    const int gwave = (blockIdx.x * blockDim.x + threadIdx.x) >> 6;
    const int nwaves = (gridDim.x * blockDim.x) >> 6;
    float* wl = lds[wid];

    bf16x8 wfh[2][4], wfl[2][4];
#pragma unroll
    for (int kk = 0; kk < 2; kk++)
#pragma unroll
        for (int ct = 0; ct < 4; ct++) {
            float wv[8];
#pragma unroll
            for (int j = 0; j < 8; j++)
                wv[j] = W[(kk * 32 + quad * 8 + j) * 64 + ct * 16 + m];
            split8r(wv, wfh[kk][ct], wfl[kk][ct]);
        }

    float bv[4];
#pragma unroll
    for (int ct = 0; ct < 4; ct++) bv[ct] = bias[ct * 16 + m];

    float sc[2][8], sh[2][8];
#pragma unroll
    for (int kk = 0; kk < 2; kk++)
#pragma unroll
        for (int j = 0; j < 8; j++) {
            int c = kk * 32 + quad * 8 + j;
            float s = fin3[64 + c] * g2[c];
            sc[kk][j] = s;
            sh[kk][j] = be2[c] - fin3[c] * s;
        }

    double ssum[4] = {0,0,0,0}, ssq[4] = {0,0,0,0};

    for (int tile = gwave; tile < NT_N; tile += nwaves) {
        const int r = (tile << 4) + m;
        bf16x8 ah[2], al[2];
#pragma unroll
        for (int kk = 0; kk < 2; kk++) {
            f32x4 v0 = *reinterpret_cast<const f32x4*>(tpre + (size_t)r * 64 + kk * 32 + quad * 8);
            f32x4 v1 = *reinterpret_cast<const f32x4*>(tpre + (size_t)r * 64 + kk * 32 + quad * 8 + 4);
            float tv[8];
#pragma unroll
            for (int j = 0; j < 4; j++) {
                tv[j]     = fmaxf(v0[j] * sc[kk][j]     + sh[kk][j],     0.f);
                tv[4 + j] = fmaxf(v1[j] * sc[kk][4 + j] + sh[kk][4 + j], 0.f);
            }
            split8r(tv, ah[kk], al[kk]);
        }

        f32x4 zero = {0.f, 0.f, 0.f, 0.f};
        f32x4 acc[4];
#pragma unroll
        for (int ct = 0; ct < 4; ct++) {
            acc[ct] = zero;
#pragma unroll
            for (int kk = 0; kk < 2; kk++) {
                acc[ct] = __builtin_amdgcn_mfma_f32_16x16x32_bf16(al[kk], wfh[kk][ct], acc[ct], 0, 0, 0);
                acc[ct] = __builtin_amdgcn_mfma_f32_16x16x32_bf16(ah[kk], wfl[kk][ct], acc[ct], 0, 0, 0);
                acc[ct] = __builtin_amdgcn_mfma_f32_16x16x32_bf16(ah[kk], wfh[kk][ct], acc[ct], 0, 0, 0);
            }
        }

        epi_tile<true, true>(wl, lane, acc, bv, outp, tile, ssum, ssq);
    }

    stats_block_out(&lds[0][0], lane, wid, ssum, ssq, part);
}

// out = relu(bn(out_pre; stats4, g3, be3)) -> f32
__global__ void k_out(const float* __restrict__ op, const float* __restrict__ fin,
                      const float* __restrict__ g, const float* __restrict__ be,
                      float* __restrict__ out) {
    int i = blockIdx.x * 256 + threadIdx.x;   // covers NN*64 exactly
    int c = i & 63;
    out[i] = fmaxf((op[i] - fin[c]) * fin[64 + c] * g[c] + be[c], 0.f);
}

extern "C" void kernel_launch(void* const* d_in, const int* in_sizes, int n_in,
                              void* d_out, int out_size, void* d_ws, size_t ws_size,
                              hipStream_t stream) {
    const float* x    = (const float*)d_in[0];
    const int*   ei   = (const int*)d_in[1];
    const float* W_un = (const float*)d_in[2];
    const float* b_un = (const float*)d_in[3];
    const float* g1   = (const float*)d_in[4];
    const float* be1  = (const float*)d_in[5];
    const float* W_gc = (const float*)d_in[6];
    const float* b_gc = (const float*)d_in[7];
    const float* g2   = (const float*)d_in[8];
    const float* be2  = (const float*)d_in[9];
    const float* W_tr = (const float*)d_in[10];
    const float* b_tr = (const float*)d_in[11];
    const float* W_li = (const float*)d_in[12];
    const float* b_li = (const float*)d_in[13];
    const float* g3   = (const float*)d_in[14];
    const float* be3  = (const float*)d_in[15];

    float* ws = (float*)d_ws;
    const size_t FN = (size_t)NN * 64;           // 3.2M floats (12.8 MB)
    const size_t FR = (size_t)RR * 64;           // 54.4M floats (217.6 MB)
    // Region plan (zero growth; lifetimes verified):
    //  P0: ub (bf16, FN ushorts) -> msg/mb -> part_mm3 -> outpre
    //  P1: v -> agg -> part_mm4
    //  P2: csum -> stb (bf16) -> part_h2 -> tpre
    //  H (FR floats): dsum [0,FN), u2 [FN,2FN), xb16 [2FN,2.5FN) — all dead after stats1a/dsum
    //      -> hb (FR ushorts = slots [0,FR/2)) + h2b (FR ushorts = slots [FR/2,FR))
    float* P0 = ws;
    float* P1 = ws + FN;
    float* P2 = ws + 2 * FN;
    float* H  = ws + 3 * FN;
    unsigned short* ub   = (unsigned short*)P0;      // bf16 u table (gathered by k_s1h)
    float* v      = P1;
    unsigned short* stb  = (unsigned short*)P2;      // bf16 s_tab (gathered by k_msg)
    int*   csum   = (int*)P2;     // 196 ints, scan scratch (dead before k_s1h writes stb)
    float* dsum   = H;
    float* u2     = H + FN;
    unsigned short* xb16 = (unsigned short*)(H + 2 * FN);   // bf16 x copy (k_dsum gather)
    unsigned short* hb  = (unsigned short*)H;        // bf16 h rows
    unsigned short* h2b = (unsigned short*)H + FR;   // bf16 h2pre rows
    float* msg    = P0;           // becomes mb after k_mb (in place; ub dead)
    float* agg    = P1;
    float* tpre   = P2;
    float* outpre = P0;
    double* part_h2 = (double*)P2;   // 2048*128*8B = 2MB   (stb dead, before tpre)
    double* part_m3 = (double*)P0;   // 512*128*8B = 512KB  (mb dead, before outpre)
    double* part_m4 = (double*)P1;   // 512KB               (agg dead)
    double*       stats_raw = (double*)(H + FR);
    int*          od        = (int*)(stats_raw + 512);
    int*          id        = od + NN;
    int*          off       = id + NN;
    int*          cursor    = off + NN + 1;
    int*          off_s     = cursor + NN;
    int*          cursor_s  = off_s + NN + 1;
    unsigned int* sd_s      = (unsigned int*)(cursor_s + NN);   // packed src|dst<<16, dst-sorted
    int*          perm_s    = (int*)(sd_s + EE);
    float*        stats_fin = (float*)(perm_s + EE);

    // zero: stats_raw + od + id (contiguous)
    hipMemsetAsync(stats_raw, 0, 512 * sizeof(double) + 2 * NN * sizeof(int), stream);

    // build dst-sorted packed edge list + src-CSR permutation (coalesced 3-phase scan)
    k_deg  <<<3125, 256, 0, stream>>>(ei, od, id);
    k_xc   <<<12500, 256, 0, stream>>>(x, xb16);
    k_scanA<<<2 * NCH, 256, 0, stream>>>(id, od, csum);
    k_scanB<<<1, 256, 0, stream>>>(csum);
    k_scanC<<<2 * NCH, 256, 0, stream>>>(id, od, csum, off, cursor, off_s, cursor_s);
    k_fill <<<3125, 256, 0, stream>>>(ei, cursor, sd_s);
    k_fill2<<<3125, 256, 0, stream>>>(sd_s, cursor_s, perm_s);

    // stage 0 + per-node tables
    k_dsum_csr<<<12500, 256, 0, stream>>>(x, xb16, off, sd_s, dsum);
    k_uv3<<<512, 256, 0, stream>>>(x, dsum, W_un, ub, v, u2);

    // stage-1: analytic stats, then CSR reduce + per-row bf16 h store
    k_stats1a<<<256, 256, 0, stream>>>(ub, v, u2, od, id, stats_raw + 0);
    k_fin1<<<1, 64, 0, stream>>>(stats_raw + 0, b_un, stats_fin + 0, 1.0 / (double)RR);
    k_s1h<<<12500, 256, 0, stream>>>(ub, v, off, sd_s, b_un, stats_fin + 0, g1, be1,
                                     stb, hb);
    k_msg_csr<<<12500, 256, 0, stream>>>(off, sd_s, stb, msg);
    k_mb<<<512, 256, 0, stream>>>(msg, msg, W_gc + 64 * 64);   // msg -> mb in place

    // stage-2: streaming matmul over bf16 h rows -> bf16 h2 rows, block-partial stats
    k_h2<<<NBLK_H2, 256, 0, stream>>>(hb, h2b, msg, sd_s, W_gc, b_gc, part_h2);
    k_red<<<32, 128, 0, stream>>>(part_h2, NBLK_H2, stats_raw + 128);
    k_fin<<<1, 64, 0, stream>>>(stats_raw + 128, stats_fin + 128, 1.0 / (double)RR);
    k_agg_csr<<<12500, 256, 0, stream>>>(h2b, off_s, perm_s, stats_fin + 128, g2, be2, agg);

    // stage 3
    k_mm3<<<NBLK_MM, 256, 0, stream>>>(h2b, agg, W_tr, b_tr, stats_fin + 128, g2, be2,
                                       tpre, part_m3);
    k_red<<<16, 128, 0, stream>>>(part_m3, NBLK_MM, stats_raw + 256);
    k_fin<<<1, 64, 0, stream>>>(stats_raw + 256, stats_fin + 256, 1.0 / (double)NN);

    // stage 4
    k_mm4<<<NBLK_MM, 256, 0, stream>>>(tpre, W_li, b_li, stats_fin + 256, g2, be2,
                                       outpre, part_m4);
    k_red<<<16, 128, 0, stream>>>(part_m4, NBLK_MM, stats_raw + 384);
    k_fin<<<1, 64, 0, stream>>>(stats_raw + 384, stats_fin + 384, 1.0 / (double)NN);

    k_out<<<12500, 256, 0, stream>>>(outpre, stats_fin + 384, g3, be3, (float*)d_out);
}

// Round 10
// 689.010 us; speedup vs baseline: 2.6995x; 1.0402x over previous
//
#include <hip/hip_runtime.h>
#include <cstdint>
#include <math.h>

// Problem sizes (fixed by the reference).
#define NN 50000
#define EE 800000
#define RR 850000      // NN + EE rows
#define NT_N 3125      // NN/16
#define NT_R 53125     // RR/16
#define NBLK_H2 2048
#define NBLK_MM 512
#define CHUNK 512
#define NCH 98         // ceil(NN/CHUNK)

typedef short  bf16x8 __attribute__((ext_vector_type(8)));
typedef float  f32x4  __attribute__((ext_vector_type(4)));

__device__ __forceinline__ float bf2f(unsigned short b) {
    unsigned int u = ((unsigned int)b) << 16;
    return __builtin_bit_cast(float, u);
}
__device__ __forceinline__ unsigned short f2bf(float f) {
    unsigned int u = __builtin_bit_cast(unsigned int, f);
    u = u + 0x7fffu + ((u >> 16) & 1u);
    return (unsigned short)(u >> 16);
}
__device__ __forceinline__ void atomAddD(double* p, double v) { unsafeAtomicAdd(p, v); }
__device__ __forceinline__ int atomAddI(int* p, int v) { return atomicAdd(p, v); }

// split 8 consecutive f32 into hi/lo bf16 fragments: hi+lo == v to ~2^-16 rel
__device__ __forceinline__ void split8(const float* p, bf16x8& hi, bf16x8& lo) {
    f32x4 v0 = *reinterpret_cast<const f32x4*>(p);
    f32x4 v1 = *reinterpret_cast<const f32x4*>(p + 4);
#pragma unroll
    for (int j = 0; j < 4; j++) {
        unsigned short h0 = f2bf(v0[j]);
        hi[j] = (short)h0; lo[j] = (short)f2bf(v0[j] - bf2f(h0));
        unsigned short h1 = f2bf(v1[j]);
        hi[4 + j] = (short)h1; lo[4 + j] = (short)f2bf(v1[j] - bf2f(h1));
    }
}
__device__ __forceinline__ void split8r(const float* v, bf16x8& hi, bf16x8& lo) {
#pragma unroll
    for (int j = 0; j < 8; j++) {
        unsigned short h = f2bf(v[j]);
        hi[j] = (short)h; lo[j] = (short)f2bf(v[j] - bf2f(h));
    }
}

// LDS-staged coalesced tile store: MFMA C-layout -> 4x 1KB contiguous dwordx4 stores.
template <bool RELU, bool STATS>
__device__ __forceinline__ void epi_tile(float* wl, int lane, const f32x4* acc,
                                         const float* bv, float* __restrict__ gout,
                                         int tile, double* ssum, double* ssq) {
    const int m = lane & 15, quad = lane >> 4;
#pragma unroll
    for (int ct = 0; ct < 4; ct++)
#pragma unroll
        for (int i = 0; i < 4; i++) {
            float val = acc[ct][i] + bv[ct];
            if (RELU) val = fmaxf(val, 0.f);
            wl[(quad * 4 + i) * 68 + ct * 16 + m] = val;
            if (STATS) { ssum[ct] += (double)val; ssq[ct] += (double)val * (double)val; }
        }
    asm volatile("s_waitcnt lgkmcnt(0)" ::: "memory");
#pragma unroll
    for (int j = 0; j < 4; j++) {
        int row = j * 4 + quad;
        f32x4 vv = *reinterpret_cast<const f32x4*>(wl + row * 68 + m * 4);
        *reinterpret_cast<f32x4*>(gout + ((size_t)(tile << 4) + row) * 64 + m * 4) = vv;
    }
}

// bf16 variant: stage f32 in LDS, pack to bf16, coalesced uint2 stores.
__device__ __forceinline__ void epi_tile_b16(float* wl, int lane, const f32x4* acc,
                                             unsigned short* __restrict__ gout, int tile) {
    const int m = lane & 15, quad = lane >> 4;
#pragma unroll
    for (int ct = 0; ct < 4; ct++)
#pragma unroll
        for (int i = 0; i < 4; i++)
            wl[(quad * 4 + i) * 68 + ct * 16 + m] = acc[ct][i];
    asm volatile("s_waitcnt lgkmcnt(0)" ::: "memory");
#pragma unroll
    for (int j = 0; j < 4; j++) {
        int row = j * 4 + quad;
        f32x4 vv = *reinterpret_cast<const f32x4*>(wl + row * 68 + m * 4);
        unsigned int p0 = (unsigned int)f2bf(vv[0]) | ((unsigned int)f2bf(vv[1]) << 16);
        unsigned int p1 = (unsigned int)f2bf(vv[2]) | ((unsigned int)f2bf(vv[3]) << 16);
        uint2 pk; pk.x = p0; pk.y = p1;
        *reinterpret_cast<uint2*>(gout + ((size_t)(tile << 4) + row) * 64 + m * 4) = pk;
    }
}

// block-level stats reduce: wave shfl-reduce -> LDS -> one coalesced 1KB store per block.
__device__ __forceinline__ void stats_block_out(float* ldsbase, int lane, int wid,
                                                const double* ssum, const double* ssq,
                                                double* __restrict__ part) {
    const int m = lane & 15, quad = lane >> 4;
    double* dl = (double*)ldsbase;
    __syncthreads();
#pragma unroll
    for (int ct = 0; ct < 4; ct++) {
        double sv = ssum[ct], qv = ssq[ct];
        sv += __shfl_xor(sv, 16, 64); sv += __shfl_xor(sv, 32, 64);
        qv += __shfl_xor(qv, 16, 64); qv += __shfl_xor(qv, 32, 64);
        if (quad == 0) {
            dl[wid * 128 + ct * 16 + m]      = sv;
            dl[wid * 128 + 64 + ct * 16 + m] = qv;
        }
    }
    __syncthreads();
    int tid = wid * 64 + lane;
    if (tid < 128) {
        double tot = dl[tid] + dl[128 + tid] + dl[256 + tid] + dl[384 + tid];
        part[(size_t)blockIdx.x * 128 + tid] = tot;
    }
}

// reduce block partials into raw[0..127] (few spread atomics only)
__global__ void k_red(const double* __restrict__ p, int nblk, double* __restrict__ raw) {
    int t = threadIdx.x;   // 128
    double acc = 0.0;
    for (int b = blockIdx.x; b < nblk; b += gridDim.x)
        acc += p[(size_t)b * 128 + t];
    atomAddD(&raw[t], acc);
}

// ---------- degree counts + x -> bf16 copy (fused) ----------
__global__ void k_degx(const int* __restrict__ ei, int* __restrict__ od, int* __restrict__ id,
                       const float* __restrict__ x, unsigned short* __restrict__ xb) {
    int i = blockIdx.x * 256 + threadIdx.x;   // 12500 blocks -> covers NN*64
    xb[i] = f2bf(x[i]);
    if (i < EE) {
        atomAddI(&od[ei[i]], 1);
        atomAddI(&id[ei[EE + i]], 1);
    }
}

// ---------- coalesced 3-phase dual scan ----------
__global__ void k_scanA(const int* __restrict__ id, const int* __restrict__ od,
                        int* __restrict__ csum) {
    int arr = blockIdx.x / NCH;
    int ch  = blockIdx.x % NCH;
    const int* cnt = arr ? od : id;
    int t = threadIdx.x;
    int i0 = ch * CHUNK + t;
    int s = 0;
    if (i0 < NN) s += cnt[i0];
    if (i0 + 256 < NN && (t + 256) < CHUNK) s += cnt[i0 + 256];
#pragma unroll
    for (int d = 1; d < 64; d <<= 1) s += __shfl_xor(s, d, 64);
    __shared__ int ws[4];
    if ((t & 63) == 0) ws[t >> 6] = s;
    __syncthreads();
    if (t == 0) csum[arr * NCH + ch] = ws[0] + ws[1] + ws[2] + ws[3];
}

__global__ void k_scanB(int* __restrict__ csum) {
    __shared__ int part[256];
    int t = threadIdx.x;
    int arr = t >> 7, slot = t & 127;
    int v = (slot < NCH) ? csum[arr * NCH + slot] : 0;
    part[t] = v;
    __syncthreads();
#pragma unroll
    for (int d = 1; d < 128; d <<= 1) {
        int val = (slot >= d) ? part[t - d] : 0;
        __syncthreads();
        part[t] += val;
        __syncthreads();
    }
    if (slot < NCH)
        csum[arr * NCH + slot] = (slot == 0) ? 0 : part[t - 1];
}

__global__ void k_scanC(const int* __restrict__ id, const int* __restrict__ od,
                        const int* __restrict__ csum,
                        int* __restrict__ off, int* __restrict__ cursor,
                        int* __restrict__ off_s, int* __restrict__ cursor_s) {
    int arr = blockIdx.x / NCH;
    int ch  = blockIdx.x % NCH;
    const int* cnt = arr ? od : id;
    int* o  = arr ? off_s : off;
    int* cu = arr ? cursor_s : cursor;
    int t = threadIdx.x;                 // 256 threads x 2 contiguous elems
    int idx = ch * CHUNK + 2 * t;
    int e0 = 0, e1 = 0;
    if (idx < NN)     e0 = cnt[idx];
    if (idx + 1 < NN) e1 = cnt[idx + 1];
    int p = e0 + e1;
    int lane = t & 63;
    int incl = p;
#pragma unroll
    for (int d = 1; d < 64; d <<= 1) {
        int v = __shfl_up(incl, d, 64);
        if (lane >= d) incl += v;
    }
    __shared__ int wsum[4];
    if (lane == 63) wsum[t >> 6] = incl;
    __syncthreads();
    int w = t >> 6;
    int wbase = 0;
#pragma unroll
    for (int i = 0; i < 4; i++) if (i < w) wbase += wsum[i];
    int base = csum[arr * NCH + ch] + wbase + (incl - p);   // exclusive prefix of e0
    if (idx < NN)     { o[idx]     = base;      cu[idx]     = base; }
    if (idx + 1 < NN) { o[idx + 1] = base + e0; cu[idx + 1] = base + e0; }
    if (blockIdx.x == 0 && t == 0) { off[NN] = EE; off_s[NN] = EE; }
}

// ---------- fill dst-sorted packed edge array: sd = src | (dst<<16) ----------
__global__ void k_fill(const int* __restrict__ ei, int* __restrict__ cursor,
                       unsigned int* __restrict__ sd_s) {
    int e = blockIdx.x * 256 + threadIdx.x;   // covers EE exactly
    int s = ei[e], d = ei[EE + e];
    int p = atomAddI(&cursor[d], 1);
    sd_s[p] = (unsigned int)s | ((unsigned int)d << 16);
}

// ---------- fill src-CSR permutation: perm_s[q] = dst-order position p ----------
__global__ void k_fill2(const unsigned int* __restrict__ sd_s, int* __restrict__ cursor_s,
                        int* __restrict__ perm_s) {
    int p = blockIdx.x * 256 + threadIdx.x;   // covers EE exactly
    int s = (int)(sd_s[p] & 0xFFFFu);
    int q = atomAddI(&cursor_s[s], 1);
    perm_s[q] = p;
}

// ---------- dsum[n] = x[n] + sum_{e: dst=n} xb[src_e]  (bf16 gather table) ----------
__global__ void k_dsum_csr(const float* __restrict__ x, const unsigned short* __restrict__ xb,
                           const int* __restrict__ off,
                           const unsigned int* __restrict__ sd_s, float* __restrict__ dsum) {
    int team = (blockIdx.x * 256 + threadIdx.x) >> 6;   // 12500 blocks x 4 = NN
    int c = threadIdx.x & 63;
    float a[16];
#pragma unroll
    for (int j = 0; j < 16; j++) a[j] = 0.f;
    a[0] = x[(size_t)team * 64 + c];
    int e = off[team], e1 = off[team + 1];
    for (; e + 15 < e1; e += 16)
#pragma unroll
        for (int j = 0; j < 16; j++) a[j] += bf2f(xb[(size_t)(sd_s[e + j] & 0xFFFFu) * 64 + c]);
    for (; e + 3 < e1; e += 4)
#pragma unroll
        for (int j = 0; j < 4; j++) a[j] += bf2f(xb[(size_t)(sd_s[e + j] & 0xFFFFu) * 64 + c]);
    for (; e < e1; e++) a[0] += bf2f(xb[(size_t)(sd_s[e] & 0xFFFFu) * 64 + c]);
#pragma unroll
    for (int j = 0; j < 8; j++) a[j] += a[j + 8];
#pragma unroll
    for (int j = 0; j < 4; j++) a[j] += a[j + 4];
    dsum[(size_t)team * 64 + c] = (a[0] + a[1]) + (a[2] + a[3]);
}

// ---------- u(bf16) = x@W_top, v = dsum@W_bot, FUSED stage-1 stats (u2 never stored) ----------
// stats: S1 += wod*u + wid*v ; S2 += wod*u^2 + wid*v^2 + 2*v*u2  (u2 = dsum@W_top, in regs)
__global__ void k_uv3(const float* __restrict__ x, const float* __restrict__ dsum,
                      const float* __restrict__ W,
                      const int* __restrict__ od, const int* __restrict__ id,
                      unsigned short* __restrict__ ub, float* __restrict__ v,
                      double* __restrict__ part) {
    __shared__ float lds[4][16 * 68];
    const int lane = threadIdx.x & 63;
    const int wid_ = threadIdx.x >> 6;
    const int m = lane & 15, quad = lane >> 4;
    const int gwave = (blockIdx.x * blockDim.x + threadIdx.x) >> 6;
    const int nwaves = (gridDim.x * blockDim.x) >> 6;
    float* wl = lds[wid_];

    bf16x8 wfh[4][4], wfl[4][4];
#pragma unroll
    for (int kk = 0; kk < 4; kk++)
#pragma unroll
        for (int ct = 0; ct < 4; ct++) {
            float wv[8];
#pragma unroll
            for (int j = 0; j < 8; j++)
                wv[j] = W[(kk * 32 + quad * 8 + j) * 64 + ct * 16 + m];
            split8r(wv, wfh[kk][ct], wfl[kk][ct]);
        }
    float zb[4] = {0.f, 0.f, 0.f, 0.f};
    double ssum[4] = {0,0,0,0}, ssq[4] = {0,0,0,0};

    for (int tile = gwave; tile < NT_N; tile += nwaves) {
        const int r = (tile << 4) + m;
        bf16x8 ah[4], al[4];
        split8(x    + (size_t)r * 64 + quad * 8,      ah[0], al[0]);
        split8(x    + (size_t)r * 64 + 32 + quad * 8, ah[1], al[1]);
        split8(dsum + (size_t)r * 64 + quad * 8,      ah[2], al[2]);
        split8(dsum + (size_t)r * 64 + 32 + quad * 8, ah[3], al[3]);

        f32x4 zero = {0.f, 0.f, 0.f, 0.f};
        f32x4 aU[4], aV[4], aU2[4];
#pragma unroll
        for (int ct = 0; ct < 4; ct++) {
            aU[ct] = zero; aV[ct] = zero; aU2[ct] = zero;
#pragma unroll
            for (int kk = 0; kk < 2; kk++) {
                aU[ct]  = __builtin_amdgcn_mfma_f32_16x16x32_bf16(al[kk],   wfh[kk][ct],   aU[ct],  0, 0, 0);
                aU[ct]  = __builtin_amdgcn_mfma_f32_16x16x32_bf16(ah[kk],   wfl[kk][ct],   aU[ct],  0, 0, 0);
                aU[ct]  = __builtin_amdgcn_mfma_f32_16x16x32_bf16(ah[kk],   wfh[kk][ct],   aU[ct],  0, 0, 0);
                aV[ct]  = __builtin_amdgcn_mfma_f32_16x16x32_bf16(al[kk+2], wfh[kk+2][ct], aV[ct],  0, 0, 0);
                aV[ct]  = __builtin_amdgcn_mfma_f32_16x16x32_bf16(ah[kk+2], wfl[kk+2][ct], aV[ct],  0, 0, 0);
                aV[ct]  = __builtin_amdgcn_mfma_f32_16x16x32_bf16(ah[kk+2], wfh[kk+2][ct], aV[ct],  0, 0, 0);
                aU2[ct] = __builtin_amdgcn_mfma_f32_16x16x32_bf16(al[kk+2], wfh[kk][ct],   aU2[ct], 0, 0, 0);
                aU2[ct] = __builtin_amdgcn_mfma_f32_16x16x32_bf16(ah[kk+2], wfl[kk][ct],   aU2[ct], 0, 0, 0);
                aU2[ct] = __builtin_amdgcn_mfma_f32_16x16x32_bf16(ah[kk+2], wfh[kk][ct],   aU2[ct], 0, 0, 0);
            }
        }

        // fused stage-1 stats (per-row weights from degrees)
#pragma unroll
        for (int i = 0; i < 4; i++) {
            int r2 = (tile << 4) + quad * 4 + i;
            double wod = 1.0 + od[r2], wgt = 1.0 + id[r2];
#pragma unroll
            for (int ct = 0; ct < 4; ct++) {
                double uu = aU[ct][i], vv = aV[ct][i], u2v = aU2[ct][i];
                ssum[ct] += wod * uu + wgt * vv;
                ssq[ct]  += wod * uu * uu + wgt * vv * vv + 2.0 * vv * u2v;
            }
        }

        epi_tile_b16(wl, lane, aU, ub, tile);
        epi_tile<false, false>(wl, lane, aV, zb, v, tile, nullptr, nullptr);
    }

    stats_block_out(&lds[0][0], lane, wid_, ssum, ssq, part);
}

__global__ void k_fin1(const double* __restrict__ raw, const float* __restrict__ b,
                       float* __restrict__ fin, double inv_cnt) {
    int c = threadIdx.x;
    double m1 = raw[c] * inv_cnt;
    double var = raw[64 + c] * inv_cnt - m1 * m1;
    if (var < 0.0) var = 0.0;
    fin[c] = (float)(m1 + (double)b[c]);
    fin[64 + c] = (float)(1.0 / sqrt(var + 1e-5));
}

__global__ void k_fin(const double* __restrict__ raw, float* __restrict__ fin, double inv_cnt) {
    int c = threadIdx.x;
    double mean = raw[c] * inv_cnt;
    double var = raw[64 + c] * inv_cnt - mean * mean;
    if (var < 0.0) var = 0.0;
    fin[c] = (float)mean;
    fin[64 + c] = (float)(1.0 / sqrt(var + 1e-5));
}

// ---------- stage-1 reduce + per-row h store in BF16 (bf16 u gather) ----------
__global__ void k_s1h(const unsigned short* __restrict__ ub, const float* __restrict__ v,
                      const int* __restrict__ off, const unsigned int* __restrict__ sd_s,
                      const float* __restrict__ b_un, const float* __restrict__ fin,
                      const float* __restrict__ g1, const float* __restrict__ be1,
                      unsigned short* __restrict__ stb, unsigned short* __restrict__ hb) {
    int team = (blockIdx.x * 256 + threadIdx.x) >> 6;
    int c = threadIdx.x & 63;
    float sc = fin[64 + c] * g1[c];
    float tsh = (b_un[c] - fin[c]) * sc + be1[c];
    float vn = v[(size_t)team * 64 + c];
    float a[16];
#pragma unroll
    for (int j = 0; j < 16; j++) a[j] = 0.f;
    float hs = fmaxf((bf2f(ub[(size_t)team * 64 + c]) + vn) * sc + tsh, 0.f);   // self row
    a[0] = hs;
    hb[(size_t)team * 64 + c] = f2bf(hs);
    int e = off[team], e1 = off[team + 1];
    for (; e + 15 < e1; e += 16)
#pragma unroll
        for (int j = 0; j < 16; j++) {
            float h = fmaxf((bf2f(ub[(size_t)(sd_s[e + j] & 0xFFFFu) * 64 + c]) + vn) * sc + tsh, 0.f);
            a[j] += h;
            hb[(size_t)(NN + e + j) * 64 + c] = f2bf(h);
        }
    for (; e + 3 < e1; e += 4)
#pragma unroll
        for (int j = 0; j < 4; j++) {
            float h = fmaxf((bf2f(ub[(size_t)(sd_s[e + j] & 0xFFFFu) * 64 + c]) + vn) * sc + tsh, 0.f);
            a[j] += h;
            hb[(size_t)(NN + e + j) * 64 + c] = f2bf(h);
        }
    for (; e < e1; e++) {
        float h = fmaxf((bf2f(ub[(size_t)(sd_s[e] & 0xFFFFu) * 64 + c]) + vn) * sc + tsh, 0.f);
        a[0] += h;
        hb[(size_t)(NN + e) * 64 + c] = f2bf(h);
    }
#pragma unroll
    for (int j = 0; j < 8; j++) a[j] += a[j + 8];
#pragma unroll
    for (int j = 0; j < 4; j++) a[j] += a[j + 4];
    stb[(size_t)team * 64 + c] = f2bf((a[0] + a[1]) + (a[2] + a[3]));
}

// ---------- msg[n] = sum_{e:dst=n} stb[src_e]  (bf16 gather table) ----------
__global__ void k_msg_csr(const int* __restrict__ off, const unsigned int* __restrict__ sd_s,
                          const unsigned short* __restrict__ stb, float* __restrict__ msg) {
    int team = (blockIdx.x * 256 + threadIdx.x) >> 6;
    int c = threadIdx.x & 63;
    float a[16];
#pragma unroll
    for (int j = 0; j < 16; j++) a[j] = 0.f;
    int e = off[team], e1 = off[team + 1];
    for (; e + 15 < e1; e += 16)
#pragma unroll
        for (int j = 0; j < 16; j++) a[j] += bf2f(stb[(size_t)(sd_s[e + j] & 0xFFFFu) * 64 + c]);
    for (; e + 3 < e1; e += 4)
#pragma unroll
        for (int j = 0; j < 4; j++) a[j] += bf2f(stb[(size_t)(sd_s[e + j] & 0xFFFFu) * 64 + c]);
    for (; e < e1; e++) a[0] += bf2f(stb[(size_t)(sd_s[e] & 0xFFFFu) * 64 + c]);
#pragma unroll
    for (int j = 0; j < 8; j++) a[j] += a[j + 8];
#pragma unroll
    for (int j = 0; j < 4; j++) a[j] += a[j + 4];
    msg[(size_t)team * 64 + c] = (a[0] + a[1]) + (a[2] + a[3]);
}

// ---------- mb = msg @ W_gc[64:128]  (streaming; in/out may differ) ----------
__global__ void k_mb(const float* __restrict__ in, float* __restrict__ outp,
                     const float* __restrict__ W) {
    __shared__ float lds[4][16 * 68];
    const int lane = threadIdx.x & 63;
    const int wid = threadIdx.x >> 6;
    const int m = lane & 15, quad = lane >> 4;
    const int gwave = (blockIdx.x * blockDim.x + threadIdx.x) >> 6;
    const int nwaves = (gridDim.x * blockDim.x) >> 6;
    float* wl = lds[wid];

    bf16x8 wfh[2][4], wfl[2][4];
#pragma unroll
    for (int kk = 0; kk < 2; kk++)
#pragma unroll
        for (int ct = 0; ct < 4; ct++) {
            float wv[8];
#pragma unroll
            for (int j = 0; j < 8; j++)
                wv[j] = W[(kk * 32 + quad * 8 + j) * 64 + ct * 16 + m];
            split8r(wv, wfh[kk][ct], wfl[kk][ct]);
        }
    float zb[4] = {0.f, 0.f, 0.f, 0.f};

    for (int tile = gwave; tile < NT_N; tile += nwaves) {
        const int r = (tile << 4) + m;
        bf16x8 ah[2], al[2];
        split8(in + (size_t)r * 64 + quad * 8,      ah[0], al[0]);
        split8(in + (size_t)r * 64 + 32 + quad * 8, ah[1], al[1]);

        f32x4 zero = {0.f, 0.f, 0.f, 0.f};
        f32x4 acc[4];
#pragma unroll
        for (int ct = 0; ct < 4; ct++) {
            acc[ct] = zero;
#pragma unroll
            for (int kk = 0; kk < 2; kk++) {
                acc[ct] = __builtin_amdgcn_mfma_f32_16x16x32_bf16(al[kk], wfh[kk][ct], acc[ct], 0, 0, 0);
                acc[ct] = __builtin_amdgcn_mfma_f32_16x16x32_bf16(ah[kk], wfl[kk][ct], acc[ct], 0, 0, 0);
                acc[ct] = __builtin_amdgcn_mfma_f32_16x16x32_bf16(ah[kk], wfh[kk][ct], acc[ct], 0, 0, 0);
            }
        }
        epi_tile<false, false>(wl, lane, acc, zb, outp, tile, nullptr, nullptr);
    }
}

// ---------- stage-2 streaming matmul over bf16 h rows:
// h2b[r] = bf16( hb[r]@Wtop2 + mb[dst(r)] + b_gc ); stats via block partials (no atomics).
__global__ void k_h2(const unsigned short* __restrict__ hb, unsigned short* __restrict__ h2b,
                     const float* __restrict__ mb, const unsigned int* __restrict__ sd_s,
                     const float* __restrict__ W, const float* __restrict__ b_gc,
                     double* __restrict__ part) {
    __shared__ float lds[4][16 * 68];
    const int lane = threadIdx.x & 63;
    const int wid = threadIdx.x >> 6;
    const int m = lane & 15, quad = lane >> 4;
    const int gwave = (blockIdx.x * blockDim.x + threadIdx.x) >> 6;
    const int nwaves = (gridDim.x * blockDim.x) >> 6;
    float* wl = lds[wid];

    bf16x8 wfh[2][4], wfl[2][4];
#pragma unroll
    for (int kk = 0; kk < 2; kk++)
#pragma unroll
        for (int ct = 0; ct < 4; ct++) {
            float wv[8];
#pragma unroll
            for (int j = 0; j < 8; j++)
                wv[j] = W[(kk * 32 + quad * 8 + j) * 64 + ct * 16 + m];
            split8r(wv, wfh[kk][ct], wfl[kk][ct]);
        }

    float bv[4];
#pragma unroll
    for (int ct = 0; ct < 4; ct++) bv[ct] = b_gc[ct * 16 + m];

    double ssum[4] = {0,0,0,0}, ssq[4] = {0,0,0,0};

    for (int tile = gwave; tile < NT_R; tile += nwaves) {
        const int r = (tile << 4) + m;
        int dm = (tile < NT_N) ? r : (int)(sd_s[r - NN] >> 16);

        bf16x8 ah[2];
        ah[0] = *reinterpret_cast<const bf16x8*>(hb + (size_t)r * 64 + quad * 8);
        ah[1] = *reinterpret_cast<const bf16x8*>(hb + (size_t)r * 64 + 32 + quad * 8);

        f32x4 zero = {0.f, 0.f, 0.f, 0.f};
        f32x4 acc[4];
#pragma unroll
        for (int ct = 0; ct < 4; ct++) {
            acc[ct] = zero;
#pragma unroll
            for (int kk = 0; kk < 2; kk++) {
                acc[ct] = __builtin_amdgcn_mfma_f32_16x16x32_bf16(ah[kk], wfl[kk][ct], acc[ct], 0, 0, 0);
                acc[ct] = __builtin_amdgcn_mfma_f32_16x16x32_bf16(ah[kk], wfh[kk][ct], acc[ct], 0, 0, 0);
            }
        }

        // add mb[dst_of_row] + b_gc per element, then stats + LDS-coalesced bf16 store
#pragma unroll
        for (int i = 0; i < 4; i++) {
            int dmv = __shfl(dm, (lane & 48) + quad * 4 + i, 64);   // dm of row quad*4+i
#pragma unroll
            for (int ct = 0; ct < 4; ct++) {
                float val = acc[ct][i] + bv[ct] + mb[(size_t)dmv * 64 + ct * 16 + m];
                wl[(quad * 4 + i) * 68 + ct * 16 + m] = val;
                ssum[ct] += (double)val;
                ssq[ct]  += (double)val * (double)val;
            }
        }
        asm volatile("s_waitcnt lgkmcnt(0)" ::: "memory");
#pragma unroll
        for (int j = 0; j < 4; j++) {
            int row = j * 4 + quad;
            f32x4 vv = *reinterpret_cast<const f32x4*>(wl + row * 68 + m * 4);
            unsigned int p0 = (unsigned int)f2bf(vv[0]) | ((unsigned int)f2bf(vv[1]) << 16);
            unsigned int p1 = (unsigned int)f2bf(vv[2]) | ((unsigned int)f2bf(vv[3]) << 16);
            uint2 pk; pk.x = p0; pk.y = p1;
            *reinterpret_cast<uint2*>(h2b + ((size_t)(tile << 4) + row) * 64 + m * 4) = pk;
        }
    }

    stats_block_out(&lds[0][0], lane, wid, ssum, ssq, part);
}

// ---------- agg(bf16)[n] = relu(bn2(h2b[n])) + sum_{q} relu(bn2(h2b[NN+perm_s[q]])) ----------
__global__ void k_agg_csr(const unsigned short* __restrict__ h2b, const int* __restrict__ off_s,
                          const int* __restrict__ perm_s, const float* __restrict__ fin2,
                          const float* __restrict__ g2, const float* __restrict__ be2,
                          unsigned short* __restrict__ aggb) {
    int n = (blockIdx.x * 256 + threadIdx.x) >> 6;
    int c = threadIdx.x & 63;
    float sc = fin2[64 + c] * g2[c];
    float sh = be2[c] - fin2[c] * sc;
    float a[16];
#pragma unroll
    for (int j = 0; j < 16; j++) a[j] = 0.f;
    a[0] = fmaxf(bf2f(h2b[(size_t)n * 64 + c]) * sc + sh, 0.f);   // self row
    int q = off_s[n], q1 = off_s[n + 1];
    for (; q + 15 < q1; q += 16)
#pragma unroll
        for (int j = 0; j < 16; j++) {
            float hv = bf2f(h2b[(size_t)(NN + perm_s[q + j]) * 64 + c]);
            a[j] += fmaxf(hv * sc + sh, 0.f);
        }
    for (; q + 3 < q1; q += 4)
#pragma unroll
        for (int j = 0; j < 4; j++) {
            float hv = bf2f(h2b[(size_t)(NN + perm_s[q + j]) * 64 + c]);
            a[j] += fmaxf(hv * sc + sh, 0.f);
        }
    for (; q < q1; q++) {
        float hv = bf2f(h2b[(size_t)(NN + perm_s[q]) * 64 + c]);
        a[0] += fmaxf(hv * sc + sh, 0.f);
    }
#pragma unroll
    for (int j = 0; j < 8; j++) a[j] += a[j + 8];
#pragma unroll
    for (int j = 0; j < 4; j++) a[j] += a[j + 4];
    aggb[(size_t)n * 64 + c] = f2bf((a[0] + a[1]) + (a[2] + a[3]));
}

// ---------- stage 3: t_pre = [relu(bn2(h2b[:N])), agg(bf16)] @ W_tr + b_tr, stats3 ----------
__global__ void k_mm3(const unsigned short* __restrict__ h2b, const unsigned short* __restrict__ aggb,
                      const float* __restrict__ W, const float* __restrict__ bias,
                      const float* __restrict__ fin2, const float* __restrict__ g2,
                      const float* __restrict__ be2,
                      float* __restrict__ outp, double* __restrict__ part) {
    __shared__ float lds[4][16 * 68];
    const int lane = threadIdx.x & 63;
    const int wid = threadIdx.x >> 6;
    const int m = lane & 15, quad = lane >> 4;
    const int gwave = (blockIdx.x * blockDim.x + threadIdx.x) >> 6;
    const int nwaves = (gridDim.x * blockDim.x) >> 6;
    float* wl = lds[wid];

    bf16x8 wfh[4][4], wfl[4][4];
#pragma unroll
    for (int kk = 0; kk < 4; kk++)
#pragma unroll
        for (int ct = 0; ct < 4; ct++) {
            float wv[8];
#pragma unroll
            for (int j = 0; j < 8; j++)
                wv[j] = W[(kk * 32 + quad * 8 + j) * 64 + ct * 16 + m];
            split8r(wv, wfh[kk][ct], wfl[kk][ct]);
        }

    float bv[4];
#pragma unroll
    for (int ct = 0; ct < 4; ct++) bv[ct] = bias[ct * 16 + m];

    float s2f[2][8], t2f[2][8];
#pragma unroll
    for (int kk = 0; kk < 2; kk++)
#pragma unroll
        for (int j = 0; j < 8; j++) {
            int c = kk * 32 + quad * 8 + j;
            float sc = fin2[64 + c] * g2[c];
            s2f[kk][j] = sc;
            t2f[kk][j] = be2[c] - fin2[c] * sc;
        }

    double ssum[4] = {0,0,0,0}, ssq[4] = {0,0,0,0};

    for (int tile = gwave; tile < NT_N; tile += nwaves) {
        const int r = (tile << 4) + m;
        bf16x8 ah[4], al[2];
#pragma unroll
        for (int kk = 0; kk < 2; kk++) {
            bf16x8 hv = *reinterpret_cast<const bf16x8*>(h2b + (size_t)r * 64 + kk * 32 + quad * 8);
            float tv[8];
#pragma unroll
            for (int j = 0; j < 8; j++) {
                float f = bf2f((unsigned short)hv[j]);
                tv[j] = fmaxf(f * s2f[kk][j] + t2f[kk][j], 0.f);
            }
            split8r(tv, ah[kk], al[kk]);
        }
        // agg rows are bf16 already: direct A-fragments, no lo term
        ah[2] = *reinterpret_cast<const bf16x8*>(aggb + (size_t)r * 64 + quad * 8);
        ah[3] = *reinterpret_cast<const bf16x8*>(aggb + (size_t)r * 64 + 32 + quad * 8);

        f32x4 zero = {0.f, 0.f, 0.f, 0.f};
        f32x4 acc[4];
#pragma unroll
        for (int ct = 0; ct < 4; ct++) {
            acc[ct] = zero;
#pragma unroll
            for (int kk = 0; kk < 2; kk++)
                acc[ct] = __builtin_amdgcn_mfma_f32_16x16x32_bf16(al[kk], wfh[kk][ct], acc[ct], 0, 0, 0);
#pragma unroll
            for (int kk = 0; kk < 4; kk++)
                acc[ct] = __builtin_amdgcn_mfma_f32_16x16x32_bf16(ah[kk], wfl[kk][ct], acc[ct], 0, 0, 0);
#pragma unroll
            for (int kk = 0; kk < 4; kk++)
                acc[ct] = __builtin_amdgcn_mfma_f32_16x16x32_bf16(ah[kk], wfh[kk][ct], acc[ct], 0, 0, 0);
        }

        epi_tile<false, true>(wl, lane, acc, bv, outp, tile, ssum, ssq);
    }

    stats_block_out(&lds[0][0], lane, wid, ssum, ssq, part);
}

// ---------- stage 4 ----------
__global__ void k_mm4(const float* __restrict__ tpre, const float* __restrict__ W,
                      const float* __restrict__ bias, const float* __restrict__ fin3,
                      const float* __restrict__ g2, const float* __restrict__ be2,
                      float* __restrict__ outp, double* __restrict__ part) {
    __shared__ float lds[4][16 * 68];
    const int lane = threadIdx.x & 63;
    const int wid = threadIdx.x >> 6;
    const int m = lane & 15, quad = lane >> 4;
    const int gwave = (blockIdx.x * blockDim.x + threadIdx.x) >> 6;
    const int nwaves = (gridDim.x * blockDim.x) >> 6;
    float* wl = lds[wid];

    bf16x8 wfh[2][4], wfl[2][4];
#pragma unroll
    for (int kk = 0; kk < 2; kk++)
#pragma unroll
        for (int ct = 0; ct < 4; ct++) {
            float wv[8];
#pragma unroll
            for (int j = 0; j < 8; j++)
                wv[j] = W[(kk * 32 + quad * 8 + j) * 64 + ct * 16 + m];
            split8r(wv, wfh[kk][ct], wfl[kk][ct]);
        }

    float bv[4];
#pragma unroll
    for (int ct = 0; ct < 4; ct++) bv[ct] = bias[ct * 16 + m];

    float sc[2][8], sh[2][8];
#pragma unroll
    for (int kk = 0; kk < 2; kk++)
#pragma unroll
        for (int j = 0; j < 8; j++) {
            int c = kk * 32 + quad * 8 + j;
            float s = fin3[64 + c] * g2[c];
            sc[kk][j] = s;
            sh[kk][j] = be2[c] - fin3[c] * s;
        }

    double ssum[4] = {0,0,0,0}, ssq[4] = {0,0,0,0};

    for (int tile = gwave; tile < NT_N; tile += nwaves) {
        const int r = (tile << 4) + m;
        bf16x8 ah[2], al[2];
#pragma unroll
        for (int kk = 0; kk < 2; kk++) {
            f32x4 v0 = *reinterpret_cast<const f32x4*>(tpre + (size_t)r * 64 + kk * 32 + quad * 8);
            f32x4 v1 = *reinterpret_cast<const f32x4*>(tpre + (size_t)r * 64 + kk * 32 + quad * 8 + 4);
            float tv[8];
#pragma unroll
            for (int j = 0; j < 4; j++) {
                tv[j]     = fmaxf(v0[j] * sc[kk][j]     + sh[kk][j],     0.f);
                tv[4 + j] = fmaxf(v1[j] * sc[kk][4 + j] + sh[kk][4 + j], 0.f);
            }
            split8r(tv, ah[kk], al[kk]);
        }

        f32x4 zero = {0.f, 0.f, 0.f, 0.f};
        f32x4 acc[4];
#pragma unroll
        for (int ct = 0; ct < 4; ct++) {
            acc[ct] = zero;
#pragma unroll
            for (int kk = 0; kk < 2; kk++) {
                acc[ct] = __builtin_amdgcn_mfma_f32_16x16x32_bf16(al[kk], wfh[kk][ct], acc[ct], 0, 0, 0);
                acc[ct] = __builtin_amdgcn_mfma_f32_16x16x32_bf16(ah[kk], wfl[kk][ct], acc[ct], 0, 0, 0);
                acc[ct] = __builtin_amdgcn_mfma_f32_16x16x32_bf16(ah[kk], wfh[kk][ct], acc[ct], 0, 0, 0);
            }
        }

        epi_tile<true, true>(wl, lane, acc, bv, outp, tile, ssum, ssq);
    }

    stats_block_out(&lds[0][0], lane, wid, ssum, ssq, part);
}

// out = relu(bn(out_pre; stats4, g3, be3)) -> f32
__global__ void k_out(const float* __restrict__ op, const float* __restrict__ fin,
                      const float* __restrict__ g, const float* __restrict__ be,
                      float* __restrict__ out) {
    int i = blockIdx.x * 256 + threadIdx.x;   // covers NN*64 exactly
    int c = i & 63;
    out[i] = fmaxf((op[i] - fin[c]) * fin[64 + c] * g[c] + be[c], 0.f);
}

extern "C" void kernel_launch(void* const* d_in, const int* in_sizes, int n_in,
                              void* d_out, int out_size, void* d_ws, size_t ws_size,
                              hipStream_t stream) {
    const float* x    = (const float*)d_in[0];
    const int*   ei   = (const int*)d_in[1];
    const float* W_un = (const float*)d_in[2];
    const float* b_un = (const float*)d_in[3];
    const float* g1   = (const float*)d_in[4];
    const float* be1  = (const float*)d_in[5];
    const float* W_gc = (const float*)d_in[6];
    const float* b_gc = (const float*)d_in[7];
    const float* g2   = (const float*)d_in[8];
    const float* be2  = (const float*)d_in[9];
    const float* W_tr = (const float*)d_in[10];
    const float* b_tr = (const float*)d_in[11];
    const float* W_li = (const float*)d_in[12];
    const float* b_li = (const float*)d_in[13];
    const float* g3   = (const float*)d_in[14];
    const float* be3  = (const float*)d_in[15];

    float* ws = (float*)d_ws;
    const size_t FN = (size_t)NN * 64;           // 3.2M floats (12.8 MB)
    const size_t FR = (size_t)RR * 64;           // 54.4M floats (217.6 MB)
    // Region plan (zero growth; lifetimes verified):
    //  P0: ub (bf16) -> msg/mb -> part_mm3 -> outpre
    //  P1: v -> aggb (bf16, after v dead) -> part_mm4 (aggb dead after k_mm3)
    //  P2: csum -> part_uv (512KB, after scans) -> stb (bf16, after k_red) -> part_h2 -> tpre
    //  H: dsum [0,FN), xb16 [FN,1.5FN) — dead after k_uv3/k_dsum
    //      -> hb (FR ushorts) + h2b (FR ushorts)
    float* P0 = ws;
    float* P1 = ws + FN;
    float* P2 = ws + 2 * FN;
    float* H  = ws + 3 * FN;
    unsigned short* ub   = (unsigned short*)P0;      // bf16 u table (gathered by k_s1h)
    float* v      = P1;
    unsigned short* stb  = (unsigned short*)P2;      // bf16 s_tab (gathered by k_msg)
    int*   csum   = (int*)P2;     // 196 ints, scan scratch
    double* part_uv = (double*)P2;   // 512*128*8B = 512KB (csum dead, before stb)
    float* dsum   = H;
    unsigned short* xb16 = (unsigned short*)(H + FN);   // bf16 x copy (k_dsum gather)
    unsigned short* hb  = (unsigned short*)H;        // bf16 h rows
    unsigned short* h2b = (unsigned short*)H + FR;   // bf16 h2pre rows
    float* msg    = P0;           // becomes mb after k_mb (in place; ub dead)
    unsigned short* aggb = (unsigned short*)P1;      // bf16 agg (v dead)
    float* tpre   = P2;
    float* outpre = P0;
    double* part_h2 = (double*)P2;   // 2MB (stb dead, before tpre)
    double* part_m3 = (double*)P0;   // 512KB (mb dead, before outpre)
    double* part_m4 = (double*)P1;   // 512KB (aggb dead)
    double*       stats_raw = (double*)(H + FR);
    int*          od        = (int*)(stats_raw + 512);
    int*          id        = od + NN;
    int*          off       = id + NN;
    int*          cursor    = off + NN + 1;
    int*          off_s     = cursor + NN;
    int*          cursor_s  = off_s + NN + 1;
    unsigned int* sd_s      = (unsigned int*)(cursor_s + NN);   // packed src|dst<<16, dst-sorted
    int*          perm_s    = (int*)(sd_s + EE);
    float*        stats_fin = (float*)(perm_s + EE);

    // zero: stats_raw + od + id (contiguous)
    hipMemsetAsync(stats_raw, 0, 512 * sizeof(double) + 2 * NN * sizeof(int), stream);

    // build dst-sorted packed edge list + src-CSR permutation (coalesced 3-phase scan)
    k_degx <<<12500, 256, 0, stream>>>(ei, od, id, x, xb16);
    k_scanA<<<2 * NCH, 256, 0, stream>>>(id, od, csum);
    k_scanB<<<1, 256, 0, stream>>>(csum);
    k_scanC<<<2 * NCH, 256, 0, stream>>>(id, od, csum, off, cursor, off_s, cursor_s);
    k_fill <<<3125, 256, 0, stream>>>(ei, cursor, sd_s);
    k_fill2<<<3125, 256, 0, stream>>>(sd_s, cursor_s, perm_s);

    // stage 0 + per-node tables (stage-1 stats fused into k_uv3; u2 never materialized)
    k_dsum_csr<<<12500, 256, 0, stream>>>(x, xb16, off, sd_s, dsum);
    k_uv3<<<NBLK_MM, 256, 0, stream>>>(x, dsum, W_un, od, id, ub, v, part_uv);
    k_red<<<16, 128, 0, stream>>>(part_uv, NBLK_MM, stats_raw + 0);
    k_fin1<<<1, 64, 0, stream>>>(stats_raw + 0, b_un, stats_fin + 0, 1.0 / (double)RR);

    // stage-1 CSR reduce + per-row bf16 h store
    k_s1h<<<12500, 256, 0, stream>>>(ub, v, off, sd_s, b_un, stats_fin + 0, g1, be1,
                                     stb, hb);
    k_msg_csr<<<12500, 256, 0, stream>>>(off, sd_s, stb, msg);
    k_mb<<<512, 256, 0, stream>>>(msg, msg, W_gc + 64 * 64);   // msg -> mb in place

    // stage-2: streaming matmul over bf16 h rows -> bf16 h2 rows, block-partial stats
    k_h2<<<NBLK_H2, 256, 0, stream>>>(hb, h2b, msg, sd_s, W_gc, b_gc, part_h2);
    k_red<<<32, 128, 0, stream>>>(part_h2, NBLK_H2, stats_raw + 128);
    k_fin<<<1, 64, 0, stream>>>(stats_raw + 128, stats_fin + 128, 1.0 / (double)RR);
    k_agg_csr<<<12500, 256, 0, stream>>>(h2b, off_s, perm_s, stats_fin + 128, g2, be2, aggb);

    // stage 3
    k_mm3<<<NBLK_MM, 256, 0, stream>>>(h2b, aggb, W_tr, b_tr, stats_fin + 128, g2, be2,
                                       tpre, part_m3);
    k_red<<<16, 128, 0, stream>>>(part_m3, NBLK_MM, stats_raw + 256);
    k_fin<<<1, 64, 0, stream>>>(stats_raw + 256, stats_fin + 256, 1.0 / (double)NN);

    // stage 4
    k_mm4<<<NBLK_MM, 256, 0, stream>>>(tpre, W_li, b_li, stats_fin + 256, g2, be2,
                                       outpre, part_m4);
    k_red<<<16, 128, 0, stream>>>(part_m4, NBLK_MM, stats_raw + 384);
    k_fin<<<1, 64, 0, stream>>>(stats_raw + 384, stats_fin + 384, 1.0 / (double)NN);

    k_out<<<12500, 256, 0, stream>>>(outpre, stats_fin + 384, g3, be3, (float*)d_out);
}

// Round 11
// 666.238 us; speedup vs baseline: 2.7917x; 1.0342x over previous
//
#include <hip/hip_runtime.h>
#include <cstdint>
#include <math.h>

// Problem sizes (fixed by the reference).
#define NN 50000
#define EE 800000
#define RR 850000      // NN + EE rows
#define NT_N 3125      // NN/16
#define NT_R 53125     // RR/16
#define NBLK_H2 2048
#define NBLK_MM 512
#define CHUNK 512
#define NCH 98         // ceil(NN/CHUNK)

typedef short  bf16x8 __attribute__((ext_vector_type(8)));
typedef float  f32x4  __attribute__((ext_vector_type(4)));

__device__ __forceinline__ float bf2f(unsigned short b) {
    unsigned int u = ((unsigned int)b) << 16;
    return __builtin_bit_cast(float, u);
}
__device__ __forceinline__ unsigned short f2bf(float f) {
    unsigned int u = __builtin_bit_cast(unsigned int, f);
    u = u + 0x7fffu + ((u >> 16) & 1u);
    return (unsigned short)(u >> 16);
}
__device__ __forceinline__ void atomAddD(double* p, double v) { unsafeAtomicAdd(p, v); }
__device__ __forceinline__ int atomAddI(int* p, int v) { return atomicAdd(p, v); }

// split 8 consecutive f32 into hi/lo bf16 fragments: hi+lo == v to ~2^-16 rel
__device__ __forceinline__ void split8(const float* p, bf16x8& hi, bf16x8& lo) {
    f32x4 v0 = *reinterpret_cast<const f32x4*>(p);
    f32x4 v1 = *reinterpret_cast<const f32x4*>(p + 4);
#pragma unroll
    for (int j = 0; j < 4; j++) {
        unsigned short h0 = f2bf(v0[j]);
        hi[j] = (short)h0; lo[j] = (short)f2bf(v0[j] - bf2f(h0));
        unsigned short h1 = f2bf(v1[j]);
        hi[4 + j] = (short)h1; lo[4 + j] = (short)f2bf(v1[j] - bf2f(h1));
    }
}
__device__ __forceinline__ void split8r(const float* v, bf16x8& hi, bf16x8& lo) {
#pragma unroll
    for (int j = 0; j < 8; j++) {
        unsigned short h = f2bf(v[j]);
        hi[j] = (short)h; lo[j] = (short)f2bf(v[j] - bf2f(h));
    }
}

// LDS-staged coalesced tile store: MFMA C-layout -> 4x 1KB contiguous dwordx4 stores.
template <bool RELU, bool STATS>
__device__ __forceinline__ void epi_tile(float* wl, int lane, const f32x4* acc,
                                         const float* bv, float* __restrict__ gout,
                                         int tile, double* ssum, double* ssq) {
    const int m = lane & 15, quad = lane >> 4;
#pragma unroll
    for (int ct = 0; ct < 4; ct++)
#pragma unroll
        for (int i = 0; i < 4; i++) {
            float val = acc[ct][i] + bv[ct];
            if (RELU) val = fmaxf(val, 0.f);
            wl[(quad * 4 + i) * 68 + ct * 16 + m] = val;
            if (STATS) { ssum[ct] += (double)val; ssq[ct] += (double)val * (double)val; }
        }
    asm volatile("s_waitcnt lgkmcnt(0)" ::: "memory");
#pragma unroll
    for (int j = 0; j < 4; j++) {
        int row = j * 4 + quad;
        f32x4 vv = *reinterpret_cast<const f32x4*>(wl + row * 68 + m * 4);
        *reinterpret_cast<f32x4*>(gout + ((size_t)(tile << 4) + row) * 64 + m * 4) = vv;
    }
}

// bf16 variant: stage f32 in LDS, pack to bf16, coalesced uint2 stores.
__device__ __forceinline__ void epi_tile_b16(float* wl, int lane, const f32x4* acc,
                                             unsigned short* __restrict__ gout, int tile) {
    const int m = lane & 15, quad = lane >> 4;
#pragma unroll
    for (int ct = 0; ct < 4; ct++)
#pragma unroll
        for (int i = 0; i < 4; i++)
            wl[(quad * 4 + i) * 68 + ct * 16 + m] = acc[ct][i];
    asm volatile("s_waitcnt lgkmcnt(0)" ::: "memory");
#pragma unroll
    for (int j = 0; j < 4; j++) {
        int row = j * 4 + quad;
        f32x4 vv = *reinterpret_cast<const f32x4*>(wl + row * 68 + m * 4);
        unsigned int p0 = (unsigned int)f2bf(vv[0]) | ((unsigned int)f2bf(vv[1]) << 16);
        unsigned int p1 = (unsigned int)f2bf(vv[2]) | ((unsigned int)f2bf(vv[3]) << 16);
        uint2 pk; pk.x = p0; pk.y = p1;
        *reinterpret_cast<uint2*>(gout + ((size_t)(tile << 4) + row) * 64 + m * 4) = pk;
    }
}

// block-level stats reduce: wave shfl-reduce -> LDS -> one coalesced 1KB store per block.
__device__ __forceinline__ void stats_block_out(float* ldsbase, int lane, int wid,
                                                const double* ssum, const double* ssq,
                                                double* __restrict__ part) {
    const int m = lane & 15, quad = lane >> 4;
    double* dl = (double*)ldsbase;
    __syncthreads();
#pragma unroll
    for (int ct = 0; ct < 4; ct++) {
        double sv = ssum[ct], qv = ssq[ct];
        sv += __shfl_xor(sv, 16, 64); sv += __shfl_xor(sv, 32, 64);
        qv += __shfl_xor(qv, 16, 64); qv += __shfl_xor(qv, 32, 64);
        if (quad == 0) {
            dl[wid * 128 + ct * 16 + m]      = sv;
            dl[wid * 128 + 64 + ct * 16 + m] = qv;
        }
    }
    __syncthreads();
    int tid = wid * 64 + lane;
    if (tid < 128) {
        double tot = dl[tid] + dl[128 + tid] + dl[256 + tid] + dl[384 + tid];
        part[(size_t)blockIdx.x * 128 + tid] = tot;
    }
}

// reduce block partials into raw[0..127] (few spread atomics only)
__global__ void k_red(const double* __restrict__ p, int nblk, double* __restrict__ raw) {
    int t = threadIdx.x;   // 128
    double acc = 0.0;
    for (int b = blockIdx.x; b < nblk; b += gridDim.x)
        acc += p[(size_t)b * 128 + t];
    atomAddD(&raw[t], acc);
}

// ---------- degree counts + x -> bf16 copy (fused) ----------
__global__ void k_degx(const int* __restrict__ ei, int* __restrict__ od, int* __restrict__ id,
                       const float* __restrict__ x, unsigned short* __restrict__ xb) {
    int i = blockIdx.x * 256 + threadIdx.x;   // 12500 blocks -> covers NN*64
    xb[i] = f2bf(x[i]);
    if (i < EE) {
        atomAddI(&od[ei[i]], 1);
        atomAddI(&id[ei[EE + i]], 1);
    }
}

// ---------- coalesced 3-phase dual scan ----------
__global__ void k_scanA(const int* __restrict__ id, const int* __restrict__ od,
                        int* __restrict__ csum) {
    int arr = blockIdx.x / NCH;
    int ch  = blockIdx.x % NCH;
    const int* cnt = arr ? od : id;
    int t = threadIdx.x;
    int i0 = ch * CHUNK + t;
    int s = 0;
    if (i0 < NN) s += cnt[i0];
    if (i0 + 256 < NN && (t + 256) < CHUNK) s += cnt[i0 + 256];
#pragma unroll
    for (int d = 1; d < 64; d <<= 1) s += __shfl_xor(s, d, 64);
    __shared__ int ws[4];
    if ((t & 63) == 0) ws[t >> 6] = s;
    __syncthreads();
    if (t == 0) csum[arr * NCH + ch] = ws[0] + ws[1] + ws[2] + ws[3];
}

__global__ void k_scanB(int* __restrict__ csum) {
    __shared__ int part[256];
    int t = threadIdx.x;
    int arr = t >> 7, slot = t & 127;
    int v = (slot < NCH) ? csum[arr * NCH + slot] : 0;
    part[t] = v;
    __syncthreads();
#pragma unroll
    for (int d = 1; d < 128; d <<= 1) {
        int val = (slot >= d) ? part[t - d] : 0;
        __syncthreads();
        part[t] += val;
        __syncthreads();
    }
    if (slot < NCH)
        csum[arr * NCH + slot] = (slot == 0) ? 0 : part[t - 1];
}

__global__ void k_scanC(const int* __restrict__ id, const int* __restrict__ od,
                        const int* __restrict__ csum,
                        int* __restrict__ off, int* __restrict__ cursor,
                        int* __restrict__ off_s, int* __restrict__ cursor_s) {
    int arr = blockIdx.x / NCH;
    int ch  = blockIdx.x % NCH;
    const int* cnt = arr ? od : id;
    int* o  = arr ? off_s : off;
    int* cu = arr ? cursor_s : cursor;
    int t = threadIdx.x;                 // 256 threads x 2 contiguous elems
    int idx = ch * CHUNK + 2 * t;
    int e0 = 0, e1 = 0;
    if (idx < NN)     e0 = cnt[idx];
    if (idx + 1 < NN) e1 = cnt[idx + 1];
    int p = e0 + e1;
    int lane = t & 63;
    int incl = p;
#pragma unroll
    for (int d = 1; d < 64; d <<= 1) {
        int v = __shfl_up(incl, d, 64);
        if (lane >= d) incl += v;
    }
    __shared__ int wsum[4];
    if (lane == 63) wsum[t >> 6] = incl;
    __syncthreads();
    int w = t >> 6;
    int wbase = 0;
#pragma unroll
    for (int i = 0; i < 4; i++) if (i < w) wbase += wsum[i];
    int base = csum[arr * NCH + ch] + wbase + (incl - p);   // exclusive prefix of e0
    if (idx < NN)     { o[idx]     = base;      cu[idx]     = base; }
    if (idx + 1 < NN) { o[idx + 1] = base + e0; cu[idx + 1] = base + e0; }
    if (blockIdx.x == 0 && t == 0) { off[NN] = EE; off_s[NN] = EE; }
}

// ---------- fill dst-sorted packed edge array: sd = src | (dst<<16) ----------
__global__ void k_fill(const int* __restrict__ ei, int* __restrict__ cursor,
                       unsigned int* __restrict__ sd_s) {
    int e = blockIdx.x * 256 + threadIdx.x;   // covers EE exactly
    int s = ei[e], d = ei[EE + e];
    int p = atomAddI(&cursor[d], 1);
    sd_s[p] = (unsigned int)s | ((unsigned int)d << 16);
}

// ---------- fill src-CSR permutation: perm_s[q] = dst-order position p ----------
__global__ void k_fill2(const unsigned int* __restrict__ sd_s, int* __restrict__ cursor_s,
                        int* __restrict__ perm_s) {
    int p = blockIdx.x * 256 + threadIdx.x;   // covers EE exactly
    int s = (int)(sd_s[p] & 0xFFFFu);
    int q = atomAddI(&cursor_s[s], 1);
    perm_s[q] = p;
}

// ---------- dsum[n] = x[n] + sum_{e: dst=n} xb[src_e]  (bf16 gather table) ----------
__global__ void k_dsum_csr(const float* __restrict__ x, const unsigned short* __restrict__ xb,
                           const int* __restrict__ off,
                           const unsigned int* __restrict__ sd_s, float* __restrict__ dsum) {
    int team = (blockIdx.x * 256 + threadIdx.x) >> 6;   // 12500 blocks x 4 = NN
    int c = threadIdx.x & 63;
    float a[16];
#pragma unroll
    for (int j = 0; j < 16; j++) a[j] = 0.f;
    a[0] = x[(size_t)team * 64 + c];
    int e = off[team], e1 = off[team + 1];
    for (; e + 15 < e1; e += 16)
#pragma unroll
        for (int j = 0; j < 16; j++) a[j] += bf2f(xb[(size_t)(sd_s[e + j] & 0xFFFFu) * 64 + c]);
    for (; e + 3 < e1; e += 4)
#pragma unroll
        for (int j = 0; j < 4; j++) a[j] += bf2f(xb[(size_t)(sd_s[e + j] & 0xFFFFu) * 64 + c]);
    for (; e < e1; e++) a[0] += bf2f(xb[(size_t)(sd_s[e] & 0xFFFFu) * 64 + c]);
#pragma unroll
    for (int j = 0; j < 8; j++) a[j] += a[j + 8];
#pragma unroll
    for (int j = 0; j < 4; j++) a[j] += a[j + 4];
    dsum[(size_t)team * 64 + c] = (a[0] + a[1]) + (a[2] + a[3]);
}

// ---------- u(bf16) = x@W_top, v = dsum@W_bot, FUSED stage-1 stats (u2 never stored) ----------
__global__ void k_uv3(const float* __restrict__ x, const float* __restrict__ dsum,
                      const float* __restrict__ W,
                      const int* __restrict__ od, const int* __restrict__ id,
                      unsigned short* __restrict__ ub, float* __restrict__ v,
                      double* __restrict__ part) {
    __shared__ float lds[4][16 * 68];
    const int lane = threadIdx.x & 63;
    const int wid_ = threadIdx.x >> 6;
    const int m = lane & 15, quad = lane >> 4;
    const int gwave = (blockIdx.x * blockDim.x + threadIdx.x) >> 6;
    const int nwaves = (gridDim.x * blockDim.x) >> 6;
    float* wl = lds[wid_];

    bf16x8 wfh[4][4], wfl[4][4];
#pragma unroll
    for (int kk = 0; kk < 4; kk++)
#pragma unroll
        for (int ct = 0; ct < 4; ct++) {
            float wv[8];
#pragma unroll
            for (int j = 0; j < 8; j++)
                wv[j] = W[(kk * 32 + quad * 8 + j) * 64 + ct * 16 + m];
            split8r(wv, wfh[kk][ct], wfl[kk][ct]);
        }
    float zb[4] = {0.f, 0.f, 0.f, 0.f};
    double ssum[4] = {0,0,0,0}, ssq[4] = {0,0,0,0};

    for (int tile = gwave; tile < NT_N; tile += nwaves) {
        const int r = (tile << 4) + m;
        bf16x8 ah[4], al[4];
        split8(x    + (size_t)r * 64 + quad * 8,      ah[0], al[0]);
        split8(x    + (size_t)r * 64 + 32 + quad * 8, ah[1], al[1]);
        split8(dsum + (size_t)r * 64 + quad * 8,      ah[2], al[2]);
        split8(dsum + (size_t)r * 64 + 32 + quad * 8, ah[3], al[3]);

        f32x4 zero = {0.f, 0.f, 0.f, 0.f};
        f32x4 aU[4], aV[4], aU2[4];
#pragma unroll
        for (int ct = 0; ct < 4; ct++) {
            aU[ct] = zero; aV[ct] = zero; aU2[ct] = zero;
#pragma unroll
            for (int kk = 0; kk < 2; kk++) {
                aU[ct]  = __builtin_amdgcn_mfma_f32_16x16x32_bf16(al[kk],   wfh[kk][ct],   aU[ct],  0, 0, 0);
                aU[ct]  = __builtin_amdgcn_mfma_f32_16x16x32_bf16(ah[kk],   wfl[kk][ct],   aU[ct],  0, 0, 0);
                aU[ct]  = __builtin_amdgcn_mfma_f32_16x16x32_bf16(ah[kk],   wfh[kk][ct],   aU[ct],  0, 0, 0);
                aV[ct]  = __builtin_amdgcn_mfma_f32_16x16x32_bf16(al[kk+2], wfh[kk+2][ct], aV[ct],  0, 0, 0);
                aV[ct]  = __builtin_amdgcn_mfma_f32_16x16x32_bf16(ah[kk+2], wfl[kk+2][ct], aV[ct],  0, 0, 0);
                aV[ct]  = __builtin_amdgcn_mfma_f32_16x16x32_bf16(ah[kk+2], wfh[kk+2][ct], aV[ct],  0, 0, 0);
                aU2[ct] = __builtin_amdgcn_mfma_f32_16x16x32_bf16(al[kk+2], wfh[kk][ct],   aU2[ct], 0, 0, 0);
                aU2[ct] = __builtin_amdgcn_mfma_f32_16x16x32_bf16(ah[kk+2], wfl[kk][ct],   aU2[ct], 0, 0, 0);
                aU2[ct] = __builtin_amdgcn_mfma_f32_16x16x32_bf16(ah[kk+2], wfh[kk][ct],   aU2[ct], 0, 0, 0);
            }
        }

        // fused stage-1 stats (per-row weights from degrees)
#pragma unroll
        for (int i = 0; i < 4; i++) {
            int r2 = (tile << 4) + quad * 4 + i;
            double wod = 1.0 + od[r2], wgt = 1.0 + id[r2];
#pragma unroll
            for (int ct = 0; ct < 4; ct++) {
                double uu = aU[ct][i], vv = aV[ct][i], u2v = aU2[ct][i];
                ssum[ct] += wod * uu + wgt * vv;
                ssq[ct]  += wod * uu * uu + wgt * vv * vv + 2.0 * vv * u2v;
            }
        }

        epi_tile_b16(wl, lane, aU, ub, tile);
        epi_tile<false, false>(wl, lane, aV, zb, v, tile, nullptr, nullptr);
    }

    stats_block_out(&lds[0][0], lane, wid_, ssum, ssq, part);
}

__global__ void k_fin1(const double* __restrict__ raw, const float* __restrict__ b,
                       float* __restrict__ fin, double inv_cnt) {
    int c = threadIdx.x;
    double m1 = raw[c] * inv_cnt;
    double var = raw[64 + c] * inv_cnt - m1 * m1;
    if (var < 0.0) var = 0.0;
    fin[c] = (float)(m1 + (double)b[c]);
    fin[64 + c] = (float)(1.0 / sqrt(var + 1e-5));
}

__global__ void k_fin(const double* __restrict__ raw, float* __restrict__ fin, double inv_cnt) {
    int c = threadIdx.x;
    double mean = raw[c] * inv_cnt;
    double var = raw[64 + c] * inv_cnt - mean * mean;
    if (var < 0.0) var = 0.0;
    fin[c] = (float)mean;
    fin[64 + c] = (float)(1.0 / sqrt(var + 1e-5));
}

// ---------- stage-1 reduce + per-row h store in BF16 (bf16 u gather) ----------
__global__ void k_s1h(const unsigned short* __restrict__ ub, const float* __restrict__ v,
                      const int* __restrict__ off, const unsigned int* __restrict__ sd_s,
                      const float* __restrict__ b_un, const float* __restrict__ fin,
                      const float* __restrict__ g1, const float* __restrict__ be1,
                      unsigned short* __restrict__ stb, unsigned short* __restrict__ hb) {
    int team = (blockIdx.x * 256 + threadIdx.x) >> 6;
    int c = threadIdx.x & 63;
    float sc = fin[64 + c] * g1[c];
    float tsh = (b_un[c] - fin[c]) * sc + be1[c];
    float vn = v[(size_t)team * 64 + c];
    float a[16];
#pragma unroll
    for (int j = 0; j < 16; j++) a[j] = 0.f;
    float hs = fmaxf((bf2f(ub[(size_t)team * 64 + c]) + vn) * sc + tsh, 0.f);   // self row
    a[0] = hs;
    hb[(size_t)team * 64 + c] = f2bf(hs);
    int e = off[team], e1 = off[team + 1];
    for (; e + 15 < e1; e += 16)
#pragma unroll
        for (int j = 0; j < 16; j++) {
            float h = fmaxf((bf2f(ub[(size_t)(sd_s[e + j] & 0xFFFFu) * 64 + c]) + vn) * sc + tsh, 0.f);
            a[j] += h;
            hb[(size_t)(NN + e + j) * 64 + c] = f2bf(h);
        }
    for (; e + 3 < e1; e += 4)
#pragma unroll
        for (int j = 0; j < 4; j++) {
            float h = fmaxf((bf2f(ub[(size_t)(sd_s[e + j] & 0xFFFFu) * 64 + c]) + vn) * sc + tsh, 0.f);
            a[j] += h;
            hb[(size_t)(NN + e + j) * 64 + c] = f2bf(h);
        }
    for (; e < e1; e++) {
        float h = fmaxf((bf2f(ub[(size_t)(sd_s[e] & 0xFFFFu) * 64 + c]) + vn) * sc + tsh, 0.f);
        a[0] += h;
        hb[(size_t)(NN + e) * 64 + c] = f2bf(h);
    }
#pragma unroll
    for (int j = 0; j < 8; j++) a[j] += a[j + 8];
#pragma unroll
    for (int j = 0; j < 4; j++) a[j] += a[j + 4];
    stb[(size_t)team * 64 + c] = f2bf((a[0] + a[1]) + (a[2] + a[3]));
}

// ---------- msg[n] = sum_{e:dst=n} stb[src_e]  (bf16 gather table) ----------
__global__ void k_msg_csr(const int* __restrict__ off, const unsigned int* __restrict__ sd_s,
                          const unsigned short* __restrict__ stb, float* __restrict__ msg) {
    int team = (blockIdx.x * 256 + threadIdx.x) >> 6;
    int c = threadIdx.x & 63;
    float a[16];
#pragma unroll
    for (int j = 0; j < 16; j++) a[j] = 0.f;
    int e = off[team], e1 = off[team + 1];
    for (; e + 15 < e1; e += 16)
#pragma unroll
        for (int j = 0; j < 16; j++) a[j] += bf2f(stb[(size_t)(sd_s[e + j] & 0xFFFFu) * 64 + c]);
    for (; e + 3 < e1; e += 4)
#pragma unroll
        for (int j = 0; j < 4; j++) a[j] += bf2f(stb[(size_t)(sd_s[e + j] & 0xFFFFu) * 64 + c]);
    for (; e < e1; e++) a[0] += bf2f(stb[(size_t)(sd_s[e] & 0xFFFFu) * 64 + c]);
#pragma unroll
    for (int j = 0; j < 8; j++) a[j] += a[j + 8];
#pragma unroll
    for (int j = 0; j < 4; j++) a[j] += a[j + 4];
    msg[(size_t)team * 64 + c] = (a[0] + a[1]) + (a[2] + a[3]);
}

// ---------- mb = msg @ W_gc[64:128]  (streaming; in/out may differ) ----------
__global__ void k_mb(const float* __restrict__ in, float* __restrict__ outp,
                     const float* __restrict__ W) {
    __shared__ float lds[4][16 * 68];
    const int lane = threadIdx.x & 63;
    const int wid = threadIdx.x >> 6;
    const int m = lane & 15, quad = lane >> 4;
    const int gwave = (blockIdx.x * blockDim.x + threadIdx.x) >> 6;
    const int nwaves = (gridDim.x * blockDim.x) >> 6;
    float* wl = lds[wid];

    bf16x8 wfh[2][4], wfl[2][4];
#pragma unroll
    for (int kk = 0; kk < 2; kk++)
#pragma unroll
        for (int ct = 0; ct < 4; ct++) {
            float wv[8];
#pragma unroll
            for (int j = 0; j < 8; j++)
                wv[j] = W[(kk * 32 + quad * 8 + j) * 64 + ct * 16 + m];
            split8r(wv, wfh[kk][ct], wfl[kk][ct]);
        }
    float zb[4] = {0.f, 0.f, 0.f, 0.f};

    for (int tile = gwave; tile < NT_N; tile += nwaves) {
        const int r = (tile << 4) + m;
        bf16x8 ah[2], al[2];
        split8(in + (size_t)r * 64 + quad * 8,      ah[0], al[0]);
        split8(in + (size_t)r * 64 + 32 + quad * 8, ah[1], al[1]);

        f32x4 zero = {0.f, 0.f, 0.f, 0.f};
        f32x4 acc[4];
#pragma unroll
        for (int ct = 0; ct < 4; ct++) {
            acc[ct] = zero;
#pragma unroll
            for (int kk = 0; kk < 2; kk++) {
                acc[ct] = __builtin_amdgcn_mfma_f32_16x16x32_bf16(al[kk], wfh[kk][ct], acc[ct], 0, 0, 0);
                acc[ct] = __builtin_amdgcn_mfma_f32_16x16x32_bf16(ah[kk], wfl[kk][ct], acc[ct], 0, 0, 0);
                acc[ct] = __builtin_amdgcn_mfma_f32_16x16x32_bf16(ah[kk], wfh[kk][ct], acc[ct], 0, 0, 0);
            }
        }
        epi_tile<false, false>(wl, lane, acc, zb, outp, tile, nullptr, nullptr);
    }
}

// ---------- stage-2 streaming matmul over bf16 h rows (SOFTWARE-PIPELINED):
// h2b[r] = bf16( hb[r]@Wtop2 + mb[dst(r)] + b_gc ); f32 in-loop stats -> f64 block partials.
// Next tile's hb/sd_s loads issue BEFORE current tile's MFMA+epilogue (hides HBM latency).
__global__ void k_h2(const unsigned short* __restrict__ hb, unsigned short* __restrict__ h2b,
                     const float* __restrict__ mb, const unsigned int* __restrict__ sd_s,
                     const float* __restrict__ W, const float* __restrict__ b_gc,
                     double* __restrict__ part) {
    __shared__ float lds[4][16 * 68];
    const int lane = threadIdx.x & 63;
    const int wid = threadIdx.x >> 6;
    const int m = lane & 15, quad = lane >> 4;
    const int gwave = (blockIdx.x * blockDim.x + threadIdx.x) >> 6;
    const int nwaves = (gridDim.x * blockDim.x) >> 6;
    float* wl = lds[wid];

    bf16x8 wfh[2][4], wfl[2][4];
#pragma unroll
    for (int kk = 0; kk < 2; kk++)
#pragma unroll
        for (int ct = 0; ct < 4; ct++) {
            float wv[8];
#pragma unroll
            for (int j = 0; j < 8; j++)
                wv[j] = W[(kk * 32 + quad * 8 + j) * 64 + ct * 16 + m];
            split8r(wv, wfh[kk][ct], wfl[kk][ct]);
        }

    float bv[4];
#pragma unroll
    for (int ct = 0; ct < 4; ct++) bv[ct] = b_gc[ct * 16 + m];

    float fsum[4] = {0.f,0.f,0.f,0.f}, fsq[4] = {0.f,0.f,0.f,0.f};

    int tile = gwave;
    bf16x8 c0, c1;
    int cdm = 0;
    if (tile < NT_R) {
        const int r = (tile << 4) + m;
        cdm = (tile < NT_N) ? r : (int)(sd_s[r - NN] >> 16);
        c0 = *reinterpret_cast<const bf16x8*>(hb + (size_t)r * 64 + quad * 8);
        c1 = *reinterpret_cast<const bf16x8*>(hb + (size_t)r * 64 + 32 + quad * 8);
    }

    for (; tile < NT_R; tile += nwaves) {
        // ---- prefetch next tile's inputs (in flight during MFMA + epilogue) ----
        const int tn = tile + nwaves;
        bf16x8 n0 = c0, n1 = c1;
        int ndm = cdm;
        if (tn < NT_R) {
            const int rn = (tn << 4) + m;
            ndm = (tn < NT_N) ? rn : (int)(sd_s[rn - NN] >> 16);
            n0 = *reinterpret_cast<const bf16x8*>(hb + (size_t)rn * 64 + quad * 8);
            n1 = *reinterpret_cast<const bf16x8*>(hb + (size_t)rn * 64 + 32 + quad * 8);
        }

        f32x4 zero = {0.f, 0.f, 0.f, 0.f};
        f32x4 acc[4];
#pragma unroll
        for (int ct = 0; ct < 4; ct++) {
            acc[ct] = zero;
            acc[ct] = __builtin_amdgcn_mfma_f32_16x16x32_bf16(c0, wfl[0][ct], acc[ct], 0, 0, 0);
            acc[ct] = __builtin_amdgcn_mfma_f32_16x16x32_bf16(c0, wfh[0][ct], acc[ct], 0, 0, 0);
            acc[ct] = __builtin_amdgcn_mfma_f32_16x16x32_bf16(c1, wfl[1][ct], acc[ct], 0, 0, 0);
            acc[ct] = __builtin_amdgcn_mfma_f32_16x16x32_bf16(c1, wfh[1][ct], acc[ct], 0, 0, 0);
        }

        // add mb[dst_of_row] + b_gc per element, then f32 stats + LDS-coalesced bf16 store
#pragma unroll
        for (int i = 0; i < 4; i++) {
            int dmv = __shfl(cdm, (lane & 48) + quad * 4 + i, 64);   // dm of row quad*4+i
#pragma unroll
            for (int ct = 0; ct < 4; ct++) {
                float val = acc[ct][i] + bv[ct] + mb[(size_t)dmv * 64 + ct * 16 + m];
                wl[(quad * 4 + i) * 68 + ct * 16 + m] = val;
                fsum[ct] += val;
                fsq[ct]  += val * val;
            }
        }
        asm volatile("s_waitcnt lgkmcnt(0)" ::: "memory");
#pragma unroll
        for (int j = 0; j < 4; j++) {
            int row = j * 4 + quad;
            f32x4 vv = *reinterpret_cast<const f32x4*>(wl + row * 68 + m * 4);
            unsigned int p0 = (unsigned int)f2bf(vv[0]) | ((unsigned int)f2bf(vv[1]) << 16);
            unsigned int p1 = (unsigned int)f2bf(vv[2]) | ((unsigned int)f2bf(vv[3]) << 16);
            uint2 pk; pk.x = p0; pk.y = p1;
            *reinterpret_cast<uint2*>(h2b + ((size_t)(tile << 4) + row) * 64 + m * 4) = pk;
        }

        c0 = n0; c1 = n1; cdm = ndm;
    }

    double dsum[4], dsq[4];
#pragma unroll
    for (int ct = 0; ct < 4; ct++) { dsum[ct] = (double)fsum[ct]; dsq[ct] = (double)fsq[ct]; }
    stats_block_out(&lds[0][0], lane, wid, dsum, dsq, part);
}

// ---------- agg(bf16)[n] = relu(bn2(h2b[n])) + sum_{q} relu(bn2(h2b[NN+perm_s[q]])) ----------
__global__ void k_agg_csr(const unsigned short* __restrict__ h2b, const int* __restrict__ off_s,
                          const int* __restrict__ perm_s, const float* __restrict__ fin2,
                          const float* __restrict__ g2, const float* __restrict__ be2,
                          unsigned short* __restrict__ aggb) {
    int n = (blockIdx.x * 256 + threadIdx.x) >> 6;
    int c = threadIdx.x & 63;
    float sc = fin2[64 + c] * g2[c];
    float sh = be2[c] - fin2[c] * sc;
    float a[16];
#pragma unroll
    for (int j = 0; j < 16; j++) a[j] = 0.f;
    a[0] = fmaxf(bf2f(h2b[(size_t)n * 64 + c]) * sc + sh, 0.f);   // self row
    int q = off_s[n], q1 = off_s[n + 1];
    for (; q + 15 < q1; q += 16)
#pragma unroll
        for (int j = 0; j < 16; j++) {
            float hv = bf2f(h2b[(size_t)(NN + perm_s[q + j]) * 64 + c]);
            a[j] += fmaxf(hv * sc + sh, 0.f);
        }
    for (; q + 3 < q1; q += 4)
#pragma unroll
        for (int j = 0; j < 4; j++) {
            float hv = bf2f(h2b[(size_t)(NN + perm_s[q + j]) * 64 + c]);
            a[j] += fmaxf(hv * sc + sh, 0.f);
        }
    for (; q < q1; q++) {
        float hv = bf2f(h2b[(size_t)(NN + perm_s[q]) * 64 + c]);
        a[0] += fmaxf(hv * sc + sh, 0.f);
    }
#pragma unroll
    for (int j = 0; j < 8; j++) a[j] += a[j + 8];
#pragma unroll
    for (int j = 0; j < 4; j++) a[j] += a[j + 4];
    aggb[(size_t)n * 64 + c] = f2bf((a[0] + a[1]) + (a[2] + a[3]));
}

// ---------- stage 3: t_pre = [relu(bn2(h2b[:N])), agg(bf16)] @ W_tr + b_tr, stats3 ----------
__global__ void k_mm3(const unsigned short* __restrict__ h2b, const unsigned short* __restrict__ aggb,
                      const float* __restrict__ W, const float* __restrict__ bias,
                      const float* __restrict__ fin2, const float* __restrict__ g2,
                      const float* __restrict__ be2,
                      float* __restrict__ outp, double* __restrict__ part) {
    __shared__ float lds[4][16 * 68];
    const int lane = threadIdx.x & 63;
    const int wid = threadIdx.x >> 6;
    const int m = lane & 15, quad = lane >> 4;
    const int gwave = (blockIdx.x * blockDim.x + threadIdx.x) >> 6;
    const int nwaves = (gridDim.x * blockDim.x) >> 6;
    float* wl = lds[wid];

    bf16x8 wfh[4][4], wfl[4][4];
#pragma unroll
    for (int kk = 0; kk < 4; kk++)
#pragma unroll
        for (int ct = 0; ct < 4; ct++) {
            float wv[8];
#pragma unroll
            for (int j = 0; j < 8; j++)
                wv[j] = W[(kk * 32 + quad * 8 + j) * 64 + ct * 16 + m];
            split8r(wv, wfh[kk][ct], wfl[kk][ct]);
        }

    float bv[4];
#pragma unroll
    for (int ct = 0; ct < 4; ct++) bv[ct] = bias[ct * 16 + m];

    float s2f[2][8], t2f[2][8];
#pragma unroll
    for (int kk = 0; kk < 2; kk++)
#pragma unroll
        for (int j = 0; j < 8; j++) {
            int c = kk * 32 + quad * 8 + j;
            float sc = fin2[64 + c] * g2[c];
            s2f[kk][j] = sc;
            t2f[kk][j] = be2[c] - fin2[c] * sc;
        }

    double ssum[4] = {0,0,0,0}, ssq[4] = {0,0,0,0};

    for (int tile = gwave; tile < NT_N; tile += nwaves) {
        const int r = (tile << 4) + m;
        bf16x8 ah[4], al[2];
#pragma unroll
        for (int kk = 0; kk < 2; kk++) {
            bf16x8 hv = *reinterpret_cast<const bf16x8*>(h2b + (size_t)r * 64 + kk * 32 + quad * 8);
            float tv[8];
#pragma unroll
            for (int j = 0; j < 8; j++) {
                float f = bf2f((unsigned short)hv[j]);
                tv[j] = fmaxf(f * s2f[kk][j] + t2f[kk][j], 0.f);
            }
            split8r(tv, ah[kk], al[kk]);
        }
        // agg rows are bf16 already: direct A-fragments, no lo term
        ah[2] = *reinterpret_cast<const bf16x8*>(aggb + (size_t)r * 64 + quad * 8);
        ah[3] = *reinterpret_cast<const bf16x8*>(aggb + (size_t)r * 64 + 32 + quad * 8);

        f32x4 zero = {0.f, 0.f, 0.f, 0.f};
        f32x4 acc[4];
#pragma unroll
        for (int ct = 0; ct < 4; ct++) {
            acc[ct] = zero;
#pragma unroll
            for (int kk = 0; kk < 2; kk++)
                acc[ct] = __builtin_amdgcn_mfma_f32_16x16x32_bf16(al[kk], wfh[kk][ct], acc[ct], 0, 0, 0);
#pragma unroll
            for (int kk = 0; kk < 4; kk++)
                acc[ct] = __builtin_amdgcn_mfma_f32_16x16x32_bf16(ah[kk], wfl[kk][ct], acc[ct], 0, 0, 0);
#pragma unroll
            for (int kk = 0; kk < 4; kk++)
                acc[ct] = __builtin_amdgcn_mfma_f32_16x16x32_bf16(ah[kk], wfh[kk][ct], acc[ct], 0, 0, 0);
        }

        epi_tile<false, true>(wl, lane, acc, bv, outp, tile, ssum, ssq);
    }

    stats_block_out(&lds[0][0], lane, wid, ssum, ssq, part);
}

// ---------- stage 4 ----------
__global__ void k_mm4(const float* __restrict__ tpre, const float* __restrict__ W,
                      const float* __restrict__ bias, const float* __restrict__ fin3,
                      const float* __restrict__ g2, const float* __restrict__ be2,
                      float* __restrict__ outp, double* __restrict__ part) {
    __shared__ float lds[4][16 * 68];
    const int lane = threadIdx.x & 63;
    const int wid = threadIdx.x >> 6;
    const int m = lane & 15, quad = lane >> 4;
    const int gwave = (blockIdx.x * blockDim.x + threadIdx.x) >> 6;
    const int nwaves = (gridDim.x * blockDim.x) >> 6;
    float* wl = lds[wid];

    bf16x8 wfh[2][4], wfl[2][4];
#pragma unroll
    for (int kk = 0; kk < 2; kk++)
#pragma unroll
        for (int ct = 0; ct < 4; ct++) {
            float wv[8];
#pragma unroll
            for (int j = 0; j < 8; j++)
                wv[j] = W[(kk * 32 + quad * 8 + j) * 64 + ct * 16 + m];
            split8r(wv, wfh[kk][ct], wfl[kk][ct]);
        }

    float bv[4];
#pragma unroll
    for (int ct = 0; ct < 4; ct++) bv[ct] = bias[ct * 16 + m];

    float sc[2][8], sh[2][8];
#pragma unroll
    for (int kk = 0; kk < 2; kk++)
#pragma unroll
        for (int j = 0; j < 8; j++) {
            int c = kk * 32 + quad * 8 + j;
            float s = fin3[64 + c] * g2[c];
            sc[kk][j] = s;
            sh[kk][j] = be2[c] - fin3[c] * s;
        }

    double ssum[4] = {0,0,0,0}, ssq[4] = {0,0,0,0};

    for (int tile = gwave; tile < NT_N; tile += nwaves) {
        const int r = (tile << 4) + m;
        bf16x8 ah[2], al[2];
#pragma unroll
        for (int kk = 0; kk < 2; kk++) {
            f32x4 v0 = *reinterpret_cast<const f32x4*>(tpre + (size_t)r * 64 + kk * 32 + quad * 8);
            f32x4 v1 = *reinterpret_cast<const f32x4*>(tpre + (size_t)r * 64 + kk * 32 + quad * 8 + 4);
            float tv[8];
#pragma unroll
            for (int j = 0; j < 4; j++) {
                tv[j]     = fmaxf(v0[j] * sc[kk][j]     + sh[kk][j],     0.f);
                tv[4 + j] = fmaxf(v1[j] * sc[kk][4 + j] + sh[kk][4 + j], 0.f);
            }
            split8r(tv, ah[kk], al[kk]);
        }

        f32x4 zero = {0.f, 0.f, 0.f, 0.f};
        f32x4 acc[4];
#pragma unroll
        for (int ct = 0; ct < 4; ct++) {
            acc[ct] = zero;
#pragma unroll
            for (int kk = 0; kk < 2; kk++) {
                acc[ct] = __builtin_amdgcn_mfma_f32_16x16x32_bf16(al[kk], wfh[kk][ct], acc[ct], 0, 0, 0);
                acc[ct] = __builtin_amdgcn_mfma_f32_16x16x32_bf16(ah[kk], wfl[kk][ct], acc[ct], 0, 0, 0);
                acc[ct] = __builtin_amdgcn_mfma_f32_16x16x32_bf16(ah[kk], wfh[kk][ct], acc[ct], 0, 0, 0);
            }
        }

        epi_tile<true, true>(wl, lane, acc, bv, outp, tile, ssum, ssq);
    }

    stats_block_out(&lds[0][0], lane, wid, ssum, ssq, part);
}

// out = relu(bn(out_pre; stats4, g3, be3)) -> f32
__global__ void k_out(const float* __restrict__ op, const float* __restrict__ fin,
                      const float* __restrict__ g, const float* __restrict__ be,
                      float* __restrict__ out) {
    int i = blockIdx.x * 256 + threadIdx.x;   // covers NN*64 exactly
    int c = i & 63;
    out[i] = fmaxf((op[i] - fin[c]) * fin[64 + c] * g[c] + be[c], 0.f);
}

extern "C" void kernel_launch(void* const* d_in, const int* in_sizes, int n_in,
                              void* d_out, int out_size, void* d_ws, size_t ws_size,
                              hipStream_t stream) {
    const float* x    = (const float*)d_in[0];
    const int*   ei   = (const int*)d_in[1];
    const float* W_un = (const float*)d_in[2];
    const float* b_un = (const float*)d_in[3];
    const float* g1   = (const float*)d_in[4];
    const float* be1  = (const float*)d_in[5];
    const float* W_gc = (const float*)d_in[6];
    const float* b_gc = (const float*)d_in[7];
    const float* g2   = (const float*)d_in[8];
    const float* be2  = (const float*)d_in[9];
    const float* W_tr = (const float*)d_in[10];
    const float* b_tr = (const float*)d_in[11];
    const float* W_li = (const float*)d_in[12];
    const float* b_li = (const float*)d_in[13];
    const float* g3   = (const float*)d_in[14];
    const float* be3  = (const float*)d_in[15];

    float* ws = (float*)d_ws;
    const size_t FN = (size_t)NN * 64;           // 3.2M floats (12.8 MB)
    const size_t FR = (size_t)RR * 64;           // 54.4M floats (217.6 MB)
    // Region plan (zero growth; lifetimes verified):
    //  P0: ub (bf16) -> msg/mb -> part_mm3 -> outpre
    //  P1: v -> aggb (bf16, after v dead) -> part_mm4 (aggb dead after k_mm3)
    //  P2: csum -> part_uv (512KB, after scans) -> stb (bf16, after k_red) -> part_h2 -> tpre
    //  H: dsum [0,FN), xb16 [FN,1.5FN) — dead after k_uv3/k_dsum
    //      -> hb (FR ushorts) + h2b (FR ushorts)
    float* P0 = ws;
    float* P1 = ws + FN;
    float* P2 = ws + 2 * FN;
    float* H  = ws + 3 * FN;
    unsigned short* ub   = (unsigned short*)P0;      // bf16 u table (gathered by k_s1h)
    float* v      = P1;
    unsigned short* stb  = (unsigned short*)P2;      // bf16 s_tab (gathered by k_msg)
    int*   csum   = (int*)P2;     // 196 ints, scan scratch
    double* part_uv = (double*)P2;   // 512*128*8B = 512KB (csum dead, before stb)
    float* dsum   = H;
    unsigned short* xb16 = (unsigned short*)(H + FN);   // bf16 x copy (k_dsum gather)
    unsigned short* hb  = (unsigned short*)H;        // bf16 h rows
    unsigned short* h2b = (unsigned short*)H + FR;   // bf16 h2pre rows
    float* msg    = P0;           // becomes mb after k_mb (in place; ub dead)
    unsigned short* aggb = (unsigned short*)P1;      // bf16 agg (v dead)
    float* tpre   = P2;
    float* outpre = P0;
    double* part_h2 = (double*)P2;   // 2MB (stb dead, before tpre)
    double* part_m3 = (double*)P0;   // 512KB (mb dead, before outpre)
    double* part_m4 = (double*)P1;   // 512KB (aggb dead)
    double*       stats_raw = (double*)(H + FR);
    int*          od        = (int*)(stats_raw + 512);
    int*          id        = od + NN;
    int*          off       = id + NN;
    int*          cursor    = off + NN + 1;
    int*          off_s     = cursor + NN;
    int*          cursor_s  = off_s + NN + 1;
    unsigned int* sd_s      = (unsigned int*)(cursor_s + NN);   // packed src|dst<<16, dst-sorted
    int*          perm_s    = (int*)(sd_s + EE);
    float*        stats_fin = (float*)(perm_s + EE);

    // zero: stats_raw + od + id (contiguous)
    hipMemsetAsync(stats_raw, 0, 512 * sizeof(double) + 2 * NN * sizeof(int), stream);

    // build dst-sorted packed edge list + src-CSR permutation (coalesced 3-phase scan)
    k_degx <<<12500, 256, 0, stream>>>(ei, od, id, x, xb16);
    k_scanA<<<2 * NCH, 256, 0, stream>>>(id, od, csum);
    k_scanB<<<1, 256, 0, stream>>>(csum);
    k_scanC<<<2 * NCH, 256, 0, stream>>>(id, od, csum, off, cursor, off_s, cursor_s);
    k_fill <<<3125, 256, 0, stream>>>(ei, cursor, sd_s);
    k_fill2<<<3125, 256, 0, stream>>>(sd_s, cursor_s, perm_s);

    // stage 0 + per-node tables (stage-1 stats fused into k_uv3; u2 never materialized)
    k_dsum_csr<<<12500, 256, 0, stream>>>(x, xb16, off, sd_s, dsum);
    k_uv3<<<NBLK_MM, 256, 0, stream>>>(x, dsum, W_un, od, id, ub, v, part_uv);
    k_red<<<16, 128, 0, stream>>>(part_uv, NBLK_MM, stats_raw + 0);
    k_fin1<<<1, 64, 0, stream>>>(stats_raw + 0, b_un, stats_fin + 0, 1.0 / (double)RR);

    // stage-1 CSR reduce + per-row bf16 h store
    k_s1h<<<12500, 256, 0, stream>>>(ub, v, off, sd_s, b_un, stats_fin + 0, g1, be1,
                                     stb, hb);
    k_msg_csr<<<12500, 256, 0, stream>>>(off, sd_s, stb, msg);
    k_mb<<<512, 256, 0, stream>>>(msg, msg, W_gc + 64 * 64);   // msg -> mb in place

    // stage-2: pipelined streaming matmul over bf16 h rows -> bf16 h2 rows
    k_h2<<<NBLK_H2, 256, 0, stream>>>(hb, h2b, msg, sd_s, W_gc, b_gc, part_h2);
    k_red<<<32, 128, 0, stream>>>(part_h2, NBLK_H2, stats_raw + 128);
    k_fin<<<1, 64, 0, stream>>>(stats_raw + 128, stats_fin + 128, 1.0 / (double)RR);
    k_agg_csr<<<12500, 256, 0, stream>>>(h2b, off_s, perm_s, stats_fin + 128, g2, be2, aggb);

    // stage 3
    k_mm3<<<NBLK_MM, 256, 0, stream>>>(h2b, aggb, W_tr, b_tr, stats_fin + 128, g2, be2,
                                       tpre, part_m3);
    k_red<<<16, 128, 0, stream>>>(part_m3, NBLK_MM, stats_raw + 256);
    k_fin<<<1, 64, 0, stream>>>(stats_raw + 256, stats_fin + 256, 1.0 / (double)NN);

    // stage 4
    k_mm4<<<NBLK_MM, 256, 0, stream>>>(tpre, W_li, b_li, stats_fin + 256, g2, be2,
                                       outpre, part_m4);
    k_red<<<16, 128, 0, stream>>>(part_m4, NBLK_MM, stats_raw + 384);
    k_fin<<<1, 64, 0, stream>>>(stats_raw + 384, stats_fin + 384, 1.0 / (double)NN);

    k_out<<<12500, 256, 0, stream>>>(outpre, stats_fin + 384, g3, be3, (float*)d_out);
}